// Round 1
// baseline (3917.619 us; speedup 1.0000x reference)
//
#include <hip/hip_runtime.h>
#include <math.h>

#define LCNT 4
#define BB 2
#define LL_ 1024
#define NN 64
#define DD 128
#define HHD 4
#define FFH 512
// tokens
#define TT (BB*LL_*NN)

// ---------------- transpose x[B,D,L,N] -> y[B,L,N,D] ----------------
__global__ __launch_bounds__(256) void k_transpose(const float* __restrict__ x,
                                                   float* __restrict__ y){
  int g = blockIdx.x;            // b*1024 + l
  int b = g >> 10, l = g & 1023;
  __shared__ float sh[128*65];
  for (int idx = threadIdx.x; idx < 128*64; idx += 256){
    int d = idx >> 6, n = idx & 63;
    sh[d*65+n] = x[(((size_t)b*128 + d)*1024 + l)*64 + n];
  }
  __syncthreads();
  for (int idx = threadIdx.x; idx < 128*64; idx += 256){
    int n = idx >> 7, d = idx & 127;
    y[((size_t)g*64 + n)*128 + d] = sh[d*65+n];
  }
}

// ---------------- LN stats (mean, rstd) per token ----------------
__global__ __launch_bounds__(256) void k_lnstats(const float* __restrict__ y,
                                                 float2* __restrict__ stats){
  int t = blockIdx.x*4 + (threadIdx.x>>6);
  int lane = threadIdx.x & 63;
  const float* p = y + (size_t)t*128;
  float a = p[lane], c = p[lane+64];
  float s = a + c;
  for (int m=32;m>=1;m>>=1) s += __shfl_xor(s, m);
  float mean = s * (1.0f/128.0f);
  float da = a-mean, dc = c-mean;
  float v = da*da + dc*dc;
  for (int m=32;m>=1;m>>=1) v += __shfl_xor(v, m);
  float rstd = rsqrtf(v*(1.0f/128.0f) + 1e-5f);
  if (lane==0) stats[t] = make_float2(mean, rstd);
}

// ---------------- row attention core: q + P per (b,l) ----------------
__global__ __launch_bounds__(256) void k_row_core(
    const float* __restrict__ y, const float2* __restrict__ stats,
    const float* __restrict__ qw, const float* __restrict__ qb,
    const float* __restrict__ kw, const float* __restrict__ kb,
    const float* __restrict__ vw, const float* __restrict__ vb,
    const float* __restrict__ ow,
    const float* __restrict__ gam, const float* __restrict__ bet,
    float* __restrict__ qout, float* __restrict__ Pout)
{
  int g = blockIdx.x;  // b*1024+l
  __shared__ float sh_h[64*129];
  __shared__ float sh_qw[512], sh_kw[512];
  __shared__ float sh_k[256];
  __shared__ float sh_hk[512];
  __shared__ float sh_ktv[128];
  int tid = threadIdx.x;
  for (int i = tid; i < 512; i += 256){ sh_qw[i] = qw[i]; sh_kw[i] = kw[i]; }
  const float* yb = y + (size_t)g*8192;
  for (int idx = tid; idx < 8192; idx += 256){
    int n = idx >> 7, d = idx & 127;
    float2 st = stats[g*64+n];
    sh_h[n*129+d] = (yb[idx]-st.x)*st.y*gam[d] + bet[d];
  }
  __syncthreads();
  int h = tid >> 6, n = tid & 63;
  float qr = qb[h], kr = kb[h];
  {
    const float* qwp = sh_qw + h*128;
    const float* kwp = sh_kw + h*128;
    const float* hp  = sh_h + n*129;
    #pragma unroll 4
    for (int d = 0; d < 128; d++){ float hv = hp[d]; qr += hv*qwp[d]; kr += hv*kwp[d]; }
  }
  qr = qr > 0.f ? qr + 1.f : expf(qr);   // elu+1
  kr = kr > 0.f ? kr + 1.f : expf(kr);
  float qs = qr; for (int m=32;m>=1;m>>=1) qs += __shfl_xor(qs, m);
  float ks = kr; for (int m=32;m>=1;m>>=1) ks += __shfl_xor(ks, m);
  float qn = qr * (64.f/qs);
  float kn = kr * (1.f/ks);
  qout[((size_t)g*4 + h)*64 + n] = qn;
  sh_k[h*64+n] = kn;
  __syncthreads();
  // hk[h][d] = sum_n k[h][n]*hnorm[n][d]
  #pragma unroll
  for (int r = 0; r < 2; r++){
    int idx = tid + r*256;
    int hh = idx >> 7, d = idx & 127;
    float acc = 0.f;
    #pragma unroll 4
    for (int nn = 0; nn < 64; nn++) acc += sh_k[hh*64+nn]*sh_h[nn*129+d];
    sh_hk[hh*128+d] = acc;
  }
  __syncthreads();
  // ktv[e] = vb[e] + vw[e,:]·hk[e>>5,:]
  if (tid < 128){
    float acc = vb[tid];
    const float* vr = vw + (size_t)tid*128;
    const float* hp2 = sh_hk + (tid>>5)*128;
    #pragma unroll 4
    for (int d = 0; d < 128; d++) acc += vr[d]*hp2[d];
    sh_ktv[tid] = acc;
  }
  __syncthreads();
  // P[h][e] = sum_{j<32} ow[e, h*32+j]*ktv[h*32+j]
  #pragma unroll
  for (int r = 0; r < 2; r++){
    int idx = tid + r*256;
    int hh = idx >> 7, e = idx & 127;
    float acc = 0.f;
    const float* orow = ow + (size_t)e*128 + hh*32;
    const float* kt = sh_ktv + hh*32;
    #pragma unroll 4
    for (int j = 0; j < 32; j++) acc += orow[j]*kt[j];
    Pout[((size_t)g*4 + hh)*128 + e] = acc;
  }
}

// ---------------- row attention output: y += q·P + ob ----------------
__global__ __launch_bounds__(256) void k_row_out(float* __restrict__ y,
    const float* __restrict__ qbuf, const float* __restrict__ P,
    const float* __restrict__ ob){
  int g = blockIdx.x;
  __shared__ float sh_P[512];
  __shared__ float sh_q[256];
  int tid = threadIdx.x;
  for (int i = tid; i < 512; i += 256) sh_P[i] = P[(size_t)g*512 + i];
  if (tid < 256) sh_q[tid] = qbuf[(size_t)g*256 + tid];
  __syncthreads();
  float4* y4 = (float4*)(y + (size_t)g*8192);
  const float4* P4 = (const float4*)sh_P;
  const float4* ob4 = (const float4*)ob;
  for (int idx = tid; idx < 2048; idx += 256){
    int n = idx >> 5, e4 = idx & 31;
    float4 v = y4[idx];
    float q0 = sh_q[n], q1 = sh_q[64+n], q2 = sh_q[128+n], q3 = sh_q[192+n];
    float4 p0 = P4[e4], p1 = P4[32+e4], p2 = P4[64+e4], p3 = P4[96+e4];
    float4 b4 = ob4[e4];
    v.x += b4.x + q0*p0.x + q1*p1.x + q2*p2.x + q3*p3.x;
    v.y += b4.y + q0*p0.y + q1*p1.y + q2*p2.y + q3*p3.y;
    v.z += b4.z + q0*p0.z + q1*p1.z + q2*p2.z + q3*p3.z;
    v.w += b4.w + q0*p0.w + q1*p1.w + q2*p2.w + q3*p3.w;
    y4[idx] = v;
  }
}

// ---------------- col attention: raw q,k (elu+1), layout [b][n][h][l] ----------------
__global__ __launch_bounds__(256) void k_col_qk(
    const float* __restrict__ y, const float2* __restrict__ stats,
    const float* __restrict__ qw, const float* __restrict__ qb,
    const float* __restrict__ kw, const float* __restrict__ kb,
    const float* __restrict__ gam, const float* __restrict__ bet,
    float* __restrict__ qout, float* __restrict__ kout)
{
  int g = blockIdx.x; int b = g >> 10, l = g & 1023;
  __shared__ float sh_h[64*129];
  __shared__ float sh_qw[512], sh_kw[512];
  int tid = threadIdx.x;
  for (int i = tid; i < 512; i += 256){ sh_qw[i] = qw[i]; sh_kw[i] = kw[i]; }
  const float* yb = y + (size_t)g*8192;
  for (int idx = tid; idx < 8192; idx += 256){
    int n = idx >> 7, d = idx & 127;
    float2 st = stats[g*64+n];
    sh_h[n*129+d] = (yb[idx]-st.x)*st.y*gam[d] + bet[d];
  }
  __syncthreads();
  int h = tid >> 6, n = tid & 63;
  float qr = qb[h], kr = kb[h];
  const float* qwp = sh_qw + h*128;
  const float* kwp = sh_kw + h*128;
  const float* hp  = sh_h + n*129;
  #pragma unroll 4
  for (int d = 0; d < 128; d++){ float hv = hp[d]; qr += hv*qwp[d]; kr += hv*kwp[d]; }
  qr = qr > 0.f ? qr + 1.f : expf(qr);
  kr = kr > 0.f ? kr + 1.f : expf(kr);
  size_t o = (((size_t)b*64 + n)*4 + h)*1024 + l;
  qout[o] = qr; kout[o] = kr;
}

// ---------------- col: normalizers per (b,n,h) ----------------
__global__ __launch_bounds__(256) void k_col_sum(const float* __restrict__ qin,
    const float* __restrict__ kin, float* __restrict__ qs, float* __restrict__ ks){
  int gg = blockIdx.x;  // (b*64+n)*4+h
  const float* qp = qin + (size_t)gg*1024;
  const float* kp = kin + (size_t)gg*1024;
  float sq = 0.f, sk = 0.f;
  for (int i = threadIdx.x; i < 1024; i += 256){ sq += qp[i]; sk += kp[i]; }
  for (int m=32;m>=1;m>>=1){ sq += __shfl_xor(sq, m); sk += __shfl_xor(sk, m); }
  __shared__ float aq[4], ak[4];
  int w = threadIdx.x >> 6;
  if ((threadIdx.x & 63) == 0){ aq[w] = sq; ak[w] = sk; }
  __syncthreads();
  if (threadIdx.x == 0){
    float fq = aq[0]+aq[1]+aq[2]+aq[3];
    float fk = ak[0]+ak[1]+ak[2]+ak[3];
    qs[gg] = 1024.f/fq;  ks[gg] = 1.f/fk;
  }
}

// ---------------- col: hk partials over l slices ----------------
__global__ __launch_bounds__(256) void k_col_hk(
    const float* __restrict__ y, const float2* __restrict__ stats,
    const float* __restrict__ kin, const float* __restrict__ ksn,
    const float* __restrict__ gam, const float* __restrict__ bet,
    float* __restrict__ hkp)
{
  int gg = blockIdx.x;                   // ((b*64+n)*8+s)
  int s = gg & 7, n = (gg>>3) & 63, b = gg>>9;
  int tid = threadIdx.x;
  __shared__ float sh_tok[256];
  int h = tid >> 6, d0 = (tid & 63)*2;
  float a0 = 0.f, a1 = 0.f;
  const float* kp = kin + (((size_t)b*64 + n)*4 + h)*1024;
  int li = tid >> 7, d = tid & 127;
  for (int l0 = s*128; l0 < s*128+128; l0 += 2){
    int t = ((b*1024 + l0 + li)*64 + n);
    float2 st = stats[t];
    sh_tok[li*128+d] = (y[(size_t)t*128 + d]-st.x)*st.y*gam[d] + bet[d];
    __syncthreads();
    float k0 = kp[l0], k1 = kp[l0+1];
    float2 t0 = *(const float2*)&sh_tok[d0];
    float2 t1 = *(const float2*)&sh_tok[128+d0];
    a0 += k0*t0.x + k1*t1.x;
    a1 += k0*t0.y + k1*t1.y;
    __syncthreads();
  }
  float kn = ksn[((size_t)b*64 + n)*4 + h];
  size_t base = ((size_t)gg*4 + h)*128;
  hkp[base + d0]   = a0*kn;
  hkp[base + d0+1] = a1*kn;
}

// ---------------- col: reduce hk, ktv, P (qs folded) ----------------
__global__ __launch_bounds__(256) void k_col_ktvP(
    const float* __restrict__ hkp,
    const float* __restrict__ vw, const float* __restrict__ vb,
    const float* __restrict__ ow, const float* __restrict__ qsn,
    float* __restrict__ Pout)
{
  int gg = blockIdx.x;   // b*64+n
  __shared__ float sh_hk[512];
  __shared__ float sh_ktv[128];
  int tid = threadIdx.x;
  #pragma unroll
  for (int r = 0; r < 2; r++){
    int idx = tid + r*256;
    float acc = 0.f;
    #pragma unroll
    for (int s = 0; s < 8; s++) acc += hkp[((size_t)gg*8 + s)*512 + idx];
    sh_hk[idx] = acc;
  }
  __syncthreads();
  if (tid < 128){
    float acc = vb[tid];
    const float* vr = vw + (size_t)tid*128;
    const float* hp2 = sh_hk + (tid>>5)*128;
    #pragma unroll 4
    for (int d = 0; d < 128; d++) acc += vr[d]*hp2[d];
    sh_ktv[tid] = acc;
  }
  __syncthreads();
  #pragma unroll
  for (int r = 0; r < 2; r++){
    int idx = tid + r*256;
    int hh = idx >> 7, e = idx & 127;
    float acc = 0.f;
    const float* orow = ow + (size_t)e*128 + hh*32;
    #pragma unroll 4
    for (int j = 0; j < 32; j++) acc += orow[j]*sh_ktv[hh*32+j];
    Pout[(size_t)gg*512 + hh*128 + e] = acc * qsn[gg*4 + hh];
  }
}

// ---------------- col attention output ----------------
__global__ __launch_bounds__(256) void k_col_out(float* __restrict__ y,
    const float* __restrict__ qin, const float* __restrict__ P,
    const float* __restrict__ ob){
  int gg = blockIdx.x;                 // ((b*64+n)*8+s)
  int s = gg & 7, n = (gg>>3) & 63, b = gg>>9;
  __shared__ float shP[512];
  __shared__ float shq[512];
  int tid = threadIdx.x;
  for (int i = tid; i < 512; i += 256) shP[i] = P[(size_t)(gg>>3)*512 + i];
  for (int i = tid; i < 512; i += 256){
    int h = i >> 7, l = i & 127;
    shq[i] = qin[(((size_t)b*64 + n)*4 + h)*1024 + s*128 + l];
  }
  __syncthreads();
  const float4* P4 = (const float4*)shP;
  const float4* ob4 = (const float4*)ob;
  for (int idx = tid; idx < 4096; idx += 256){
    int ll = idx >> 5, e4 = idx & 31;
    size_t t = ((size_t)b*1024 + s*128 + ll)*64 + n;
    float4* yp = (float4*)(y + t*128) + e4;
    float4 v = *yp;
    float q0 = shq[ll], q1 = shq[128+ll], q2 = shq[256+ll], q3 = shq[384+ll];
    float4 p0 = P4[e4], p1 = P4[32+e4], p2 = P4[64+e4], p3 = P4[96+e4];
    float4 b4 = ob4[e4];
    v.x += b4.x + q0*p0.x + q1*p1.x + q2*p2.x + q3*p3.x;
    v.y += b4.y + q0*p0.y + q1*p1.y + q2*p2.y + q3*p3.y;
    v.z += b4.z + q0*p0.z + q1*p1.z + q2*p2.z + q3*p3.z;
    v.w += b4.w + q0*p0.w + q1*p1.w + q2*p2.w + q3*p3.w;
    *yp = v;
  }
}

// ---------------- fused FFN: y += W2·gelu(W1·LN(y)+b1)+b2 ----------------
__global__ __launch_bounds__(256) void k_ffn(
    float* __restrict__ y, const float2* __restrict__ stats,
    const float* __restrict__ gam, const float* __restrict__ bet,
    const float* __restrict__ w1, const float* __restrict__ b1,
    const float* __restrict__ w2, const float* __restrict__ b2)
{
  __shared__ float sh_h[32*132];
  __shared__ float sh_w[8448];     // union: w1t [128][66] / w2t [64][132]
  __shared__ float sh_hf[32*66];
  int tid = threadIdx.x;
  size_t tb = (size_t)blockIdx.x*32;
  for (int idx = tid; idx < 4096; idx += 256){
    int tt = idx >> 7, d = idx & 127;
    float2 st = stats[tb+tt];
    sh_h[tt*132+d] = (y[(tb+tt)*128 + d]-st.x)*st.y*gam[d] + bet[d];
  }
  float acc[4][4] = {};
  int ttg = tid >> 5, dg = tid & 31;
  for (int c = 0; c < 8; c++){
    int e0 = c*64;
    __syncthreads();
    // stage w1 chunk transposed: sh_w[d*66 + el] = w1[e0+el][d]
    for (int idx = tid; idx < 2048; idx += 256){
      int el = idx >> 5, d4 = idx & 31;
      float4 wv = ((const float4* __restrict__)w1)[(size_t)(e0+el)*32 + d4];
      sh_w[(d4*4+0)*66 + el] = wv.x;
      sh_w[(d4*4+1)*66 + el] = wv.y;
      sh_w[(d4*4+2)*66 + el] = wv.z;
      sh_w[(d4*4+3)*66 + el] = wv.w;
    }
    __syncthreads();
    float acc1[4][2] = {};
    #pragma unroll 4
    for (int d = 0; d < 128; d++){
      float2 wv = *(const float2*)&sh_w[d*66 + dg*2];
      float h0 = sh_h[(ttg*4+0)*132+d];
      float h1 = sh_h[(ttg*4+1)*132+d];
      float h2 = sh_h[(ttg*4+2)*132+d];
      float h3 = sh_h[(ttg*4+3)*132+d];
      acc1[0][0] += h0*wv.x; acc1[0][1] += h0*wv.y;
      acc1[1][0] += h1*wv.x; acc1[1][1] += h1*wv.y;
      acc1[2][0] += h2*wv.x; acc1[2][1] += h2*wv.y;
      acc1[3][0] += h3*wv.x; acc1[3][1] += h3*wv.y;
    }
    __syncthreads();   // GEMM1 done reading sh_w
    #pragma unroll
    for (int i = 0; i < 4; i++){
      #pragma unroll
      for (int j = 0; j < 2; j++){
        float v = acc1[i][j] + b1[e0 + dg*2 + j];
        sh_hf[(ttg*4+i)*66 + dg*2 + j] = 0.5f*v*(1.0f + erff(v*0.70710678118f));
      }
    }
    // stage w2 chunk transposed: sh_w[el*132 + d] = w2[d][e0+el]
    for (int idx = tid; idx < 8192; idx += 256){
      int el = idx & 63, d = idx >> 6;
      sh_w[el*132 + d] = w2[(size_t)d*512 + e0 + el];
    }
    __syncthreads();
    #pragma unroll 2
    for (int el = 0; el < 64; el++){
      float4 w4 = *(const float4*)&sh_w[el*132 + dg*4];
      float f0 = sh_hf[(ttg*4+0)*66+el];
      float f1 = sh_hf[(ttg*4+1)*66+el];
      float f2 = sh_hf[(ttg*4+2)*66+el];
      float f3 = sh_hf[(ttg*4+3)*66+el];
      acc[0][0]+=f0*w4.x; acc[0][1]+=f0*w4.y; acc[0][2]+=f0*w4.z; acc[0][3]+=f0*w4.w;
      acc[1][0]+=f1*w4.x; acc[1][1]+=f1*w4.y; acc[1][2]+=f1*w4.z; acc[1][3]+=f1*w4.w;
      acc[2][0]+=f2*w4.x; acc[2][1]+=f2*w4.y; acc[2][2]+=f2*w4.z; acc[2][3]+=f2*w4.w;
      acc[3][0]+=f3*w4.x; acc[3][1]+=f3*w4.y; acc[3][2]+=f3*w4.z; acc[3][3]+=f3*w4.w;
    }
  }
  float4 bb = ((const float4* __restrict__)b2)[dg];
  #pragma unroll
  for (int i = 0; i < 4; i++){
    float4* yp = (float4*)(y + (tb + ttg*4 + i)*128) + dg;
    float4 v = *yp;
    v.x += acc[i][0]+bb.x; v.y += acc[i][1]+bb.y;
    v.z += acc[i][2]+bb.z; v.w += acc[i][3]+bb.w;
    *yp = v;
  }
}

// ---------------- head: xb = mean over l=1..1023 ----------------
__global__ __launch_bounds__(128) void k_xb(const float* __restrict__ y,
                                            float* __restrict__ xb){
  int gg = blockIdx.x;   // b*64+n
  int b = gg >> 6, n = gg & 63;
  int d = threadIdx.x;
  float acc = 0.f;
  const float* p = y + (((size_t)b*1024 + 1)*64 + n)*128 + d;
  #pragma unroll 4
  for (int l = 1; l < 1024; l++){ acc += *p; p += 64*128; }
  xb[(size_t)gg*128 + d] = acc * (1.0f/1023.0f);
}

// ---------------- head: pairwise distances ----------------
__global__ __launch_bounds__(64) void k_dist(const float* __restrict__ xb,
                                             float* __restrict__ out){
  int p = blockIdx.x;           // b*2016 + pair
  int b = p >= 2016 ? 1 : 0;
  int pr = p - b*2016;
  int i0 = (int)((1.0f + sqrtf(1.0f + 8.0f*(float)pr))*0.5f);
  while (i0*(i0-1)/2 > pr) i0--;
  while ((i0+1)*i0/2 <= pr) i0++;
  int i1 = pr - i0*(i0-1)/2;
  int lane = threadIdx.x;
  const float* xa = xb + ((size_t)b*64 + i0)*128;
  const float* xc = xb + ((size_t)b*64 + i1)*128;
  float d0 = xa[lane]-xc[lane], d1 = xa[lane+64]-xc[lane+64];
  float s = d0*d0 + d1*d1;
  for (int m=32;m>=1;m>>=1) s += __shfl_xor(s, m);
  if (lane == 0) out[p] = sqrtf(s + 1e-8f);
}

extern "C" void kernel_launch(void* const* d_in, const int* in_sizes, int n_in,
                              void* d_out, int out_size, void* d_ws, size_t ws_size,
                              hipStream_t stream){
  const float* x    = (const float*)d_in[0];
  const float* rq_w = (const float*)d_in[1];  const float* rq_b = (const float*)d_in[2];
  const float* rk_w = (const float*)d_in[3];  const float* rk_b = (const float*)d_in[4];
  const float* rv_w = (const float*)d_in[5];  const float* rv_b = (const float*)d_in[6];
  const float* ro_w = (const float*)d_in[7];  const float* ro_b = (const float*)d_in[8];
  const float* cq_w = (const float*)d_in[9];  const float* cq_b = (const float*)d_in[10];
  const float* ck_w = (const float*)d_in[11]; const float* ck_b = (const float*)d_in[12];
  const float* cv_w = (const float*)d_in[13]; const float* cv_b = (const float*)d_in[14];
  const float* co_w = (const float*)d_in[15]; const float* co_b = (const float*)d_in[16];
  const float* lrg  = (const float*)d_in[17]; const float* lrb  = (const float*)d_in[18];
  const float* lcg  = (const float*)d_in[19]; const float* lcb  = (const float*)d_in[20];
  const float* lfg  = (const float*)d_in[21]; const float* lfb  = (const float*)d_in[22];
  const float* f1w  = (const float*)d_in[23]; const float* f1b  = (const float*)d_in[24];
  const float* f2w  = (const float*)d_in[25]; const float* f2b  = (const float*)d_in[26];

  float* ws = (float*)d_ws;
  float*  y   = ws;                           // 16777216
  float2* st  = (float2*)(ws + 16777216);     // 262144 floats
  float*  qb_ = ws + 17039360;                // 524288
  float*  kb_ = ws + 17563648;                // 524288
  float*  Pb  = ws + 18087936;                // 1048576
  float*  hkp = ws + 19136512;                // 524288
  float*  qs  = ws + 19660800;                // 512
  float*  ks  = ws + 19661312;                // 512
  float*  xb  = ws + 19661824;                // 16384

  k_transpose<<<dim3(2048), dim3(256), 0, stream>>>(x, y);
  for (int l = 0; l < LCNT; l++){
    // row attention
    k_lnstats<<<dim3(32768), dim3(256), 0, stream>>>(y, st);
    k_row_core<<<dim3(2048), dim3(256), 0, stream>>>(y, st,
        rq_w + l*512, rq_b + l*4, rk_w + l*512, rk_b + l*4,
        rv_w + (size_t)l*16384, rv_b + l*128, ro_w + (size_t)l*16384,
        lrg + l*128, lrb + l*128, qb_, Pb);
    k_row_out<<<dim3(2048), dim3(256), 0, stream>>>(y, qb_, Pb, ro_b + l*128);
    // col attention
    k_lnstats<<<dim3(32768), dim3(256), 0, stream>>>(y, st);
    k_col_qk<<<dim3(2048), dim3(256), 0, stream>>>(y, st,
        cq_w + l*512, cq_b + l*4, ck_w + l*512, ck_b + l*4,
        lcg + l*128, lcb + l*128, qb_, kb_);
    k_col_sum<<<dim3(512), dim3(256), 0, stream>>>(qb_, kb_, qs, ks);
    k_col_hk<<<dim3(1024), dim3(256), 0, stream>>>(y, st, kb_, ks,
        lcg + l*128, lcb + l*128, hkp);
    k_col_ktvP<<<dim3(128), dim3(256), 0, stream>>>(hkp,
        cv_w + (size_t)l*16384, cv_b + l*128, co_w + (size_t)l*16384, qs, Pb);
    k_col_out<<<dim3(1024), dim3(256), 0, stream>>>(y, qb_, Pb, co_b + l*128);
    // FFN
    k_lnstats<<<dim3(32768), dim3(256), 0, stream>>>(y, st);
    k_ffn<<<dim3(4096), dim3(256), 0, stream>>>(y, st, lfg + l*128, lfb + l*128,
        f1w + (size_t)l*65536, f1b + l*512, f2w + (size_t)l*65536, f2b + l*128);
  }
  k_xb<<<dim3(128), dim3(128), 0, stream>>>(y, xb);
  k_dist<<<dim3(4032), dim3(64), 0, stream>>>(xb, (float*)d_out);
}

// Round 2
// 2056.446 us; speedup vs baseline: 1.9050x; 1.9050x over previous
//
#include <hip/hip_runtime.h>
#include <math.h>

#define LCNT 4

typedef float f32x4 __attribute__((ext_vector_type(4)));
typedef short bf16x8 __attribute__((ext_vector_type(8)));

__device__ __forceinline__ ushort bfr(float x){
  unsigned int b = __float_as_uint(x);
  return (ushort)((b + 0x7FFFu + ((b>>16)&1u)) >> 16);
}
__device__ __forceinline__ unsigned int pk2(float a, float b){
  return (unsigned int)bfr(a) | ((unsigned int)bfr(b)<<16);
}
__device__ __forceinline__ float fast_gelu(float v){
  float s = fabsf(v) * 0.70710678118f;
  float t = 1.0f/(1.0f + 0.3275911f*s);
  float p = t*(0.254829592f + t*(-0.284496736f + t*(1.421413741f +
            t*(-1.453152027f + t*1.061405429f))));
  float e = 1.0f - p*__expf(-s*s);
  e = copysignf(e, v);
  return 0.5f*v*(1.0f + e);
}

// ---------------- transpose x[B,D,L,N] -> y[B,L,N,D] ----------------
__global__ __launch_bounds__(256) void k_transpose(const float* __restrict__ x,
                                                   float* __restrict__ y){
  int g = blockIdx.x;            // b*1024 + l
  int b = g >> 10, l = g & 1023;
  __shared__ float sh[128*65];
  for (int idx = threadIdx.x; idx < 128*64; idx += 256){
    int d = idx >> 6, n = idx & 63;
    sh[d*65+n] = x[(((size_t)b*128 + d)*1024 + l)*64 + n];
  }
  __syncthreads();
  for (int idx = threadIdx.x; idx < 128*64; idx += 256){
    int n = idx >> 7, d = idx & 127;
    y[((size_t)g*64 + n)*128 + d] = sh[d*65+n];
  }
}

// ---------------- fp32 -> bf16 weight conversion ----------------
__global__ __launch_bounds__(256) void k_cvt(const float* __restrict__ src,
                                             ushort* __restrict__ dst, int n4){
  int i = blockIdx.x*256 + threadIdx.x;
  if (i < n4){
    float4 v = ((const float4*)src)[i];
    ushort4 p; p.x=bfr(v.x); p.y=bfr(v.y); p.z=bfr(v.z); p.w=bfr(v.w);
    ((ushort4*)dst)[i] = p;
  }
}

// ---------------- LN stats (mean, rstd) per token ----------------
__global__ __launch_bounds__(256) void k_lnstats(const float* __restrict__ y,
                                                 float2* __restrict__ stats){
  int t = blockIdx.x*4 + (threadIdx.x>>6);
  int lane = threadIdx.x & 63;
  const float* p = y + (size_t)t*128;
  float a = p[lane], c = p[lane+64];
  float s = a + c;
  for (int m=32;m>=1;m>>=1) s += __shfl_xor(s, m);
  float mean = s * (1.0f/128.0f);
  float da = a-mean, dc = c-mean;
  float v = da*da + dc*dc;
  for (int m=32;m>=1;m>>=1) v += __shfl_xor(v, m);
  float rstd = rsqrtf(v*(1.0f/128.0f) + 1e-5f);
  if (lane==0) stats[t] = make_float2(mean, rstd);
}

// ---------------- row attention core: q + P per (b,l) ----------------
__global__ __launch_bounds__(256) void k_row_core(
    const float* __restrict__ y, const float2* __restrict__ stats,
    const float* __restrict__ qw, const float* __restrict__ qb,
    const float* __restrict__ kw, const float* __restrict__ kb,
    const float* __restrict__ vw, const float* __restrict__ vb,
    const float* __restrict__ ow,
    const float* __restrict__ gam, const float* __restrict__ bet,
    float* __restrict__ qout, float* __restrict__ Pout)
{
  int g = blockIdx.x;  // b*1024+l
  __shared__ float sh_h[64*129];
  __shared__ float sh_qw[512], sh_kw[512];
  __shared__ float sh_k[256];
  __shared__ float sh_hk[512];
  __shared__ float sh_ktv[128];
  int tid = threadIdx.x;
  for (int i = tid; i < 512; i += 256){ sh_qw[i] = qw[i]; sh_kw[i] = kw[i]; }
  const float* yb = y + (size_t)g*8192;
  for (int idx = tid; idx < 8192; idx += 256){
    int n = idx >> 7, d = idx & 127;
    float2 st = stats[g*64+n];
    sh_h[n*129+d] = (yb[idx]-st.x)*st.y*gam[d] + bet[d];
  }
  __syncthreads();
  int h = tid >> 6, n = tid & 63;
  float qr = qb[h], kr = kb[h];
  {
    const float* qwp = sh_qw + h*128;
    const float* kwp = sh_kw + h*128;
    const float* hp  = sh_h + n*129;
    #pragma unroll 4
    for (int d = 0; d < 128; d++){ float hv = hp[d]; qr += hv*qwp[d]; kr += hv*kwp[d]; }
  }
  qr = qr > 0.f ? qr + 1.f : __expf(qr);   // elu+1
  kr = kr > 0.f ? kr + 1.f : __expf(kr);
  float qs = qr; for (int m=32;m>=1;m>>=1) qs += __shfl_xor(qs, m);
  float ks = kr; for (int m=32;m>=1;m>>=1) ks += __shfl_xor(ks, m);
  float qn = qr * (64.f/qs);
  float kn = kr * (1.f/ks);
  qout[((size_t)g*4 + h)*64 + n] = qn;
  sh_k[h*64+n] = kn;
  __syncthreads();
  // hk[h][d] = sum_n k[h][n]*hnorm[n][d]
  #pragma unroll
  for (int r = 0; r < 2; r++){
    int idx = tid + r*256;
    int hh = idx >> 7, d = idx & 127;
    float acc = 0.f;
    #pragma unroll 4
    for (int nn = 0; nn < 64; nn++) acc += sh_k[hh*64+nn]*sh_h[nn*129+d];
    sh_hk[hh*128+d] = acc;
  }
  __syncthreads();
  // ktv[e] = vb[e] + vw[e,:]·hk[e>>5,:]
  if (tid < 128){
    float acc = vb[tid];
    const float* vr = vw + (size_t)tid*128;
    const float* hp2 = sh_hk + (tid>>5)*128;
    #pragma unroll 4
    for (int d = 0; d < 128; d++) acc += vr[d]*hp2[d];
    sh_ktv[tid] = acc;
  }
  __syncthreads();
  // P[h][e] = sum_{j<32} ow[e, h*32+j]*ktv[h*32+j]
  #pragma unroll
  for (int r = 0; r < 2; r++){
    int idx = tid + r*256;
    int hh = idx >> 7, e = idx & 127;
    float acc = 0.f;
    const float* orow = ow + (size_t)e*128 + hh*32;
    const float* kt = sh_ktv + hh*32;
    #pragma unroll 4
    for (int j = 0; j < 32; j++) acc += orow[j]*kt[j];
    Pout[((size_t)g*4 + hh)*128 + e] = acc;
  }
}

// ---------------- row attention output: y += q·P + ob ----------------
__global__ __launch_bounds__(256) void k_row_out(float* __restrict__ y,
    const float* __restrict__ qbuf, const float* __restrict__ P,
    const float* __restrict__ ob){
  int g = blockIdx.x;
  __shared__ float sh_P[512];
  __shared__ float sh_q[256];
  int tid = threadIdx.x;
  for (int i = tid; i < 512; i += 256) sh_P[i] = P[(size_t)g*512 + i];
  if (tid < 256) sh_q[tid] = qbuf[(size_t)g*256 + tid];
  __syncthreads();
  float4* y4 = (float4*)(y + (size_t)g*8192);
  const float4* P4 = (const float4*)sh_P;
  const float4* ob4 = (const float4*)ob;
  for (int idx = tid; idx < 2048; idx += 256){
    int n = idx >> 5, e4 = idx & 31;
    float4 v = y4[idx];
    float q0 = sh_q[n], q1 = sh_q[64+n], q2 = sh_q[128+n], q3 = sh_q[192+n];
    float4 p0 = P4[e4], p1 = P4[32+e4], p2 = P4[64+e4], p3 = P4[96+e4];
    float4 b4 = ob4[e4];
    v.x += b4.x + q0*p0.x + q1*p1.x + q2*p2.x + q3*p3.x;
    v.y += b4.y + q0*p0.y + q1*p1.y + q2*p2.y + q3*p3.y;
    v.z += b4.z + q0*p0.z + q1*p1.z + q2*p2.z + q3*p3.z;
    v.w += b4.w + q0*p0.w + q1*p1.w + q2*p2.w + q3*p3.w;
    y4[idx] = v;
  }
}

// ---------------- col attention: raw q,k (elu+1), layout [b][n][h][l] ----------------
__global__ __launch_bounds__(256) void k_col_qk(
    const float* __restrict__ y, const float2* __restrict__ stats,
    const float* __restrict__ qw, const float* __restrict__ qb,
    const float* __restrict__ kw, const float* __restrict__ kb,
    const float* __restrict__ gam, const float* __restrict__ bet,
    float* __restrict__ qout, float* __restrict__ kout)
{
  int g = blockIdx.x; int b = g >> 10, l = g & 1023;
  __shared__ float sh_h[64*129];
  __shared__ float sh_qw[512], sh_kw[512];
  int tid = threadIdx.x;
  for (int i = tid; i < 512; i += 256){ sh_qw[i] = qw[i]; sh_kw[i] = kw[i]; }
  const float* yb = y + (size_t)g*8192;
  for (int idx = tid; idx < 8192; idx += 256){
    int n = idx >> 7, d = idx & 127;
    float2 st = stats[g*64+n];
    sh_h[n*129+d] = (yb[idx]-st.x)*st.y*gam[d] + bet[d];
  }
  __syncthreads();
  int h = tid >> 6, n = tid & 63;
  float qr = qb[h], kr = kb[h];
  const float* qwp = sh_qw + h*128;
  const float* kwp = sh_kw + h*128;
  const float* hp  = sh_h + n*129;
  #pragma unroll 4
  for (int d = 0; d < 128; d++){ float hv = hp[d]; qr += hv*qwp[d]; kr += hv*kwp[d]; }
  qr = qr > 0.f ? qr + 1.f : __expf(qr);
  kr = kr > 0.f ? kr + 1.f : __expf(kr);
  size_t o = (((size_t)b*64 + n)*4 + h)*1024 + l;
  qout[o] = qr; kout[o] = kr;
}

// ---------------- col: normalizers per (b,n,h) ----------------
__global__ __launch_bounds__(256) void k_col_sum(const float* __restrict__ qin,
    const float* __restrict__ kin, float* __restrict__ qs, float* __restrict__ ks){
  int gg = blockIdx.x;  // (b*64+n)*4+h
  const float* qp = qin + (size_t)gg*1024;
  const float* kp = kin + (size_t)gg*1024;
  float sq = 0.f, sk = 0.f;
  for (int i = threadIdx.x; i < 1024; i += 256){ sq += qp[i]; sk += kp[i]; }
  for (int m=32;m>=1;m>>=1){ sq += __shfl_xor(sq, m); sk += __shfl_xor(sk, m); }
  __shared__ float aq[4], ak[4];
  int w = threadIdx.x >> 6;
  if ((threadIdx.x & 63) == 0){ aq[w] = sq; ak[w] = sk; }
  __syncthreads();
  if (threadIdx.x == 0){
    float fq = aq[0]+aq[1]+aq[2]+aq[3];
    float fk = ak[0]+ak[1]+ak[2]+ak[3];
    qs[gg] = 1024.f/fq;  ks[gg] = 1.f/fk;
  }
}

// ---------------- col: hk partials over l slices ----------------
__global__ __launch_bounds__(256) void k_col_hk(
    const float* __restrict__ y, const float2* __restrict__ stats,
    const float* __restrict__ kin, const float* __restrict__ ksn,
    const float* __restrict__ gam, const float* __restrict__ bet,
    float* __restrict__ hkp)
{
  int gg = blockIdx.x;                   // ((b*64+n)*8+s)
  int s = gg & 7, n = (gg>>3) & 63, b = gg>>9;
  int tid = threadIdx.x;
  __shared__ float sh_tok[256];
  int h = tid >> 6, d0 = (tid & 63)*2;
  float a0 = 0.f, a1 = 0.f;
  const float* kp = kin + (((size_t)b*64 + n)*4 + h)*1024;
  int li = tid >> 7, d = tid & 127;
  for (int l0 = s*128; l0 < s*128+128; l0 += 2){
    int t = ((b*1024 + l0 + li)*64 + n);
    float2 st = stats[t];
    sh_tok[li*128+d] = (y[(size_t)t*128 + d]-st.x)*st.y*gam[d] + bet[d];
    __syncthreads();
    float k0 = kp[l0], k1 = kp[l0+1];
    float2 t0 = *(const float2*)&sh_tok[d0];
    float2 t1 = *(const float2*)&sh_tok[128+d0];
    a0 += k0*t0.x + k1*t1.x;
    a1 += k0*t0.y + k1*t1.y;
    __syncthreads();
  }
  float kn = ksn[((size_t)b*64 + n)*4 + h];
  size_t base = ((size_t)gg*4 + h)*128;
  hkp[base + d0]   = a0*kn;
  hkp[base + d0+1] = a1*kn;
}

// ---------------- col: reduce hk, ktv, P (qs folded) ----------------
__global__ __launch_bounds__(256) void k_col_ktvP(
    const float* __restrict__ hkp,
    const float* __restrict__ vw, const float* __restrict__ vb,
    const float* __restrict__ ow, const float* __restrict__ qsn,
    float* __restrict__ Pout)
{
  int gg = blockIdx.x;   // b*64+n
  __shared__ float sh_hk[512];
  __shared__ float sh_ktv[128];
  int tid = threadIdx.x;
  #pragma unroll
  for (int r = 0; r < 2; r++){
    int idx = tid + r*256;
    float acc = 0.f;
    #pragma unroll
    for (int s = 0; s < 8; s++) acc += hkp[((size_t)gg*8 + s)*512 + idx];
    sh_hk[idx] = acc;
  }
  __syncthreads();
  if (tid < 128){
    float acc = vb[tid];
    const float* vr = vw + (size_t)tid*128;
    const float* hp2 = sh_hk + (tid>>5)*128;
    #pragma unroll 4
    for (int d = 0; d < 128; d++) acc += vr[d]*hp2[d];
    sh_ktv[tid] = acc;
  }
  __syncthreads();
  #pragma unroll
  for (int r = 0; r < 2; r++){
    int idx = tid + r*256;
    int hh = idx >> 7, e = idx & 127;
    float acc = 0.f;
    const float* orow = ow + (size_t)e*128 + hh*32;
    #pragma unroll 4
    for (int j = 0; j < 32; j++) acc += orow[j]*sh_ktv[hh*32+j];
    Pout[(size_t)gg*512 + hh*128 + e] = acc * qsn[gg*4 + hh];
  }
}

// ---------------- col attention output ----------------
__global__ __launch_bounds__(256) void k_col_out(float* __restrict__ y,
    const float* __restrict__ qin, const float* __restrict__ P,
    const float* __restrict__ ob){
  int gg = blockIdx.x;                 // ((b*64+n)*8+s)
  int s = gg & 7, n = (gg>>3) & 63, b = gg>>9;
  __shared__ float shP[512];
  __shared__ float shq[512];
  int tid = threadIdx.x;
  for (int i = tid; i < 512; i += 256) shP[i] = P[(size_t)(gg>>3)*512 + i];
  for (int i = tid; i < 512; i += 256){
    int h = i >> 7, l = i & 127;
    shq[i] = qin[(((size_t)b*64 + n)*4 + h)*1024 + s*128 + l];
  }
  __syncthreads();
  const float4* P4 = (const float4*)shP;
  const float4* ob4 = (const float4*)ob;
  for (int idx = tid; idx < 4096; idx += 256){
    int ll = idx >> 5, e4 = idx & 31;
    size_t t = ((size_t)b*1024 + s*128 + ll)*64 + n;
    float4* yp = (float4*)(y + t*128) + e4;
    float4 v = *yp;
    float q0 = shq[ll], q1 = shq[128+ll], q2 = shq[256+ll], q3 = shq[384+ll];
    float4 p0 = P4[e4], p1 = P4[32+e4], p2 = P4[64+e4], p3 = P4[96+e4];
    float4 b4 = ob4[e4];
    v.x += b4.x + q0*p0.x + q1*p1.x + q2*p2.x + q3*p3.x;
    v.y += b4.y + q0*p0.y + q1*p1.y + q2*p2.y + q3*p3.y;
    v.z += b4.z + q0*p0.z + q1*p1.z + q2*p2.z + q3*p3.z;
    v.w += b4.w + q0*p0.w + q1*p1.w + q2*p2.w + q3*p3.w;
    *yp = v;
  }
}

// ---------------- fused FFN via bf16 MFMA ----------------
// Per block: 32 tokens. LN fused. GEMM1 swapped (D[e][t] = W1·H^T) so the
// gelu'd output packs into ds_write_b64 of a row-major Hf[t][e]; GEMM2 normal.
__global__ __launch_bounds__(256, 3) void k_ffn(
    float* __restrict__ y,
    const float* __restrict__ gam, const float* __restrict__ bet,
    const ushort* __restrict__ w1b, const float* __restrict__ b1,
    const ushort* __restrict__ w2b, const float* __restrict__ b2)
{
  __shared__ ushort sH[32*136];     // LN'ed tile, bf16, stride 136
  __shared__ ushort sHf[32*520];    // gelu'ed hidden, bf16, stride 520
  int tid = threadIdx.x;
  size_t tb = (size_t)blockIdx.x*32;

  // ---- load + LN + stage H (8 threads per token) ----
  {
    int ttk = tid>>3, s8 = tid&7;
    const float* yr = y + (tb+ttk)*128 + s8*16;
    float4 v0 = *(const float4*)(yr);
    float4 v1 = *(const float4*)(yr+4);
    float4 v2 = *(const float4*)(yr+8);
    float4 v3 = *(const float4*)(yr+12);
    float sum = (v0.x+v0.y+v0.z+v0.w)+(v1.x+v1.y+v1.z+v1.w)
              + (v2.x+v2.y+v2.z+v2.w)+(v3.x+v3.y+v3.z+v3.w);
    sum += __shfl_xor(sum,1); sum += __shfl_xor(sum,2); sum += __shfl_xor(sum,4);
    float mean = sum*(1.0f/128.0f);
    v0.x-=mean; v0.y-=mean; v0.z-=mean; v0.w-=mean;
    v1.x-=mean; v1.y-=mean; v1.z-=mean; v1.w-=mean;
    v2.x-=mean; v2.y-=mean; v2.z-=mean; v2.w-=mean;
    v3.x-=mean; v3.y-=mean; v3.z-=mean; v3.w-=mean;
    float vs = v0.x*v0.x+v0.y*v0.y+v0.z*v0.z+v0.w*v0.w
             + v1.x*v1.x+v1.y*v1.y+v1.z*v1.z+v1.w*v1.w
             + v2.x*v2.x+v2.y*v2.y+v2.z*v2.z+v2.w*v2.w
             + v3.x*v3.x+v3.y*v3.y+v3.z*v3.z+v3.w*v3.w;
    vs += __shfl_xor(vs,1); vs += __shfl_xor(vs,2); vs += __shfl_xor(vs,4);
    float rstd = rsqrtf(vs*(1.0f/128.0f) + 1e-5f);
    const float* gp = gam + s8*16; const float* bp = bet + s8*16;
    float4 g0=*(const float4*)(gp),   g1=*(const float4*)(gp+4);
    float4 g2=*(const float4*)(gp+8), g3=*(const float4*)(gp+12);
    float4 e0=*(const float4*)(bp),   e1=*(const float4*)(bp+4);
    float4 e2=*(const float4*)(bp+8), e3=*(const float4*)(bp+12);
    int4 o0, o1;
    o0.x = (int)pk2(v0.x*rstd*g0.x+e0.x, v0.y*rstd*g0.y+e0.y);
    o0.y = (int)pk2(v0.z*rstd*g0.z+e0.z, v0.w*rstd*g0.w+e0.w);
    o0.z = (int)pk2(v1.x*rstd*g1.x+e1.x, v1.y*rstd*g1.y+e1.y);
    o0.w = (int)pk2(v1.z*rstd*g1.z+e1.z, v1.w*rstd*g1.w+e1.w);
    o1.x = (int)pk2(v2.x*rstd*g2.x+e2.x, v2.y*rstd*g2.y+e2.y);
    o1.y = (int)pk2(v2.z*rstd*g2.z+e2.z, v2.w*rstd*g2.w+e2.w);
    o1.z = (int)pk2(v3.x*rstd*g3.x+e3.x, v3.y*rstd*g3.y+e3.y);
    o1.w = (int)pk2(v3.z*rstd*g3.z+e3.z, v3.w*rstd*g3.w+e3.w);
    *(int4*)&sH[ttk*136 + s8*16]     = o0;
    *(int4*)&sH[ttk*136 + s8*16 + 8] = o1;
  }
  __syncthreads();

  int wid = tid>>6, l = tid&63;
  int lr = l&15, gq = l>>4;
  int wt = wid>>1, we = wid&1;
  int t0 = wt*16;

  // ---- GEMM1 (swapped): D[e][t], two passes of 8 e-tiles ----
  const ushort* w1base = w1b + ((size_t)(we*256 + lr))*128 + gq*8;
  #pragma unroll
  for (int p = 0; p < 2; p++){
    const ushort* wp = w1base + p*128*128;
    f32x4 acc[8] = {};
    #pragma unroll
    for (int ks = 0; ks < 4; ks++){
      bf16x8 bfv = *(const bf16x8*)&sH[(t0+lr)*136 + ks*32 + gq*8];
      #pragma unroll
      for (int i = 0; i < 8; i++){
        bf16x8 afv = *(const bf16x8*)(wp + i*2048 + ks*32);
        acc[i] = __builtin_amdgcn_mfma_f32_16x16x32_bf16(afv, bfv, acc[i], 0, 0, 0);
      }
    }
    int e0base = we*256 + p*128;
    #pragma unroll
    for (int i = 0; i < 8; i++){
      int e0 = e0base + i*16;
      float4 bb = *((const float4*)b1 + (e0>>2) + gq);
      ushort4 pk;
      pk.x = bfr(fast_gelu(acc[i][0] + bb.x));
      pk.y = bfr(fast_gelu(acc[i][1] + bb.y));
      pk.z = bfr(fast_gelu(acc[i][2] + bb.z));
      pk.w = bfr(fast_gelu(acc[i][3] + bb.w));
      *(ushort4*)&sHf[(t0+lr)*520 + e0 + 4*gq] = pk;
    }
  }
  __syncthreads();

  // ---- GEMM2: D[t][d] = Hf · W2^T ----
  int d0 = (wid&1)*64;
  f32x4 acc2[4] = {};
  const ushort* w2base = w2b + (size_t)(d0 + lr)*512 + gq*8;
  #pragma unroll 4
  for (int ks = 0; ks < 16; ks++){
    bf16x8 afv = *(const bf16x8*)&sHf[(t0+lr)*520 + ks*32 + gq*8];
    #pragma unroll
    for (int j = 0; j < 4; j++){
      bf16x8 bfv = *(const bf16x8*)(w2base + j*8192 + ks*32);
      acc2[j] = __builtin_amdgcn_mfma_f32_16x16x32_bf16(afv, bfv, acc2[j], 0, 0, 0);
    }
  }
  // ---- epilogue: residual add ----
  #pragma unroll
  for (int j = 0; j < 4; j++){
    int d = d0 + j*16 + lr;
    float b2v = b2[d];
    #pragma unroll
    for (int r = 0; r < 4; r++){
      size_t off = (tb + t0 + 4*gq + r)*128 + d;
      y[off] += acc2[j][r] + b2v;
    }
  }
}

// ---------------- head: xb = mean over l=1..1023 ----------------
__global__ __launch_bounds__(128) void k_xb(const float* __restrict__ y,
                                            float* __restrict__ xb){
  int gg = blockIdx.x;   // b*64+n
  int b = gg >> 6, n = gg & 63;
  int d = threadIdx.x;
  float acc = 0.f;
  const float* p = y + (((size_t)b*1024 + 1)*64 + n)*128 + d;
  #pragma unroll 4
  for (int l = 1; l < 1024; l++){ acc += *p; p += 64*128; }
  xb[(size_t)gg*128 + d] = acc * (1.0f/1023.0f);
}

// ---------------- head: pairwise distances ----------------
__global__ __launch_bounds__(64) void k_dist(const float* __restrict__ xb,
                                             float* __restrict__ out){
  int p = blockIdx.x;           // b*2016 + pair
  int b = p >= 2016 ? 1 : 0;
  int pr = p - b*2016;
  int i0 = (int)((1.0f + sqrtf(1.0f + 8.0f*(float)pr))*0.5f);
  while (i0*(i0-1)/2 > pr) i0--;
  while ((i0+1)*i0/2 <= pr) i0++;
  int i1 = pr - i0*(i0-1)/2;
  int lane = threadIdx.x;
  const float* xa = xb + ((size_t)b*64 + i0)*128;
  const float* xc = xb + ((size_t)b*64 + i1)*128;
  float d0 = xa[lane]-xc[lane], d1 = xa[lane+64]-xc[lane+64];
  float s = d0*d0 + d1*d1;
  for (int m=32;m>=1;m>>=1) s += __shfl_xor(s, m);
  if (lane == 0) out[p] = sqrtf(s + 1e-8f);
}

extern "C" void kernel_launch(void* const* d_in, const int* in_sizes, int n_in,
                              void* d_out, int out_size, void* d_ws, size_t ws_size,
                              hipStream_t stream){
  const float* x    = (const float*)d_in[0];
  const float* rq_w = (const float*)d_in[1];  const float* rq_b = (const float*)d_in[2];
  const float* rk_w = (const float*)d_in[3];  const float* rk_b = (const float*)d_in[4];
  const float* rv_w = (const float*)d_in[5];  const float* rv_b = (const float*)d_in[6];
  const float* ro_w = (const float*)d_in[7];  const float* ro_b = (const float*)d_in[8];
  const float* cq_w = (const float*)d_in[9];  const float* cq_b = (const float*)d_in[10];
  const float* ck_w = (const float*)d_in[11]; const float* ck_b = (const float*)d_in[12];
  const float* cv_w = (const float*)d_in[13]; const float* cv_b = (const float*)d_in[14];
  const float* co_w = (const float*)d_in[15]; const float* co_b = (const float*)d_in[16];
  const float* lrg  = (const float*)d_in[17]; const float* lrb  = (const float*)d_in[18];
  const float* lcg  = (const float*)d_in[19]; const float* lcb  = (const float*)d_in[20];
  const float* lfg  = (const float*)d_in[21]; const float* lfb  = (const float*)d_in[22];
  const float* f1w  = (const float*)d_in[23]; const float* f1b  = (const float*)d_in[24];
  const float* f2w  = (const float*)d_in[25]; const float* f2b  = (const float*)d_in[26];

  float* ws = (float*)d_ws;
  float*  y   = ws;                           // 16777216
  float2* st  = (float2*)(ws + 16777216);     // 262144 floats
  float*  qb_ = ws + 17039360;                // 524288
  float*  kb_ = ws + 17563648;                // 524288
  float*  Pb  = ws + 18087936;                // 1048576
  float*  hkp = ws + 19136512;                // 524288
  float*  qs  = ws + 19660800;                // 512
  float*  ks  = ws + 19661312;                // 512
  float*  xb  = ws + 19661824;                // 16384
  ushort* w1b = (ushort*)(ws + 19678208);     // 262144 ushorts (131072 floats)
  ushort* w2b = (ushort*)(ws + 19809280);     // 262144 ushorts

  k_transpose<<<dim3(2048), dim3(256), 0, stream>>>(x, y);
  k_cvt<<<dim3(256), dim3(256), 0, stream>>>(f1w, w1b, 65536);
  k_cvt<<<dim3(256), dim3(256), 0, stream>>>(f2w, w2b, 65536);
  for (int l = 0; l < LCNT; l++){
    // row attention
    k_lnstats<<<dim3(32768), dim3(256), 0, stream>>>(y, st);
    k_row_core<<<dim3(2048), dim3(256), 0, stream>>>(y, st,
        rq_w + l*512, rq_b + l*4, rk_w + l*512, rk_b + l*4,
        rv_w + (size_t)l*16384, rv_b + l*128, ro_w + (size_t)l*16384,
        lrg + l*128, lrb + l*128, qb_, Pb);
    k_row_out<<<dim3(2048), dim3(256), 0, stream>>>(y, qb_, Pb, ro_b + l*128);
    // col attention
    k_lnstats<<<dim3(32768), dim3(256), 0, stream>>>(y, st);
    k_col_qk<<<dim3(2048), dim3(256), 0, stream>>>(y, st,
        cq_w + l*512, cq_b + l*4, ck_w + l*512, ck_b + l*4,
        lcg + l*128, lcb + l*128, qb_, kb_);
    k_col_sum<<<dim3(512), dim3(256), 0, stream>>>(qb_, kb_, qs, ks);
    k_col_hk<<<dim3(1024), dim3(256), 0, stream>>>(y, st, kb_, ks,
        lcg + l*128, lcb + l*128, hkp);
    k_col_ktvP<<<dim3(128), dim3(256), 0, stream>>>(hkp,
        cv_w + (size_t)l*16384, cv_b + l*128, co_w + (size_t)l*16384, qs, Pb);
    k_col_out<<<dim3(1024), dim3(256), 0, stream>>>(y, qb_, Pb, co_b + l*128);
    // FFN (LN fused)
    k_ffn<<<dim3(4096), dim3(256), 0, stream>>>(y, lfg + l*128, lfb + l*128,
        w1b + (size_t)l*65536, f1b + l*512, w2b + (size_t)l*65536, f2b + l*128);
  }
  k_xb<<<dim3(128), dim3(128), 0, stream>>>(y, xb);
  k_dist<<<dim3(4032), dim3(64), 0, stream>>>(xb, (float*)d_out);
}

// Round 4
// 1956.772 us; speedup vs baseline: 2.0021x; 1.0509x over previous
//
#include <hip/hip_runtime.h>
#include <math.h>

#define LCNT 4

typedef float f32x4 __attribute__((ext_vector_type(4)));
typedef short bf16x8 __attribute__((ext_vector_type(8)));

__device__ __forceinline__ ushort bfr(float x){
  unsigned int b = __float_as_uint(x);
  return (ushort)((b + 0x7FFFu + ((b>>16)&1u)) >> 16);
}
__device__ __forceinline__ unsigned int pk2(float a, float b){
  return (unsigned int)bfr(a) | ((unsigned int)bfr(b)<<16);
}
__device__ __forceinline__ float fast_gelu(float v){
  float s = fabsf(v) * 0.70710678118f;
  float t = 1.0f/(1.0f + 0.3275911f*s);
  float p = t*(0.254829592f + t*(-0.284496736f + t*(1.421413741f +
            t*(-1.453152027f + t*1.061405429f))));
  float e = 1.0f - p*__expf(-s*s);
  e = copysignf(e, v);
  return 0.5f*v*(1.0f + e);
}

// ---------------- transpose x[B,D,L,N] -> y[B,L,N,D] ----------------
__global__ __launch_bounds__(256) void k_transpose(const float* __restrict__ x,
                                                   float* __restrict__ y){
  int g = blockIdx.x;            // b*1024 + l
  int b = g >> 10, l = g & 1023;
  __shared__ float sh[128*65];
  for (int idx = threadIdx.x; idx < 128*64; idx += 256){
    int d = idx >> 6, n = idx & 63;
    sh[d*65+n] = x[(((size_t)b*128 + d)*1024 + l)*64 + n];
  }
  __syncthreads();
  for (int idx = threadIdx.x; idx < 128*64; idx += 256){
    int n = idx >> 7, d = idx & 127;
    y[((size_t)g*64 + n)*128 + d] = sh[d*65+n];
  }
}

// ---------------- fp32 -> bf16 weight conversion ----------------
__global__ __launch_bounds__(256) void k_cvt(const float* __restrict__ src,
                                             ushort* __restrict__ dst, int n4){
  int i = blockIdx.x*256 + threadIdx.x;
  if (i < n4){
    float4 v = ((const float4*)src)[i];
    ushort4 p; p.x=bfr(v.x); p.y=bfr(v.y); p.z=bfr(v.z); p.w=bfr(v.w);
    ((ushort4*)dst)[i] = p;
  }
}

// ---------------- LN stats (mean, rstd) per token ----------------
__global__ __launch_bounds__(256) void k_lnstats(const float* __restrict__ y,
                                                 float2* __restrict__ stats){
  int t = blockIdx.x*4 + (threadIdx.x>>6);
  int lane = threadIdx.x & 63;
  const float* p = y + (size_t)t*128;
  float a = p[lane], c = p[lane+64];
  float s = a + c;
  for (int m=32;m>=1;m>>=1) s += __shfl_xor(s, m);
  float mean = s * (1.0f/128.0f);
  float da = a-mean, dc = c-mean;
  float v = da*da + dc*dc;
  for (int m=32;m>=1;m>>=1) v += __shfl_xor(v, m);
  float rstd = rsqrtf(v*(1.0f/128.0f) + 1e-5f);
  if (lane==0) stats[t] = make_float2(mean, rstd);
}

// ---------------- row attention core: q + P per (b,l) ----------------
__global__ __launch_bounds__(256) void k_row_core(
    const float* __restrict__ y, const float2* __restrict__ stats,
    const float* __restrict__ qw, const float* __restrict__ qb,
    const float* __restrict__ kw, const float* __restrict__ kb,
    const float* __restrict__ vw, const float* __restrict__ vb,
    const float* __restrict__ ow,
    const float* __restrict__ gam, const float* __restrict__ bet,
    float* __restrict__ qout, float* __restrict__ Pout)
{
  int g = blockIdx.x;  // b*1024+l
  __shared__ float sh_h[64*129];
  __shared__ float sh_qw[512], sh_kw[512];
  __shared__ float sh_k[256];
  __shared__ float sh_hk[512];
  __shared__ float sh_ktv[128];
  int tid = threadIdx.x;
  for (int i = tid; i < 512; i += 256){ sh_qw[i] = qw[i]; sh_kw[i] = kw[i]; }
  const float* yb = y + (size_t)g*8192;
  for (int idx = tid; idx < 8192; idx += 256){
    int n = idx >> 7, d = idx & 127;
    float2 st = stats[g*64+n];
    sh_h[n*129+d] = (yb[idx]-st.x)*st.y*gam[d] + bet[d];
  }
  __syncthreads();
  int h = tid >> 6, n = tid & 63;
  float qr = qb[h], kr = kb[h];
  {
    const float* qwp = sh_qw + h*128;
    const float* kwp = sh_kw + h*128;
    const float* hp  = sh_h + n*129;
    #pragma unroll 4
    for (int d = 0; d < 128; d++){ float hv = hp[d]; qr += hv*qwp[d]; kr += hv*kwp[d]; }
  }
  qr = qr > 0.f ? qr + 1.f : __expf(qr);   // elu+1
  kr = kr > 0.f ? kr + 1.f : __expf(kr);
  float qs = qr; for (int m=32;m>=1;m>>=1) qs += __shfl_xor(qs, m);
  float ks = kr; for (int m=32;m>=1;m>>=1) ks += __shfl_xor(ks, m);
  float qn = qr * (64.f/qs);
  float kn = kr * (1.f/ks);
  qout[((size_t)g*4 + h)*64 + n] = qn;
  sh_k[h*64+n] = kn;
  __syncthreads();
  // hk[h][d] = sum_n k[h][n]*hnorm[n][d]
  #pragma unroll
  for (int r = 0; r < 2; r++){
    int idx = tid + r*256;
    int hh = idx >> 7, d = idx & 127;
    float acc = 0.f;
    #pragma unroll 4
    for (int nn = 0; nn < 64; nn++) acc += sh_k[hh*64+nn]*sh_h[nn*129+d];
    sh_hk[hh*128+d] = acc;
  }
  __syncthreads();
  // ktv[e] = vb[e] + vw[e,:]·hk[e>>5,:]
  if (tid < 128){
    float acc = vb[tid];
    const float* vr = vw + (size_t)tid*128;
    const float* hp2 = sh_hk + (tid>>5)*128;
    #pragma unroll 4
    for (int d = 0; d < 128; d++) acc += vr[d]*hp2[d];
    sh_ktv[tid] = acc;
  }
  __syncthreads();
  // P[h][e] = sum_{j<32} ow[e, h*32+j]*ktv[h*32+j]
  #pragma unroll
  for (int r = 0; r < 2; r++){
    int idx = tid + r*256;
    int hh = idx >> 7, e = idx & 127;
    float acc = 0.f;
    const float* orow = ow + (size_t)e*128 + hh*32;
    const float* kt = sh_ktv + hh*32;
    #pragma unroll 4
    for (int j = 0; j < 32; j++) acc += orow[j]*kt[j];
    Pout[((size_t)g*4 + hh)*128 + e] = acc;
  }
}

// ---------------- row attention output: y += q·P + ob ----------------
__global__ __launch_bounds__(256) void k_row_out(float* __restrict__ y,
    const float* __restrict__ qbuf, const float* __restrict__ P,
    const float* __restrict__ ob){
  int g = blockIdx.x;
  __shared__ float sh_P[512];
  __shared__ float sh_q[256];
  int tid = threadIdx.x;
  for (int i = tid; i < 512; i += 256) sh_P[i] = P[(size_t)g*512 + i];
  if (tid < 256) sh_q[tid] = qbuf[(size_t)g*256 + tid];
  __syncthreads();
  float4* y4 = (float4*)(y + (size_t)g*8192);
  const float4* P4 = (const float4*)sh_P;
  const float4* ob4 = (const float4*)ob;
  for (int idx = tid; idx < 2048; idx += 256){
    int n = idx >> 5, e4 = idx & 31;
    float4 v = y4[idx];
    float q0 = sh_q[n], q1 = sh_q[64+n], q2 = sh_q[128+n], q3 = sh_q[192+n];
    float4 p0 = P4[e4], p1 = P4[32+e4], p2 = P4[64+e4], p3 = P4[96+e4];
    float4 b4 = ob4[e4];
    v.x += b4.x + q0*p0.x + q1*p1.x + q2*p2.x + q3*p3.x;
    v.y += b4.y + q0*p0.y + q1*p1.y + q2*p2.y + q3*p3.y;
    v.z += b4.z + q0*p0.z + q1*p1.z + q2*p2.z + q3*p3.z;
    v.w += b4.w + q0*p0.w + q1*p1.w + q2*p2.w + q3*p3.w;
    y4[idx] = v;
  }
}

// ---------------- col attention: raw q,k (elu+1), layout [b][n][h][l] ----------------
__global__ __launch_bounds__(256) void k_col_qk(
    const float* __restrict__ y, const float2* __restrict__ stats,
    const float* __restrict__ qw, const float* __restrict__ qb,
    const float* __restrict__ kw, const float* __restrict__ kb,
    const float* __restrict__ gam, const float* __restrict__ bet,
    float* __restrict__ qout, float* __restrict__ kout)
{
  int g = blockIdx.x; int b = g >> 10, l = g & 1023;
  __shared__ float sh_h[64*129];
  __shared__ float sh_qw[512], sh_kw[512];
  int tid = threadIdx.x;
  for (int i = tid; i < 512; i += 256){ sh_qw[i] = qw[i]; sh_kw[i] = kw[i]; }
  const float* yb = y + (size_t)g*8192;
  for (int idx = tid; idx < 8192; idx += 256){
    int n = idx >> 7, d = idx & 127;
    float2 st = stats[g*64+n];
    sh_h[n*129+d] = (yb[idx]-st.x)*st.y*gam[d] + bet[d];
  }
  __syncthreads();
  int h = tid >> 6, n = tid & 63;
  float qr = qb[h], kr = kb[h];
  const float* qwp = sh_qw + h*128;
  const float* kwp = sh_kw + h*128;
  const float* hp  = sh_h + n*129;
  #pragma unroll 4
  for (int d = 0; d < 128; d++){ float hv = hp[d]; qr += hv*qwp[d]; kr += hv*kwp[d]; }
  qr = qr > 0.f ? qr + 1.f : __expf(qr);
  kr = kr > 0.f ? kr + 1.f : __expf(kr);
  size_t o = (((size_t)b*64 + n)*4 + h)*1024 + l;
  qout[o] = qr; kout[o] = kr;
}

// ---------------- col: normalizers per (b,n,h) ----------------
__global__ __launch_bounds__(256) void k_col_sum(const float* __restrict__ qin,
    const float* __restrict__ kin, float* __restrict__ qs, float* __restrict__ ks){
  int gg = blockIdx.x;  // (b*64+n)*4+h
  const float* qp = qin + (size_t)gg*1024;
  const float* kp = kin + (size_t)gg*1024;
  float sq = 0.f, sk = 0.f;
  for (int i = threadIdx.x; i < 1024; i += 256){ sq += qp[i]; sk += kp[i]; }
  for (int m=32;m>=1;m>>=1){ sq += __shfl_xor(sq, m); sk += __shfl_xor(sk, m); }
  __shared__ float aq[4], ak[4];
  int w = threadIdx.x >> 6;
  if ((threadIdx.x & 63) == 0){ aq[w] = sq; ak[w] = sk; }
  __syncthreads();
  if (threadIdx.x == 0){
    float fq = aq[0]+aq[1]+aq[2]+aq[3];
    float fk = ak[0]+ak[1]+ak[2]+ak[3];
    qs[gg] = 1024.f/fq;  ks[gg] = 1.f/fk;
  }
}

// ---------------- col: hk partials over l slices ----------------
__global__ __launch_bounds__(256) void k_col_hk(
    const float* __restrict__ y, const float2* __restrict__ stats,
    const float* __restrict__ kin, const float* __restrict__ ksn,
    const float* __restrict__ gam, const float* __restrict__ bet,
    float* __restrict__ hkp)
{
  int gg = blockIdx.x;                   // ((b*64+n)*8+s)
  int s = gg & 7, n = (gg>>3) & 63, b = gg>>9;
  int tid = threadIdx.x;
  __shared__ float sh_tok[256];
  int h = tid >> 6, d0 = (tid & 63)*2;
  float a0 = 0.f, a1 = 0.f;
  const float* kp = kin + (((size_t)b*64 + n)*4 + h)*1024;
  int li = tid >> 7, d = tid & 127;
  for (int l0 = s*128; l0 < s*128+128; l0 += 2){
    int t = ((b*1024 + l0 + li)*64 + n);
    float2 st = stats[t];
    sh_tok[li*128+d] = (y[(size_t)t*128 + d]-st.x)*st.y*gam[d] + bet[d];
    __syncthreads();
    float k0 = kp[l0], k1 = kp[l0+1];
    float2 t0 = *(const float2*)&sh_tok[d0];
    float2 t1 = *(const float2*)&sh_tok[128+d0];
    a0 += k0*t0.x + k1*t1.x;
    a1 += k0*t0.y + k1*t1.y;
    __syncthreads();
  }
  float kn = ksn[((size_t)b*64 + n)*4 + h];
  size_t base = ((size_t)gg*4 + h)*128;
  hkp[base + d0]   = a0*kn;
  hkp[base + d0+1] = a1*kn;
}

// ---------------- col: reduce hk, ktv, P (qs folded) ----------------
__global__ __launch_bounds__(256) void k_col_ktvP(
    const float* __restrict__ hkp,
    const float* __restrict__ vw, const float* __restrict__ vb,
    const float* __restrict__ ow, const float* __restrict__ qsn,
    float* __restrict__ Pout)
{
  int gg = blockIdx.x;   // b*64+n
  __shared__ float sh_hk[512];
  __shared__ float sh_ktv[128];
  int tid = threadIdx.x;
  #pragma unroll
  for (int r = 0; r < 2; r++){
    int idx = tid + r*256;
    float acc = 0.f;
    #pragma unroll
    for (int s = 0; s < 8; s++) acc += hkp[((size_t)gg*8 + s)*512 + idx];
    sh_hk[idx] = acc;
  }
  __syncthreads();
  if (tid < 128){
    float acc = vb[tid];
    const float* vr = vw + (size_t)tid*128;
    const float* hp2 = sh_hk + (tid>>5)*128;
    #pragma unroll 4
    for (int d = 0; d < 128; d++) acc += vr[d]*hp2[d];
    sh_ktv[tid] = acc;
  }
  __syncthreads();
  #pragma unroll
  for (int r = 0; r < 2; r++){
    int idx = tid + r*256;
    int hh = idx >> 7, e = idx & 127;
    float acc = 0.f;
    const float* orow = ow + (size_t)e*128 + hh*32;
    #pragma unroll 4
    for (int j = 0; j < 32; j++) acc += orow[j]*sh_ktv[hh*32+j];
    Pout[(size_t)gg*512 + hh*128 + e] = acc * qsn[gg*4 + hh];
  }
}

// ---------------- col attention output ----------------
__global__ __launch_bounds__(256) void k_col_out(float* __restrict__ y,
    const float* __restrict__ qin, const float* __restrict__ P,
    const float* __restrict__ ob){
  int gg = blockIdx.x;                 // ((b*64+n)*8+s)
  int s = gg & 7, n = (gg>>3) & 63, b = gg>>9;
  __shared__ float shP[512];
  __shared__ float shq[512];
  int tid = threadIdx.x;
  for (int i = tid; i < 512; i += 256) shP[i] = P[(size_t)(gg>>3)*512 + i];
  for (int i = tid; i < 512; i += 256){
    int h = i >> 7, l = i & 127;
    shq[i] = qin[(((size_t)b*64 + n)*4 + h)*1024 + s*128 + l];
  }
  __syncthreads();
  const float4* P4 = (const float4*)shP;
  const float4* ob4 = (const float4*)ob;
  for (int idx = tid; idx < 4096; idx += 256){
    int ll = idx >> 5, e4 = idx & 31;
    size_t t = ((size_t)b*1024 + s*128 + ll)*64 + n;
    float4* yp = (float4*)(y + t*128) + e4;
    float4 v = *yp;
    float q0 = shq[ll], q1 = shq[128+ll], q2 = shq[256+ll], q3 = shq[384+ll];
    float4 p0 = P4[e4], p1 = P4[32+e4], p2 = P4[64+e4], p3 = P4[96+e4];
    float4 b4 = ob4[e4];
    v.x += b4.x + q0*p0.x + q1*p1.x + q2*p2.x + q3*p3.x;
    v.y += b4.y + q0*p0.y + q1*p1.y + q2*p2.y + q3*p3.y;
    v.z += b4.z + q0*p0.z + q1*p1.z + q2*p2.z + q3*p3.z;
    v.w += b4.w + q0*p0.w + q1*p1.w + q2*p2.w + q3*p3.w;
    *yp = v;
  }
}

// ---------------- fused FFN via bf16 MFMA, LDS-staged weights ----------------
// 64 tokens/block, 4 waves, e-chunks of 128. Weights reg-prefetched into a
// single LDS panel (sW): 2 threads/row, 8×int4 (64 ushorts) each.
// GEMM1 swapped D[e][t]; GEMM2 swapped D[d][t] -> float4 residual RMW epilogue.
__global__ __launch_bounds__(256) void k_ffn(
    float* __restrict__ y,
    const float* __restrict__ gam, const float* __restrict__ bet,
    const ushort* __restrict__ w1b, const float* __restrict__ b1,
    const ushort* __restrict__ w2b, const float* __restrict__ b2)
{
  __shared__ ushort sH[64*136];     // LN'ed tile bf16
  __shared__ ushort sHf[64*136];    // gelu'ed hidden chunk bf16
  __shared__ ushort sW[128*136];    // weight panel (w1 chunk / w2 chunk)
  int tid = threadIdx.x;
  size_t tb = (size_t)blockIdx.x*64;

  // ---- load + LN + stage H (4 threads per token, 32 elems each) ----
  {
    int ttk = tid>>2, s4 = tid&3;
    const float* yr = y + (tb+ttk)*128 + s4*32;
    float4 v[8];
    #pragma unroll
    for (int i = 0; i < 8; i++) v[i] = *(const float4*)(yr + i*4);
    float sum = 0.f;
    #pragma unroll
    for (int i = 0; i < 8; i++) sum += v[i].x+v[i].y+v[i].z+v[i].w;
    sum += __shfl_xor(sum,1); sum += __shfl_xor(sum,2);
    float mean = sum*(1.0f/128.0f);
    float vs = 0.f;
    #pragma unroll
    for (int i = 0; i < 8; i++){
      v[i].x-=mean; v[i].y-=mean; v[i].z-=mean; v[i].w-=mean;
      vs += v[i].x*v[i].x+v[i].y*v[i].y+v[i].z*v[i].z+v[i].w*v[i].w;
    }
    vs += __shfl_xor(vs,1); vs += __shfl_xor(vs,2);
    float rstd = rsqrtf(vs*(1.0f/128.0f) + 1e-5f);
    const float* gp = gam + s4*32; const float* bp = bet + s4*32;
    #pragma unroll
    for (int i = 0; i < 4; i++){
      float4 ga = *(const float4*)(gp + i*8),     gb = *(const float4*)(gp + i*8 + 4);
      float4 ba = *(const float4*)(bp + i*8),     bb = *(const float4*)(bp + i*8 + 4);
      float4 va = v[i*2], vb2 = v[i*2+1];
      int4 o;
      o.x = (int)pk2(va.x*rstd*ga.x+ba.x,  va.y*rstd*ga.y+ba.y);
      o.y = (int)pk2(va.z*rstd*ga.z+ba.z,  va.w*rstd*ga.w+ba.w);
      o.z = (int)pk2(vb2.x*rstd*gb.x+bb.x, vb2.y*rstd*gb.y+bb.y);
      o.w = (int)pk2(vb2.z*rstd*gb.z+bb.z, vb2.w*rstd*gb.w+bb.w);
      *(int4*)&sH[ttk*136 + s4*32 + i*8] = o;
    }
  }

  int wid = tid>>6, l = tid&63;
  int lr = l&15, gq = l>>4;
  int t0 = wid*16;
  int srow = tid>>1, shalf = (tid&1)*64;   // 2 threads/row, 64 ushorts each
  ushort* swp = sW + srow*136 + shalf;

  f32x4 acc2[8] = {};
  int4 pf[8];

  // prefetch w1 chunk 0
  {
    const ushort* g = w1b + srow*128 + shalf;
    #pragma unroll
    for (int j = 0; j < 8; j++) pf[j] = *(const int4*)(g + j*8);
  }

  for (int c = 0; c < 4; c++){
    // ---- stage w1 chunk c, prefetch w2 chunk c ----
    __syncthreads();                 // previous GEMM2 (or LN, c==0) done
    #pragma unroll
    for (int j = 0; j < 8; j++) *(int4*)(swp + j*8) = pf[j];
    {
      const ushort* g = w2b + srow*512 + c*128 + shalf;
      #pragma unroll
      for (int j = 0; j < 8; j++) pf[j] = *(const int4*)(g + j*8);
    }
    __syncthreads();                 // sW = w1 chunk ready

    // ---- GEMM1 (swapped): D[e][t] for this chunk ----
    f32x4 acc1[8] = {};
    #pragma unroll
    for (int ks = 0; ks < 4; ks++){
      bf16x8 bfv = *(const bf16x8*)&sH[(t0+lr)*136 + ks*32 + gq*8];
      #pragma unroll
      for (int i = 0; i < 8; i++){
        bf16x8 afv = *(const bf16x8*)&sW[(i*16+lr)*136 + ks*32 + gq*8];
        acc1[i] = __builtin_amdgcn_mfma_f32_16x16x32_bf16(afv, bfv, acc1[i], 0, 0, 0);
      }
    }
    // ---- gelu -> sHf (wave-private rows) ----
    #pragma unroll
    for (int i = 0; i < 8; i++){
      float4 bb = *(const float4*)&b1[c*128 + i*16 + gq*4];
      ushort4 pk;
      pk.x = bfr(fast_gelu(acc1[i][0] + bb.x));
      pk.y = bfr(fast_gelu(acc1[i][1] + bb.y));
      pk.z = bfr(fast_gelu(acc1[i][2] + bb.z));
      pk.w = bfr(fast_gelu(acc1[i][3] + bb.w));
      *(ushort4*)&sHf[(t0+lr)*136 + i*16 + gq*4] = pk;
    }

    // ---- stage w2 chunk c, prefetch w1 chunk c+1 ----
    __syncthreads();                 // all waves done reading sW (GEMM1)
    #pragma unroll
    for (int j = 0; j < 8; j++) *(int4*)(swp + j*8) = pf[j];
    if (c < 3){
      const ushort* g = w1b + (c+1)*16384 + srow*128 + shalf;
      #pragma unroll
      for (int j = 0; j < 8; j++) pf[j] = *(const int4*)(g + j*8);
    }
    __syncthreads();                 // sW = w2 chunk ready

    // ---- GEMM2 (swapped): acc2[d][t] += W2chunk · Hf^T ----
    #pragma unroll
    for (int ks = 0; ks < 4; ks++){
      bf16x8 bfv = *(const bf16x8*)&sHf[(t0+lr)*136 + ks*32 + gq*8];
      #pragma unroll
      for (int j = 0; j < 8; j++){
        bf16x8 afv = *(const bf16x8*)&sW[(j*16+lr)*136 + ks*32 + gq*8];
        acc2[j] = __builtin_amdgcn_mfma_f32_16x16x32_bf16(afv, bfv, acc2[j], 0, 0, 0);
      }
    }
  }

  // ---- epilogue: float4 residual RMW ----
  #pragma unroll
  for (int j = 0; j < 8; j++){
    float4* yp = (float4*)(y + (tb + t0 + lr)*128 + j*16 + gq*4);
    float4 bb = *(const float4*)&b2[j*16 + gq*4];
    float4 v = *yp;
    v.x += acc2[j][0] + bb.x;
    v.y += acc2[j][1] + bb.y;
    v.z += acc2[j][2] + bb.z;
    v.w += acc2[j][3] + bb.w;
    *yp = v;
  }
}

// ---------------- head: xb = mean over l=1..1023 ----------------
__global__ __launch_bounds__(128) void k_xb(const float* __restrict__ y,
                                            float* __restrict__ xb){
  int gg = blockIdx.x;   // b*64+n
  int b = gg >> 6, n = gg & 63;
  int d = threadIdx.x;
  float acc = 0.f;
  const float* p = y + (((size_t)b*1024 + 1)*64 + n)*128 + d;
  #pragma unroll 4
  for (int l = 1; l < 1024; l++){ acc += *p; p += 64*128; }
  xb[(size_t)gg*128 + d] = acc * (1.0f/1023.0f);
}

// ---------------- head: pairwise distances ----------------
__global__ __launch_bounds__(64) void k_dist(const float* __restrict__ xb,
                                             float* __restrict__ out){
  int p = blockIdx.x;           // b*2016 + pair
  int b = p >= 2016 ? 1 : 0;
  int pr = p - b*2016;
  int i0 = (int)((1.0f + sqrtf(1.0f + 8.0f*(float)pr))*0.5f);
  while (i0*(i0-1)/2 > pr) i0--;
  while ((i0+1)*i0/2 <= pr) i0++;
  int i1 = pr - i0*(i0-1)/2;
  int lane = threadIdx.x;
  const float* xa = xb + ((size_t)b*64 + i0)*128;
  const float* xc = xb + ((size_t)b*64 + i1)*128;
  float d0 = xa[lane]-xc[lane], d1 = xa[lane+64]-xc[lane+64];
  float s = d0*d0 + d1*d1;
  for (int m=32;m>=1;m>>=1) s += __shfl_xor(s, m);
  if (lane == 0) out[p] = sqrtf(s + 1e-8f);
}

extern "C" void kernel_launch(void* const* d_in, const int* in_sizes, int n_in,
                              void* d_out, int out_size, void* d_ws, size_t ws_size,
                              hipStream_t stream){
  const float* x    = (const float*)d_in[0];
  const float* rq_w = (const float*)d_in[1];  const float* rq_b = (const float*)d_in[2];
  const float* rk_w = (const float*)d_in[3];  const float* rk_b = (const float*)d_in[4];
  const float* rv_w = (const float*)d_in[5];  const float* rv_b = (const float*)d_in[6];
  const float* ro_w = (const float*)d_in[7];  const float* ro_b = (const float*)d_in[8];
  const float* cq_w = (const float*)d_in[9];  const float* cq_b = (const float*)d_in[10];
  const float* ck_w = (const float*)d_in[11]; const float* ck_b = (const float*)d_in[12];
  const float* cv_w = (const float*)d_in[13]; const float* cv_b = (const float*)d_in[14];
  const float* co_w = (const float*)d_in[15]; const float* co_b = (const float*)d_in[16];
  const float* lrg  = (const float*)d_in[17]; const float* lrb  = (const float*)d_in[18];
  const float* lcg  = (const float*)d_in[19]; const float* lcb  = (const float*)d_in[20];
  const float* lfg  = (const float*)d_in[21]; const float* lfb  = (const float*)d_in[22];
  const float* f1w  = (const float*)d_in[23]; const float* f1b  = (const float*)d_in[24];
  const float* f2w  = (const float*)d_in[25]; const float* f2b  = (const float*)d_in[26];

  float* ws = (float*)d_ws;
  float*  y   = ws;                           // 16777216
  float2* st  = (float2*)(ws + 16777216);     // 262144 floats
  float*  qb_ = ws + 17039360;                // 524288
  float*  kb_ = ws + 17563648;                // 524288
  float*  Pb  = ws + 18087936;                // 1048576
  float*  hkp = ws + 19136512;                // 524288
  float*  qs  = ws + 19660800;                // 512
  float*  ks  = ws + 19661312;                // 512
  float*  xb  = ws + 19661824;                // 16384
  ushort* w1b = (ushort*)(ws + 19678208);     // 262144 ushorts (131072 floats)
  ushort* w2b = (ushort*)(ws + 19809280);     // 262144 ushorts

  k_transpose<<<dim3(2048), dim3(256), 0, stream>>>(x, y);
  k_cvt<<<dim3(256), dim3(256), 0, stream>>>(f1w, w1b, 65536);
  k_cvt<<<dim3(256), dim3(256), 0, stream>>>(f2w, w2b, 65536);
  for (int l = 0; l < LCNT; l++){
    // row attention
    k_lnstats<<<dim3(32768), dim3(256), 0, stream>>>(y, st);
    k_row_core<<<dim3(2048), dim3(256), 0, stream>>>(y, st,
        rq_w + l*512, rq_b + l*4, rk_w + l*512, rk_b + l*4,
        rv_w + (size_t)l*16384, rv_b + l*128, ro_w + (size_t)l*16384,
        lrg + l*128, lrb + l*128, qb_, Pb);
    k_row_out<<<dim3(2048), dim3(256), 0, stream>>>(y, qb_, Pb, ro_b + l*128);
    // col attention
    k_lnstats<<<dim3(32768), dim3(256), 0, stream>>>(y, st);
    k_col_qk<<<dim3(2048), dim3(256), 0, stream>>>(y, st,
        cq_w + l*512, cq_b + l*4, ck_w + l*512, ck_b + l*4,
        lcg + l*128, lcb + l*128, qb_, kb_);
    k_col_sum<<<dim3(512), dim3(256), 0, stream>>>(qb_, kb_, qs, ks);
    k_col_hk<<<dim3(1024), dim3(256), 0, stream>>>(y, st, kb_, ks,
        lcg + l*128, lcb + l*128, hkp);
    k_col_ktvP<<<dim3(128), dim3(256), 0, stream>>>(hkp,
        cv_w + (size_t)l*16384, cv_b + l*128, co_w + (size_t)l*16384, qs, Pb);
    k_col_out<<<dim3(1024), dim3(256), 0, stream>>>(y, qb_, Pb, co_b + l*128);
    // FFN (LN fused, LDS-staged weights)
    k_ffn<<<dim3(2048), dim3(256), 0, stream>>>(y, lfg + l*128, lfb + l*128,
        w1b + (size_t)l*65536, f1b + l*512, w2b + (size_t)l*65536, f2b + l*128);
  }
  k_xb<<<dim3(128), dim3(128), 0, stream>>>(y, xb);
  k_dist<<<dim3(4032), dim3(64), 0, stream>>>(xb, (float*)d_out);
}

// Round 5
// 1540.047 us; speedup vs baseline: 2.5438x; 1.2706x over previous
//
#include <hip/hip_runtime.h>
#include <math.h>

#define LCNT 4

typedef float f32x4 __attribute__((ext_vector_type(4)));
typedef short bf16x8 __attribute__((ext_vector_type(8)));
typedef unsigned int u32;

__device__ __forceinline__ ushort bfr(float x){
  unsigned int b = __float_as_uint(x);
  return (ushort)((b + 0x7FFFu + ((b>>16)&1u)) >> 16);
}
__device__ __forceinline__ unsigned int pk2(float a, float b){
  return (unsigned int)bfr(a) | ((unsigned int)bfr(b)<<16);
}
__device__ __forceinline__ float fast_gelu(float v){
  float s = fabsf(v) * 0.70710678118f;
  float t = 1.0f/(1.0f + 0.3275911f*s);
  float p = t*(0.254829592f + t*(-0.284496736f + t*(1.421413741f +
            t*(-1.453152027f + t*1.061405429f))));
  float e = 1.0f - p*__expf(-s*s);
  e = copysignf(e, v);
  return 0.5f*v*(1.0f + e);
}
// async global->LDS, 16B per lane; LDS dest = wave-uniform base + lane*16
__device__ __forceinline__ void gl_lds16(const void* g, void* l){
  __builtin_amdgcn_global_load_lds(
      (const __attribute__((address_space(1))) u32*)g,
      (__attribute__((address_space(3))) u32*)l, 16, 0, 0);
}

// ---------------- transpose x[B,D,L,N] -> y[B,L,N,D] ----------------
__global__ __launch_bounds__(256) void k_transpose(const float* __restrict__ x,
                                                   float* __restrict__ y){
  int g = blockIdx.x;            // b*1024 + l
  int b = g >> 10, l = g & 1023;
  __shared__ float sh[128*65];
  for (int idx = threadIdx.x; idx < 128*64; idx += 256){
    int d = idx >> 6, n = idx & 63;
    sh[d*65+n] = x[(((size_t)b*128 + d)*1024 + l)*64 + n];
  }
  __syncthreads();
  for (int idx = threadIdx.x; idx < 128*64; idx += 256){
    int n = idx >> 7, d = idx & 127;
    y[((size_t)g*64 + n)*128 + d] = sh[d*65+n];
  }
}

// ---------------- fp32 -> bf16 weight conversion ----------------
__global__ __launch_bounds__(256) void k_cvt(const float* __restrict__ src,
                                             ushort* __restrict__ dst, int n4){
  int i = blockIdx.x*256 + threadIdx.x;
  if (i < n4){
    float4 v = ((const float4*)src)[i];
    ushort4 p; p.x=bfr(v.x); p.y=bfr(v.y); p.z=bfr(v.z); p.w=bfr(v.w);
    ((ushort4*)dst)[i] = p;
  }
}

// ---------------- LN stats (mean, rstd) per token ----------------
__global__ __launch_bounds__(256) void k_lnstats(const float* __restrict__ y,
                                                 float2* __restrict__ stats){
  int t = blockIdx.x*4 + (threadIdx.x>>6);
  int lane = threadIdx.x & 63;
  const float* p = y + (size_t)t*128;
  float a = p[lane], c = p[lane+64];
  float s = a + c;
  for (int m=32;m>=1;m>>=1) s += __shfl_xor(s, m);
  float mean = s * (1.0f/128.0f);
  float da = a-mean, dc = c-mean;
  float v = da*da + dc*dc;
  for (int m=32;m>=1;m>>=1) v += __shfl_xor(v, m);
  float rstd = rsqrtf(v*(1.0f/128.0f) + 1e-5f);
  if (lane==0) stats[t] = make_float2(mean, rstd);
}

// ---------------- row attention core: q + P per (b,l) ----------------
__global__ __launch_bounds__(256) void k_row_core(
    const float* __restrict__ y, const float2* __restrict__ stats,
    const float* __restrict__ qw, const float* __restrict__ qb,
    const float* __restrict__ kw, const float* __restrict__ kb,
    const float* __restrict__ vw, const float* __restrict__ vb,
    const float* __restrict__ ow,
    const float* __restrict__ gam, const float* __restrict__ bet,
    float* __restrict__ qout, float* __restrict__ Pout)
{
  int g = blockIdx.x;  // b*1024+l
  __shared__ float sh_h[64*129];
  __shared__ float sh_qw[512], sh_kw[512];
  __shared__ float sh_k[256];
  __shared__ float sh_hk[512];
  __shared__ float sh_ktv[128];
  int tid = threadIdx.x;
  for (int i = tid; i < 512; i += 256){ sh_qw[i] = qw[i]; sh_kw[i] = kw[i]; }
  const float* yb = y + (size_t)g*8192;
  for (int idx = tid; idx < 8192; idx += 256){
    int n = idx >> 7, d = idx & 127;
    float2 st = stats[g*64+n];
    sh_h[n*129+d] = (yb[idx]-st.x)*st.y*gam[d] + bet[d];
  }
  __syncthreads();
  int h = tid >> 6, n = tid & 63;
  float qr = qb[h], kr = kb[h];
  {
    const float* qwp = sh_qw + h*128;
    const float* kwp = sh_kw + h*128;
    const float* hp  = sh_h + n*129;
    #pragma unroll 4
    for (int d = 0; d < 128; d++){ float hv = hp[d]; qr += hv*qwp[d]; kr += hv*kwp[d]; }
  }
  qr = qr > 0.f ? qr + 1.f : __expf(qr);   // elu+1
  kr = kr > 0.f ? kr + 1.f : __expf(kr);
  float qs = qr; for (int m=32;m>=1;m>>=1) qs += __shfl_xor(qs, m);
  float ks = kr; for (int m=32;m>=1;m>>=1) ks += __shfl_xor(ks, m);
  float qn = qr * (64.f/qs);
  float kn = kr * (1.f/ks);
  qout[((size_t)g*4 + h)*64 + n] = qn;
  sh_k[h*64+n] = kn;
  __syncthreads();
  // hk[h][d] = sum_n k[h][n]*hnorm[n][d]
  #pragma unroll
  for (int r = 0; r < 2; r++){
    int idx = tid + r*256;
    int hh = idx >> 7, d = idx & 127;
    float acc = 0.f;
    #pragma unroll 4
    for (int nn = 0; nn < 64; nn++) acc += sh_k[hh*64+nn]*sh_h[nn*129+d];
    sh_hk[hh*128+d] = acc;
  }
  __syncthreads();
  // ktv[e] = vb[e] + vw[e,:]·hk[e>>5,:]
  if (tid < 128){
    float acc = vb[tid];
    const float* vr = vw + (size_t)tid*128;
    const float* hp2 = sh_hk + (tid>>5)*128;
    #pragma unroll 4
    for (int d = 0; d < 128; d++) acc += vr[d]*hp2[d];
    sh_ktv[tid] = acc;
  }
  __syncthreads();
  // P[h][e] = sum_{j<32} ow[e, h*32+j]*ktv[h*32+j]
  #pragma unroll
  for (int r = 0; r < 2; r++){
    int idx = tid + r*256;
    int hh = idx >> 7, e = idx & 127;
    float acc = 0.f;
    const float* orow = ow + (size_t)e*128 + hh*32;
    const float* kt = sh_ktv + hh*32;
    #pragma unroll 4
    for (int j = 0; j < 32; j++) acc += orow[j]*kt[j];
    Pout[((size_t)g*4 + hh)*128 + e] = acc;
  }
}

// ---------------- row attention output: y += q·P + ob ----------------
__global__ __launch_bounds__(256) void k_row_out(float* __restrict__ y,
    const float* __restrict__ qbuf, const float* __restrict__ P,
    const float* __restrict__ ob){
  int g = blockIdx.x;
  __shared__ float sh_P[512];
  __shared__ float sh_q[256];
  int tid = threadIdx.x;
  for (int i = tid; i < 512; i += 256) sh_P[i] = P[(size_t)g*512 + i];
  if (tid < 256) sh_q[tid] = qbuf[(size_t)g*256 + tid];
  __syncthreads();
  float4* y4 = (float4*)(y + (size_t)g*8192);
  const float4* P4 = (const float4*)sh_P;
  const float4* ob4 = (const float4*)ob;
  for (int idx = tid; idx < 2048; idx += 256){
    int n = idx >> 5, e4 = idx & 31;
    float4 v = y4[idx];
    float q0 = sh_q[n], q1 = sh_q[64+n], q2 = sh_q[128+n], q3 = sh_q[192+n];
    float4 p0 = P4[e4], p1 = P4[32+e4], p2 = P4[64+e4], p3 = P4[96+e4];
    float4 b4 = ob4[e4];
    v.x += b4.x + q0*p0.x + q1*p1.x + q2*p2.x + q3*p3.x;
    v.y += b4.y + q0*p0.y + q1*p1.y + q2*p2.y + q3*p3.y;
    v.z += b4.z + q0*p0.z + q1*p1.z + q2*p2.z + q3*p3.z;
    v.w += b4.w + q0*p0.w + q1*p1.w + q2*p2.w + q3*p3.w;
    y4[idx] = v;
  }
}

// ---------------- col attention: raw q,k (elu+1), layout [b][n][h][l] ----------------
__global__ __launch_bounds__(256) void k_col_qk(
    const float* __restrict__ y, const float2* __restrict__ stats,
    const float* __restrict__ qw, const float* __restrict__ qb,
    const float* __restrict__ kw, const float* __restrict__ kb,
    const float* __restrict__ gam, const float* __restrict__ bet,
    float* __restrict__ qout, float* __restrict__ kout)
{
  int g = blockIdx.x; int b = g >> 10, l = g & 1023;
  __shared__ float sh_h[64*129];
  __shared__ float sh_qw[512], sh_kw[512];
  int tid = threadIdx.x;
  for (int i = tid; i < 512; i += 256){ sh_qw[i] = qw[i]; sh_kw[i] = kw[i]; }
  const float* yb = y + (size_t)g*8192;
  for (int idx = tid; idx < 8192; idx += 256){
    int n = idx >> 7, d = idx & 127;
    float2 st = stats[g*64+n];
    sh_h[n*129+d] = (yb[idx]-st.x)*st.y*gam[d] + bet[d];
  }
  __syncthreads();
  int h = tid >> 6, n = tid & 63;
  float qr = qb[h], kr = kb[h];
  const float* qwp = sh_qw + h*128;
  const float* kwp = sh_kw + h*128;
  const float* hp  = sh_h + n*129;
  #pragma unroll 4
  for (int d = 0; d < 128; d++){ float hv = hp[d]; qr += hv*qwp[d]; kr += hv*kwp[d]; }
  qr = qr > 0.f ? qr + 1.f : __expf(qr);
  kr = kr > 0.f ? kr + 1.f : __expf(kr);
  size_t o = (((size_t)b*64 + n)*4 + h)*1024 + l;
  qout[o] = qr; kout[o] = kr;
}

// ---------------- col: normalizers per (b,n,h) ----------------
__global__ __launch_bounds__(256) void k_col_sum(const float* __restrict__ qin,
    const float* __restrict__ kin, float* __restrict__ qs, float* __restrict__ ks){
  int gg = blockIdx.x;  // (b*64+n)*4+h
  const float* qp = qin + (size_t)gg*1024;
  const float* kp = kin + (size_t)gg*1024;
  float sq = 0.f, sk = 0.f;
  for (int i = threadIdx.x; i < 1024; i += 256){ sq += qp[i]; sk += kp[i]; }
  for (int m=32;m>=1;m>>=1){ sq += __shfl_xor(sq, m); sk += __shfl_xor(sk, m); }
  __shared__ float aq[4], ak[4];
  int w = threadIdx.x >> 6;
  if ((threadIdx.x & 63) == 0){ aq[w] = sq; ak[w] = sk; }
  __syncthreads();
  if (threadIdx.x == 0){
    float fq = aq[0]+aq[1]+aq[2]+aq[3];
    float fk = ak[0]+ak[1]+ak[2]+ak[3];
    qs[gg] = 1024.f/fq;  ks[gg] = 1.f/fk;
  }
}

// ---------------- col: hk partials over l slices ----------------
__global__ __launch_bounds__(256) void k_col_hk(
    const float* __restrict__ y, const float2* __restrict__ stats,
    const float* __restrict__ kin, const float* __restrict__ ksn,
    const float* __restrict__ gam, const float* __restrict__ bet,
    float* __restrict__ hkp)
{
  int gg = blockIdx.x;                   // ((b*64+n)*8+s)
  int s = gg & 7, n = (gg>>3) & 63, b = gg>>9;
  int tid = threadIdx.x;
  __shared__ float sh_tok[256];
  int h = tid >> 6, d0 = (tid & 63)*2;
  float a0 = 0.f, a1 = 0.f;
  const float* kp = kin + (((size_t)b*64 + n)*4 + h)*1024;
  int li = tid >> 7, d = tid & 127;
  for (int l0 = s*128; l0 < s*128+128; l0 += 2){
    int t = ((b*1024 + l0 + li)*64 + n);
    float2 st = stats[t];
    sh_tok[li*128+d] = (y[(size_t)t*128 + d]-st.x)*st.y*gam[d] + bet[d];
    __syncthreads();
    float k0 = kp[l0], k1 = kp[l0+1];
    float2 t0 = *(const float2*)&sh_tok[d0];
    float2 t1 = *(const float2*)&sh_tok[128+d0];
    a0 += k0*t0.x + k1*t1.x;
    a1 += k0*t0.y + k1*t1.y;
    __syncthreads();
  }
  float kn = ksn[((size_t)b*64 + n)*4 + h];
  size_t base = ((size_t)gg*4 + h)*128;
  hkp[base + d0]   = a0*kn;
  hkp[base + d0+1] = a1*kn;
}

// ---------------- col: reduce hk, ktv, P (qs folded) ----------------
__global__ __launch_bounds__(256) void k_col_ktvP(
    const float* __restrict__ hkp,
    const float* __restrict__ vw, const float* __restrict__ vb,
    const float* __restrict__ ow, const float* __restrict__ qsn,
    float* __restrict__ Pout)
{
  int gg = blockIdx.x;   // b*64+n
  __shared__ float sh_hk[512];
  __shared__ float sh_ktv[128];
  int tid = threadIdx.x;
  #pragma unroll
  for (int r = 0; r < 2; r++){
    int idx = tid + r*256;
    float acc = 0.f;
    #pragma unroll
    for (int s = 0; s < 8; s++) acc += hkp[((size_t)gg*8 + s)*512 + idx];
    sh_hk[idx] = acc;
  }
  __syncthreads();
  if (tid < 128){
    float acc = vb[tid];
    const float* vr = vw + (size_t)tid*128;
    const float* hp2 = sh_hk + (tid>>5)*128;
    #pragma unroll 4
    for (int d = 0; d < 128; d++) acc += vr[d]*hp2[d];
    sh_ktv[tid] = acc;
  }
  __syncthreads();
  #pragma unroll
  for (int r = 0; r < 2; r++){
    int idx = tid + r*256;
    int hh = idx >> 7, e = idx & 127;
    float acc = 0.f;
    const float* orow = ow + (size_t)e*128 + hh*32;
    #pragma unroll 4
    for (int j = 0; j < 32; j++) acc += orow[j]*sh_ktv[hh*32+j];
    Pout[(size_t)gg*512 + hh*128 + e] = acc * qsn[gg*4 + hh];
  }
}

// ---------------- col attention output ----------------
__global__ __launch_bounds__(256) void k_col_out(float* __restrict__ y,
    const float* __restrict__ qin, const float* __restrict__ P,
    const float* __restrict__ ob){
  int gg = blockIdx.x;                 // ((b*64+n)*8+s)
  int s = gg & 7, n = (gg>>3) & 63, b = gg>>9;
  __shared__ float shP[512];
  __shared__ float shq[512];
  int tid = threadIdx.x;
  for (int i = tid; i < 512; i += 256) shP[i] = P[(size_t)(gg>>3)*512 + i];
  for (int i = tid; i < 512; i += 256){
    int h = i >> 7, l = i & 127;
    shq[i] = qin[(((size_t)b*64 + n)*4 + h)*1024 + s*128 + l];
  }
  __syncthreads();
  const float4* P4 = (const float4*)shP;
  const float4* ob4 = (const float4*)ob;
  for (int idx = tid; idx < 4096; idx += 256){
    int ll = idx >> 5, e4 = idx & 31;
    size_t t = ((size_t)b*1024 + s*128 + ll)*64 + n;
    float4* yp = (float4*)(y + t*128) + e4;
    float4 v = *yp;
    float q0 = shq[ll], q1 = shq[128+ll], q2 = shq[256+ll], q3 = shq[384+ll];
    float4 p0 = P4[e4], p1 = P4[32+e4], p2 = P4[64+e4], p3 = P4[96+e4];
    float4 b4 = ob4[e4];
    v.x += b4.x + q0*p0.x + q1*p1.x + q2*p2.x + q3*p3.x;
    v.y += b4.y + q0*p0.y + q1*p1.y + q2*p2.y + q3*p3.y;
    v.z += b4.z + q0*p0.z + q1*p1.z + q2*p2.z + q3*p3.z;
    v.w += b4.w + q0*p0.w + q1*p1.w + q2*p2.w + q3*p3.w;
    *yp = v;
  }
}

// ---------------- fused FFN via bf16 MFMA, global_load_lds weights ----------------
// 64 tokens/block, 4 waves. Weight panel sW is LINEAR [128][128] ushorts,
// staged via global_load_lds (zero staging VGPRs). Bank conflicts fixed by
// pre-swizzling the global source granule (g ^= row&7) and XOR-ing the
// ds_read address the same way (both-sides swizzle).
// GEMM1 swapped D[e][t]; GEMM2 swapped D[d][t] -> float4 residual RMW.
__global__ __launch_bounds__(256) void k_ffn(
    float* __restrict__ y,
    const float* __restrict__ gam, const float* __restrict__ bet,
    const ushort* __restrict__ w1b, const float* __restrict__ b1,
    const ushort* __restrict__ w2b, const float* __restrict__ b2)
{
  __shared__ ushort sW[128*128];    // weight panel, linear
  __shared__ ushort sH[64*136];     // LN'ed tile bf16 (padded)
  __shared__ ushort sHf[64*136];    // gelu'ed hidden chunk bf16 (padded)
  int tid = threadIdx.x;
  size_t tb = (size_t)blockIdx.x*64;

  int wid = tid>>6, l = tid&63;
  int lr = l&15, gq = l>>4;
  int t0 = wid*16;
  int rin = l>>4;                  // row within 4-row stage issue
  int gin = l&15;                  // 16B granule within row

  // ---- issue w1 chunk-0 stage (overlaps LN below) ----
  #pragma unroll
  for (int i = 0; i < 8; i++){
    int rr = wid*32 + i*4 + rin;
    gl_lds16(w1b + (size_t)rr*128 + ((gin ^ (rr&7))<<3), &sW[(wid*32 + i*4)*128]);
  }

  // ---- load + LN + stage H (4 threads per token, 32 elems each) ----
  {
    int ttk = tid>>2, s4 = tid&3;
    const float* yr = y + (tb+ttk)*128 + s4*32;
    float4 v[8];
    #pragma unroll
    for (int i = 0; i < 8; i++) v[i] = *(const float4*)(yr + i*4);
    float sum = 0.f;
    #pragma unroll
    for (int i = 0; i < 8; i++) sum += v[i].x+v[i].y+v[i].z+v[i].w;
    sum += __shfl_xor(sum,1); sum += __shfl_xor(sum,2);
    float mean = sum*(1.0f/128.0f);
    float vs = 0.f;
    #pragma unroll
    for (int i = 0; i < 8; i++){
      v[i].x-=mean; v[i].y-=mean; v[i].z-=mean; v[i].w-=mean;
      vs += v[i].x*v[i].x+v[i].y*v[i].y+v[i].z*v[i].z+v[i].w*v[i].w;
    }
    vs += __shfl_xor(vs,1); vs += __shfl_xor(vs,2);
    float rstd = rsqrtf(vs*(1.0f/128.0f) + 1e-5f);
    const float* gp = gam + s4*32; const float* bp = bet + s4*32;
    #pragma unroll
    for (int i = 0; i < 4; i++){
      float4 ga = *(const float4*)(gp + i*8),     gb = *(const float4*)(gp + i*8 + 4);
      float4 ba = *(const float4*)(bp + i*8),     bb = *(const float4*)(bp + i*8 + 4);
      float4 va = v[i*2], vb2 = v[i*2+1];
      int4 o;
      o.x = (int)pk2(va.x*rstd*ga.x+ba.x,  va.y*rstd*ga.y+ba.y);
      o.y = (int)pk2(va.z*rstd*ga.z+ba.z,  va.w*rstd*ga.w+ba.w);
      o.z = (int)pk2(vb2.x*rstd*gb.x+bb.x, vb2.y*rstd*gb.y+bb.y);
      o.w = (int)pk2(vb2.z*rstd*gb.z+bb.z, vb2.w*rstd*gb.w+bb.w);
      *(int4*)&sH[ttk*136 + s4*32 + i*8] = o;
    }
  }
  __syncthreads();   // drains vmcnt (w1 chunk 0 ready) + lgkm (sH ready)

  f32x4 acc2[8] = {};

  for (int c = 0; c < 4; c++){
    // ---- GEMM1 (swapped): D[e][t] for this chunk (sW = w1 chunk c) ----
    f32x4 acc1[8] = {};
    #pragma unroll
    for (int ks = 0; ks < 4; ks++){
      bf16x8 bfv = *(const bf16x8*)&sH[(t0+lr)*136 + ks*32 + gq*8];
      #pragma unroll
      for (int i = 0; i < 8; i++){
        bf16x8 afv = *(const bf16x8*)&sW[(i*16+lr)*128 + ((((ks<<2)|gq) ^ (lr&7))<<3)];
        acc1[i] = __builtin_amdgcn_mfma_f32_16x16x32_bf16(afv, bfv, acc1[i], 0, 0, 0);
      }
    }
    // ---- gelu -> sHf (wave-private rows) ----
    #pragma unroll
    for (int i = 0; i < 8; i++){
      float4 bb = *(const float4*)&b1[c*128 + i*16 + gq*4];
      ushort4 pk;
      pk.x = bfr(fast_gelu(acc1[i][0] + bb.x));
      pk.y = bfr(fast_gelu(acc1[i][1] + bb.y));
      pk.z = bfr(fast_gelu(acc1[i][2] + bb.z));
      pk.w = bfr(fast_gelu(acc1[i][3] + bb.w));
      *(ushort4*)&sHf[(t0+lr)*136 + i*16 + gq*4] = pk;
    }
    __syncthreads();               // all waves done reading sW (w1)

    // ---- stage w2 chunk c ----
    #pragma unroll
    for (int i = 0; i < 8; i++){
      int rr = wid*32 + i*4 + rin;
      gl_lds16(w2b + (size_t)rr*512 + c*128 + ((gin ^ (rr&7))<<3),
               &sW[(wid*32 + i*4)*128]);
    }
    __syncthreads();               // drains vmcnt -> w2 ready

    // ---- GEMM2 (swapped): acc2[d][t] += W2chunk · Hf^T ----
    #pragma unroll
    for (int ks = 0; ks < 4; ks++){
      bf16x8 bfv = *(const bf16x8*)&sHf[(t0+lr)*136 + ks*32 + gq*8];
      #pragma unroll
      for (int j = 0; j < 8; j++){
        bf16x8 afv = *(const bf16x8*)&sW[(j*16+lr)*128 + ((((ks<<2)|gq) ^ (lr&7))<<3)];
        acc2[j] = __builtin_amdgcn_mfma_f32_16x16x32_bf16(afv, bfv, acc2[j], 0, 0, 0);
      }
    }
    __syncthreads();               // all waves done reading sW (w2)

    // ---- stage w1 chunk c+1 ----
    if (c < 3){
      #pragma unroll
      for (int i = 0; i < 8; i++){
        int rr = wid*32 + i*4 + rin;
        gl_lds16(w1b + (size_t)(c+1)*16384 + (size_t)rr*128 + ((gin ^ (rr&7))<<3),
                 &sW[(wid*32 + i*4)*128]);
      }
      __syncthreads();             // drains vmcnt -> w1 chunk c+1 ready
    }
  }

  // ---- epilogue: float4 residual RMW ----
  #pragma unroll
  for (int j = 0; j < 8; j++){
    float4* yp = (float4*)(y + (tb + t0 + lr)*128 + j*16 + gq*4);
    float4 bb = *(const float4*)&b2[j*16 + gq*4];
    float4 v = *yp;
    v.x += acc2[j][0] + bb.x;
    v.y += acc2[j][1] + bb.y;
    v.z += acc2[j][2] + bb.z;
    v.w += acc2[j][3] + bb.w;
    *yp = v;
  }
}

// ---------------- head: xb = mean over l=1..1023 ----------------
__global__ __launch_bounds__(128) void k_xb(const float* __restrict__ y,
                                            float* __restrict__ xb){
  int gg = blockIdx.x;   // b*64+n
  int b = gg >> 6, n = gg & 63;
  int d = threadIdx.x;
  float acc = 0.f;
  const float* p = y + (((size_t)b*1024 + 1)*64 + n)*128 + d;
  #pragma unroll 4
  for (int l = 1; l < 1024; l++){ acc += *p; p += 64*128; }
  xb[(size_t)gg*128 + d] = acc * (1.0f/1023.0f);
}

// ---------------- head: pairwise distances ----------------
__global__ __launch_bounds__(64) void k_dist(const float* __restrict__ xb,
                                             float* __restrict__ out){
  int p = blockIdx.x;           // b*2016 + pair
  int b = p >= 2016 ? 1 : 0;
  int pr = p - b*2016;
  int i0 = (int)((1.0f + sqrtf(1.0f + 8.0f*(float)pr))*0.5f);
  while (i0*(i0-1)/2 > pr) i0--;
  while ((i0+1)*i0/2 <= pr) i0++;
  int i1 = pr - i0*(i0-1)/2;
  int lane = threadIdx.x;
  const float* xa = xb + ((size_t)b*64 + i0)*128;
  const float* xc = xb + ((size_t)b*64 + i1)*128;
  float d0 = xa[lane]-xc[lane], d1 = xa[lane+64]-xc[lane+64];
  float s = d0*d0 + d1*d1;
  for (int m=32;m>=1;m>>=1) s += __shfl_xor(s, m);
  if (lane == 0) out[p] = sqrtf(s + 1e-8f);
}

extern "C" void kernel_launch(void* const* d_in, const int* in_sizes, int n_in,
                              void* d_out, int out_size, void* d_ws, size_t ws_size,
                              hipStream_t stream){
  const float* x    = (const float*)d_in[0];
  const float* rq_w = (const float*)d_in[1];  const float* rq_b = (const float*)d_in[2];
  const float* rk_w = (const float*)d_in[3];  const float* rk_b = (const float*)d_in[4];
  const float* rv_w = (const float*)d_in[5];  const float* rv_b = (const float*)d_in[6];
  const float* ro_w = (const float*)d_in[7];  const float* ro_b = (const float*)d_in[8];
  const float* cq_w = (const float*)d_in[9];  const float* cq_b = (const float*)d_in[10];
  const float* ck_w = (const float*)d_in[11]; const float* ck_b = (const float*)d_in[12];
  const float* cv_w = (const float*)d_in[13]; const float* cv_b = (const float*)d_in[14];
  const float* co_w = (const float*)d_in[15]; const float* co_b = (const float*)d_in[16];
  const float* lrg  = (const float*)d_in[17]; const float* lrb  = (const float*)d_in[18];
  const float* lcg  = (const float*)d_in[19]; const float* lcb  = (const float*)d_in[20];
  const float* lfg  = (const float*)d_in[21]; const float* lfb  = (const float*)d_in[22];
  const float* f1w  = (const float*)d_in[23]; const float* f1b  = (const float*)d_in[24];
  const float* f2w  = (const float*)d_in[25]; const float* f2b  = (const float*)d_in[26];

  float* ws = (float*)d_ws;
  float*  y   = ws;                           // 16777216
  float2* st  = (float2*)(ws + 16777216);     // 262144 floats
  float*  qb_ = ws + 17039360;                // 524288
  float*  kb_ = ws + 17563648;                // 524288
  float*  Pb  = ws + 18087936;                // 1048576
  float*  hkp = ws + 19136512;                // 524288
  float*  qs  = ws + 19660800;                // 512
  float*  ks  = ws + 19661312;                // 512
  float*  xb  = ws + 19661824;                // 16384
  ushort* w1b = (ushort*)(ws + 19678208);     // 262144 ushorts (131072 floats)
  ushort* w2b = (ushort*)(ws + 19809280);     // 262144 ushorts

  k_transpose<<<dim3(2048), dim3(256), 0, stream>>>(x, y);
  k_cvt<<<dim3(256), dim3(256), 0, stream>>>(f1w, w1b, 65536);
  k_cvt<<<dim3(256), dim3(256), 0, stream>>>(f2w, w2b, 65536);
  for (int l = 0; l < LCNT; l++){
    // row attention
    k_lnstats<<<dim3(32768), dim3(256), 0, stream>>>(y, st);
    k_row_core<<<dim3(2048), dim3(256), 0, stream>>>(y, st,
        rq_w + l*512, rq_b + l*4, rk_w + l*512, rk_b + l*4,
        rv_w + (size_t)l*16384, rv_b + l*128, ro_w + (size_t)l*16384,
        lrg + l*128, lrb + l*128, qb_, Pb);
    k_row_out<<<dim3(2048), dim3(256), 0, stream>>>(y, qb_, Pb, ro_b + l*128);
    // col attention
    k_lnstats<<<dim3(32768), dim3(256), 0, stream>>>(y, st);
    k_col_qk<<<dim3(2048), dim3(256), 0, stream>>>(y, st,
        cq_w + l*512, cq_b + l*4, ck_w + l*512, ck_b + l*4,
        lcg + l*128, lcb + l*128, qb_, kb_);
    k_col_sum<<<dim3(512), dim3(256), 0, stream>>>(qb_, kb_, qs, ks);
    k_col_hk<<<dim3(1024), dim3(256), 0, stream>>>(y, st, kb_, ks,
        lcg + l*128, lcb + l*128, hkp);
    k_col_ktvP<<<dim3(128), dim3(256), 0, stream>>>(hkp,
        cv_w + (size_t)l*16384, cv_b + l*128, co_w + (size_t)l*16384, qs, Pb);
    k_col_out<<<dim3(1024), dim3(256), 0, stream>>>(y, qb_, Pb, co_b + l*128);
    // FFN (LN fused, global_load_lds weights)
    k_ffn<<<dim3(2048), dim3(256), 0, stream>>>(y, lfg + l*128, lfb + l*128,
        w1b + (size_t)l*65536, f1b + l*512, w2b + (size_t)l*65536, f2b + l*128);
  }
  k_xb<<<dim3(128), dim3(128), 0, stream>>>(y, xb);
  k_dist<<<dim3(4032), dim3(64), 0, stream>>>(xb, (float*)d_out);
}

// Round 6
// 1331.319 us; speedup vs baseline: 2.9427x; 1.1568x over previous
//
#include <hip/hip_runtime.h>
#include <math.h>

#define LCNT 4

typedef float f32x4 __attribute__((ext_vector_type(4)));
typedef short bf16x8 __attribute__((ext_vector_type(8)));
typedef unsigned int u32;

__device__ __forceinline__ ushort bfr(float x){
  unsigned int b = __float_as_uint(x);
  return (ushort)((b + 0x7FFFu + ((b>>16)&1u)) >> 16);
}
__device__ __forceinline__ unsigned int pk2(float a, float b){
  return (unsigned int)bfr(a) | ((unsigned int)bfr(b)<<16);
}
__device__ __forceinline__ float fast_gelu(float v){
  float s = fabsf(v) * 0.70710678118f;
  float t = 1.0f/(1.0f + 0.3275911f*s);
  float p = t*(0.254829592f + t*(-0.284496736f + t*(1.421413741f +
            t*(-1.453152027f + t*1.061405429f))));
  float e = 1.0f - p*__expf(-s*s);
  e = copysignf(e, v);
  return 0.5f*v*(1.0f + e);
}
// async global->LDS, 16B per lane; LDS dest = wave-uniform base + lane*16
__device__ __forceinline__ void gl_lds16(const void* g, void* l){
  __builtin_amdgcn_global_load_lds(
      (const __attribute__((address_space(1))) u32*)g,
      (__attribute__((address_space(3))) u32*)l, 16, 0, 0);
}

// ---------------- transpose x[B,D,L,N] -> y[B,L,N,D] ----------------
__global__ __launch_bounds__(256) void k_transpose(const float* __restrict__ x,
                                                   float* __restrict__ y){
  int g = blockIdx.x;            // b*1024 + l
  int b = g >> 10, l = g & 1023;
  __shared__ float sh[128*65];
  for (int idx = threadIdx.x; idx < 128*64; idx += 256){
    int d = idx >> 6, n = idx & 63;
    sh[d*65+n] = x[(((size_t)b*128 + d)*1024 + l)*64 + n];
  }
  __syncthreads();
  for (int idx = threadIdx.x; idx < 128*64; idx += 256){
    int n = idx >> 7, d = idx & 127;
    y[((size_t)g*64 + n)*128 + d] = sh[d*65+n];
  }
}

// ---------------- fp32 -> bf16 weight conversion ----------------
__global__ __launch_bounds__(256) void k_cvt(const float* __restrict__ src,
                                             ushort* __restrict__ dst, int n4){
  int i = blockIdx.x*256 + threadIdx.x;
  if (i < n4){
    float4 v = ((const float4*)src)[i];
    ushort4 p; p.x=bfr(v.x); p.y=bfr(v.y); p.z=bfr(v.z); p.w=bfr(v.w);
    ((ushort4*)dst)[i] = p;
  }
}

// ---------------- fused per-(b,l) kernel: row LN + row attn + residual
//                  + col LN stats + col raw q,k ----------------
__global__ __launch_bounds__(256) void k_row(
    float* __restrict__ y,
    const float* __restrict__ rqw, const float* __restrict__ rqb,
    const float* __restrict__ rkw, const float* __restrict__ rkb,
    const float* __restrict__ rvw, const float* __restrict__ rvb,
    const float* __restrict__ roW, const float* __restrict__ rob,
    const float* __restrict__ lrg, const float* __restrict__ lrb,
    const float* __restrict__ cqw, const float* __restrict__ cqb,
    const float* __restrict__ ckw, const float* __restrict__ ckb,
    const float* __restrict__ lcg, const float* __restrict__ lcb,
    float2* __restrict__ stats,
    float* __restrict__ qout, float* __restrict__ kout)
{
  int g = blockIdx.x; int b = g>>10, l = g&1023;
  __shared__ float sh_h[64*129];
  __shared__ float sh_w4[2048];         // rqw|rkw|cqw|ckw (512 each)
  __shared__ float sh_q[256], sh_k[256];
  __shared__ float sh_hk[512];
  __shared__ float sh_ktv[128];
  __shared__ __align__(16) float sh_P[512];
  int tid = threadIdx.x;
  for (int i = tid; i < 512; i += 256){
    sh_w4[i] = rqw[i]; sh_w4[512+i] = rkw[i];
    sh_w4[1024+i] = cqw[i]; sh_w4[1536+i] = ckw[i];
  }
  // ---- A: load raw tile (regs) + row LN -> sh_h ----
  int ttk = tid>>2, s4 = tid&3;
  float* yr = y + ((size_t)g*64 + ttk)*128 + s4*32;
  float4 v[8];
  #pragma unroll
  for (int i=0;i<8;i++) v[i] = *(const float4*)(yr + i*4);
  float sum = 0.f;
  #pragma unroll
  for (int i=0;i<8;i++) sum += v[i].x+v[i].y+v[i].z+v[i].w;
  sum += __shfl_xor(sum,1); sum += __shfl_xor(sum,2);
  float mean = sum*(1.0f/128.0f);
  float vs = 0.f;
  #pragma unroll
  for (int i=0;i<8;i++){
    v[i].x-=mean; v[i].y-=mean; v[i].z-=mean; v[i].w-=mean;
    vs += v[i].x*v[i].x+v[i].y*v[i].y+v[i].z*v[i].z+v[i].w*v[i].w;
  }
  vs += __shfl_xor(vs,1); vs += __shfl_xor(vs,2);
  float rstd = rsqrtf(vs*(1.0f/128.0f) + 1e-5f);
  {
    const float* gp = lrg + s4*32; const float* bp = lrb + s4*32;
    float* hrow = &sh_h[ttk*129 + s4*32];
    #pragma unroll
    for (int i=0;i<8;i++){
      float4 g4 = *(const float4*)(gp+i*4);
      float4 b4 = *(const float4*)(bp+i*4);
      hrow[i*4+0]=v[i].x*rstd*g4.x+b4.x;
      hrow[i*4+1]=v[i].y*rstd*g4.y+b4.y;
      hrow[i*4+2]=v[i].z*rstd*g4.z+b4.z;
      hrow[i*4+3]=v[i].w*rstd*g4.w+b4.w;
    }
  }
  __syncthreads();
  // ---- B1: row q,k + normalize ----
  int h = tid>>6, n = tid&63;
  {
    float qr = rqb[h], kr = rkb[h];
    const float* qwp = sh_w4 + h*128;
    const float* kwp = sh_w4 + 512 + h*128;
    const float* hp  = sh_h + n*129;
    #pragma unroll 4
    for (int d=0; d<128; d++){ float hv=hp[d]; qr+=hv*qwp[d]; kr+=hv*kwp[d]; }
    qr = qr > 0.f ? qr + 1.f : __expf(qr);
    kr = kr > 0.f ? kr + 1.f : __expf(kr);
    float qs = qr; for (int m=32;m>=1;m>>=1) qs += __shfl_xor(qs, m);
    float ks = kr; for (int m=32;m>=1;m>>=1) ks += __shfl_xor(ks, m);
    sh_q[h*64+n] = qr * (64.f/qs);
    sh_k[h*64+n] = kr * (1.f/ks);
  }
  __syncthreads();
  // ---- B2: hk[h][d] ----
  #pragma unroll
  for (int r=0;r<2;r++){
    int idx = tid + r*256;
    int hh = idx>>7, d = idx&127;
    float acc = 0.f;
    #pragma unroll 4
    for (int nn=0;nn<64;nn++) acc += sh_k[hh*64+nn]*sh_h[nn*129+d];
    sh_hk[hh*128+d] = acc;
  }
  __syncthreads();
  // ---- B3: ktv[e] ----
  if (tid < 128){
    float acc = rvb[tid];
    const float* vr = rvw + (size_t)tid*128;
    const float* hp2 = sh_hk + (tid>>5)*128;
    #pragma unroll 4
    for (int d=0;d<128;d++) acc += vr[d]*hp2[d];
    sh_ktv[tid] = acc;
  }
  __syncthreads();
  // ---- B4: P[h][e] ----
  #pragma unroll
  for (int r=0;r<2;r++){
    int idx = tid + r*256;
    int hh = idx>>7, e = idx&127;
    float acc = 0.f;
    const float* orow = roW + (size_t)e*128 + hh*32;
    #pragma unroll 4
    for (int j=0;j<32;j++) acc += orow[j]*sh_ktv[hh*32+j];
    sh_P[hh*128+e] = acc;
  }
  __syncthreads();
  // ---- C: y_new = raw + ob + q.P  (write y once) ----
  {
    float q0=sh_q[ttk], q1=sh_q[64+ttk], q2=sh_q[128+ttk], q3=sh_q[192+ttk];
    const float4* P4 = (const float4*)sh_P;
    #pragma unroll
    for (int i=0;i<8;i++){
      int d4 = s4*8 + i;
      float4 p0=P4[d4], p1=P4[32+d4], p2=P4[64+d4], p3=P4[96+d4];
      float4 o4=*(const float4*)&rob[s4*32+i*4];
      v[i].x += mean + o4.x + q0*p0.x+q1*p1.x+q2*p2.x+q3*p3.x;
      v[i].y += mean + o4.y + q0*p0.y+q1*p1.y+q2*p2.y+q3*p3.y;
      v[i].z += mean + o4.z + q0*p0.z+q1*p1.z+q2*p2.z+q3*p3.z;
      v[i].w += mean + o4.w + q0*p0.w+q1*p1.w+q2*p2.w+q3*p3.w;
      *(float4*)(yr + i*4) = v[i];
    }
  }
  // ---- D0: col LN stats on y_new + hnormc -> sh_h ----
  float sum2 = 0.f;
  #pragma unroll
  for (int i=0;i<8;i++) sum2 += v[i].x+v[i].y+v[i].z+v[i].w;
  sum2 += __shfl_xor(sum2,1); sum2 += __shfl_xor(sum2,2);
  float cmean = sum2*(1.0f/128.0f);
  float cvs = 0.f;
  #pragma unroll
  for (int i=0;i<8;i++){
    v[i].x-=cmean; v[i].y-=cmean; v[i].z-=cmean; v[i].w-=cmean;
    cvs += v[i].x*v[i].x+v[i].y*v[i].y+v[i].z*v[i].z+v[i].w*v[i].w;
  }
  cvs += __shfl_xor(cvs,1); cvs += __shfl_xor(cvs,2);
  float crstd = rsqrtf(cvs*(1.0f/128.0f) + 1e-5f);
  if (s4 == 0) stats[(size_t)g*64 + ttk] = make_float2(cmean, crstd);
  {
    const float* gp = lcg + s4*32; const float* bp = lcb + s4*32;
    float* hrow = &sh_h[ttk*129 + s4*32];
    #pragma unroll
    for (int i=0;i<8;i++){
      float4 g4 = *(const float4*)(gp+i*4);
      float4 b4 = *(const float4*)(bp+i*4);
      hrow[i*4+0]=v[i].x*crstd*g4.x+b4.x;
      hrow[i*4+1]=v[i].y*crstd*g4.y+b4.y;
      hrow[i*4+2]=v[i].z*crstd*g4.z+b4.z;
      hrow[i*4+3]=v[i].w*crstd*g4.w+b4.w;
    }
  }
  __syncthreads();
  // ---- D1: col raw q,k ----
  {
    float qv = cqb[h], kv = ckb[h];
    const float* qwp = sh_w4 + 1024 + h*128;
    const float* kwp = sh_w4 + 1536 + h*128;
    const float* hp  = sh_h + n*129;
    #pragma unroll 4
    for (int d=0; d<128; d++){ float hv=hp[d]; qv+=hv*qwp[d]; kv+=hv*kwp[d]; }
    qv = qv > 0.f ? qv + 1.f : __expf(qv);
    kv = kv > 0.f ? kv + 1.f : __expf(kv);
    size_t o = (((size_t)b*64 + n)*4 + h)*1024 + l;
    qout[o] = qv; kout[o] = kv;
  }
}

// ---------------- col: normalizers per (b,n,h) ----------------
__global__ __launch_bounds__(256) void k_col_sum(const float* __restrict__ qin,
    const float* __restrict__ kin, float* __restrict__ qs, float* __restrict__ ks){
  int gg = blockIdx.x;  // (b*64+n)*4+h
  const float* qp = qin + (size_t)gg*1024;
  const float* kp = kin + (size_t)gg*1024;
  float sq = 0.f, sk = 0.f;
  for (int i = threadIdx.x; i < 1024; i += 256){ sq += qp[i]; sk += kp[i]; }
  for (int m=32;m>=1;m>>=1){ sq += __shfl_xor(sq, m); sk += __shfl_xor(sk, m); }
  __shared__ float aq[4], ak[4];
  int w = threadIdx.x >> 6;
  if ((threadIdx.x & 63) == 0){ aq[w] = sq; ak[w] = sk; }
  __syncthreads();
  if (threadIdx.x == 0){
    float fq = aq[0]+aq[1]+aq[2]+aq[3];
    float fk = ak[0]+ak[1]+ak[2]+ak[3];
    qs[gg] = 1024.f/fq;  ks[gg] = 1.f/fk;
  }
}

// ---------------- col: hk partials over l slices ----------------
__global__ __launch_bounds__(256) void k_col_hk(
    const float* __restrict__ y, const float2* __restrict__ stats,
    const float* __restrict__ kin, const float* __restrict__ ksn,
    const float* __restrict__ gam, const float* __restrict__ bet,
    float* __restrict__ hkp)
{
  int gg = blockIdx.x;                   // ((b*64+n)*8+s)
  int s = gg & 7, n = (gg>>3) & 63, b = gg>>9;
  int tid = threadIdx.x;
  __shared__ float sh_tok[256];
  int h = tid >> 6, d0 = (tid & 63)*2;
  float a0 = 0.f, a1 = 0.f;
  const float* kp = kin + (((size_t)b*64 + n)*4 + h)*1024;
  int li = tid >> 7, d = tid & 127;
  for (int l0 = s*128; l0 < s*128+128; l0 += 2){
    int t = ((b*1024 + l0 + li)*64 + n);
    float2 st = stats[t];
    sh_tok[li*128+d] = (y[(size_t)t*128 + d]-st.x)*st.y*gam[d] + bet[d];
    __syncthreads();
    float k0 = kp[l0], k1 = kp[l0+1];
    float2 t0 = *(const float2*)&sh_tok[d0];
    float2 t1 = *(const float2*)&sh_tok[128+d0];
    a0 += k0*t0.x + k1*t1.x;
    a1 += k0*t0.y + k1*t1.y;
    __syncthreads();
  }
  float kn = ksn[((size_t)b*64 + n)*4 + h];
  size_t base = ((size_t)gg*4 + h)*128;
  hkp[base + d0]   = a0*kn;
  hkp[base + d0+1] = a1*kn;
}

// ---------------- col: reduce hk, ktv, P (qs folded) ----------------
__global__ __launch_bounds__(256) void k_col_ktvP(
    const float* __restrict__ hkp,
    const float* __restrict__ vw, const float* __restrict__ vb,
    const float* __restrict__ ow, const float* __restrict__ qsn,
    float* __restrict__ Pout)
{
  int gg = blockIdx.x;   // b*64+n
  __shared__ float sh_hk[512];
  __shared__ float sh_ktv[128];
  int tid = threadIdx.x;
  #pragma unroll
  for (int r = 0; r < 2; r++){
    int idx = tid + r*256;
    float acc = 0.f;
    #pragma unroll
    for (int s = 0; s < 8; s++) acc += hkp[((size_t)gg*8 + s)*512 + idx];
    sh_hk[idx] = acc;
  }
  __syncthreads();
  if (tid < 128){
    float acc = vb[tid];
    const float* vr = vw + (size_t)tid*128;
    const float* hp2 = sh_hk + (tid>>5)*128;
    #pragma unroll 4
    for (int d = 0; d < 128; d++) acc += vr[d]*hp2[d];
    sh_ktv[tid] = acc;
  }
  __syncthreads();
  #pragma unroll
  for (int r = 0; r < 2; r++){
    int idx = tid + r*256;
    int hh = idx >> 7, e = idx & 127;
    float acc = 0.f;
    const float* orow = ow + (size_t)e*128 + hh*32;
    #pragma unroll 4
    for (int j = 0; j < 32; j++) acc += orow[j]*sh_ktv[hh*32+j];
    Pout[(size_t)gg*512 + hh*128 + e] = acc * qsn[gg*4 + hh];
  }
}

// ---------------- fused col-out + FFN (bf16 MFMA, gload_lds weights) ----------------
// LN phase also applies col attention output (q from qbuf, P via L2).
// y_new kept in regs; epilogue roundtrips acc2 through LDS (sF over dead sW)
// so final y is written exactly once.
__global__ __launch_bounds__(256, 2) void k_ffn(
    float* __restrict__ y,
    const float* __restrict__ qbuf, const float* __restrict__ Pb,
    const float* __restrict__ cob,
    const float* __restrict__ gam, const float* __restrict__ bet,
    const ushort* __restrict__ w1b, const float* __restrict__ b1,
    const ushort* __restrict__ w2b, const float* __restrict__ b2)
{
  __shared__ __align__(16) ushort pool[33792];  // 67584 B
  ushort* sW  = pool;            // 16384 ushorts (linear weight panel)
  ushort* sH  = pool + 16384;    // 64*136
  ushort* sHf = pool + 25088;    // 64*136
  float*  sF  = (float*)pool;    // epilogue: 64 rows, stride 132 (33792 B)
  int tid = threadIdx.x;
  int g = blockIdx.x; int b = g>>10, l = g&1023;
  size_t tb = (size_t)g*64;

  int wid = tid>>6, ln = tid&63;
  int lr = ln&15, gq = ln>>4;
  int t0 = wid*16;
  int rin = ln>>4;
  int gin = ln&15;

  // ---- issue w1 chunk-0 stage (overlaps LN/col-out below) ----
  #pragma unroll
  for (int i = 0; i < 8; i++){
    int rr = wid*32 + i*4 + rin;
    gl_lds16(w1b + (size_t)rr*128 + ((gin ^ (rr&7))<<3), &sW[(wid*32 + i*4)*128]);
  }

  // ---- LN phase + col-out, y_new kept in v[] ----
  int ttk = tid>>2, s4 = tid&3;
  float* yr = y + (tb+ttk)*128 + s4*32;
  float4 v[8];
  float fmean, rstd;
  {
    #pragma unroll
    for (int i = 0; i < 8; i++) v[i] = *(const float4*)(yr + i*4);
    // col attention output: v += cob + sum_h q_h * P[h]
    const float* qp = qbuf + ((size_t)(b*64+ttk)*4)*1024 + l;
    float q0 = qp[0], q1 = qp[1024], q2 = qp[2048], q3 = qp[3072];
    const float* pr = Pb + (size_t)(b*64+ttk)*512 + s4*32;
    #pragma unroll
    for (int i = 0; i < 8; i++){
      float4 p0 = *(const float4*)(pr + i*4);
      float4 p1 = *(const float4*)(pr + 128 + i*4);
      float4 p2 = *(const float4*)(pr + 256 + i*4);
      float4 p3 = *(const float4*)(pr + 384 + i*4);
      float4 c4 = *(const float4*)&cob[s4*32 + i*4];
      v[i].x += c4.x + q0*p0.x+q1*p1.x+q2*p2.x+q3*p3.x;
      v[i].y += c4.y + q0*p0.y+q1*p1.y+q2*p2.y+q3*p3.y;
      v[i].z += c4.z + q0*p0.z+q1*p1.z+q2*p2.z+q3*p3.z;
      v[i].w += c4.w + q0*p0.w+q1*p1.w+q2*p2.w+q3*p3.w;
    }
    // LN
    float sum = 0.f;
    #pragma unroll
    for (int i = 0; i < 8; i++) sum += v[i].x+v[i].y+v[i].z+v[i].w;
    sum += __shfl_xor(sum,1); sum += __shfl_xor(sum,2);
    fmean = sum*(1.0f/128.0f);
    float vs = 0.f;
    #pragma unroll
    for (int i = 0; i < 8; i++){
      v[i].x-=fmean; v[i].y-=fmean; v[i].z-=fmean; v[i].w-=fmean;
      vs += v[i].x*v[i].x+v[i].y*v[i].y+v[i].z*v[i].z+v[i].w*v[i].w;
    }
    vs += __shfl_xor(vs,1); vs += __shfl_xor(vs,2);
    rstd = rsqrtf(vs*(1.0f/128.0f) + 1e-5f);
    const float* gp = gam + s4*32; const float* bp = bet + s4*32;
    #pragma unroll
    for (int i = 0; i < 4; i++){
      float4 ga = *(const float4*)(gp + i*8),     gb = *(const float4*)(gp + i*8 + 4);
      float4 ba = *(const float4*)(bp + i*8),     bb = *(const float4*)(bp + i*8 + 4);
      float4 va = v[i*2], vb2 = v[i*2+1];
      int4 o;
      o.x = (int)pk2(va.x*rstd*ga.x+ba.x,  va.y*rstd*ga.y+ba.y);
      o.y = (int)pk2(va.z*rstd*ga.z+ba.z,  va.w*rstd*ga.w+ba.w);
      o.z = (int)pk2(vb2.x*rstd*gb.x+bb.x, vb2.y*rstd*gb.y+bb.y);
      o.w = (int)pk2(vb2.z*rstd*gb.z+bb.z, vb2.w*rstd*gb.w+bb.w);
      *(int4*)&sH[ttk*136 + s4*32 + i*8] = o;
    }
  }
  __syncthreads();   // drains vmcnt (w1 chunk 0 ready) + lgkm (sH ready)

  f32x4 acc2[8] = {};

  for (int c = 0; c < 4; c++){
    // ---- GEMM1 (swapped): D[e][t] ----
    f32x4 acc1[8] = {};
    #pragma unroll
    for (int ks = 0; ks < 4; ks++){
      bf16x8 bfv = *(const bf16x8*)&sH[(t0+lr)*136 + ks*32 + gq*8];
      #pragma unroll
      for (int i = 0; i < 8; i++){
        bf16x8 afv = *(const bf16x8*)&sW[(i*16+lr)*128 + ((((ks<<2)|gq) ^ (lr&7))<<3)];
        acc1[i] = __builtin_amdgcn_mfma_f32_16x16x32_bf16(afv, bfv, acc1[i], 0, 0, 0);
      }
    }
    // ---- gelu -> sHf ----
    #pragma unroll
    for (int i = 0; i < 8; i++){
      float4 bb = *(const float4*)&b1[c*128 + i*16 + gq*4];
      ushort4 pk;
      pk.x = bfr(fast_gelu(acc1[i][0] + bb.x));
      pk.y = bfr(fast_gelu(acc1[i][1] + bb.y));
      pk.z = bfr(fast_gelu(acc1[i][2] + bb.z));
      pk.w = bfr(fast_gelu(acc1[i][3] + bb.w));
      *(ushort4*)&sHf[(t0+lr)*136 + i*16 + gq*4] = pk;
    }
    __syncthreads();               // all waves done reading sW (w1)
    // ---- stage w2 chunk c ----
    #pragma unroll
    for (int i = 0; i < 8; i++){
      int rr = wid*32 + i*4 + rin;
      gl_lds16(w2b + (size_t)rr*512 + c*128 + ((gin ^ (rr&7))<<3),
               &sW[(wid*32 + i*4)*128]);
    }
    __syncthreads();               // drains vmcnt -> w2 ready
    // ---- GEMM2 (swapped): acc2[d][t] ----
    #pragma unroll
    for (int ks = 0; ks < 4; ks++){
      bf16x8 bfv = *(const bf16x8*)&sHf[(t0+lr)*136 + ks*32 + gq*8];
      #pragma unroll
      for (int j = 0; j < 8; j++){
        bf16x8 afv = *(const bf16x8*)&sW[(j*16+lr)*128 + ((((ks<<2)|gq) ^ (lr&7))<<3)];
        acc2[j] = __builtin_amdgcn_mfma_f32_16x16x32_bf16(afv, bfv, acc2[j], 0, 0, 0);
      }
    }
    __syncthreads();               // all waves done reading sW (w2)
    // ---- stage w1 chunk c+1 ----
    if (c < 3){
      #pragma unroll
      for (int i = 0; i < 8; i++){
        int rr = wid*32 + i*4 + rin;
        gl_lds16(w1b + (size_t)(c+1)*16384 + (size_t)rr*128 + ((gin ^ (rr&7))<<3),
                 &sW[(wid*32 + i*4)*128]);
      }
      __syncthreads();
    }
  }

  // ---- epilogue: acc2 -> sF (LDS), then single y write ----
  #pragma unroll
  for (int j = 0; j < 8; j++){
    float4 fo; fo.x=acc2[j][0]; fo.y=acc2[j][1]; fo.z=acc2[j][2]; fo.w=acc2[j][3];
    *(float4*)&sF[(t0+lr)*132 + j*16 + gq*4] = fo;
  }
  __syncthreads();
  #pragma unroll
  for (int i = 0; i < 8; i++){
    float4 f = *(const float4*)&sF[ttk*132 + s4*32 + i*4];
    float4 b4 = *(const float4*)&b2[s4*32 + i*4];
    float4 o;
    o.x = v[i].x + fmean + f.x + b4.x;
    o.y = v[i].y + fmean + f.y + b4.y;
    o.z = v[i].z + fmean + f.z + b4.z;
    o.w = v[i].w + fmean + f.w + b4.w;
    *(float4*)(yr + i*4) = o;
  }
}

// ---------------- head: xb partials (4 l-slices) + reduce ----------------
__global__ __launch_bounds__(128) void k_xbp(const float* __restrict__ y,
                                             float* __restrict__ xbq){
  int gg = blockIdx.x;   // (b*64+n)*4 + s
  int s = gg & 3, n = (gg>>2) & 63, b = gg>>8;
  int d = threadIdx.x;
  float acc = 0.f;
  int l0 = s*256 + (s==0 ? 1 : 0);
  const float* p = y + (((size_t)b*1024 + l0)*64 + n)*128 + d;
  for (int l = l0; l < s*256+256; l++){ acc += *p; p += 64*128; }
  xbq[(size_t)gg*128 + d] = acc;
}
__global__ __launch_bounds__(128) void k_xbr(const float* __restrict__ xbq,
                                             float* __restrict__ xb){
  int gg = blockIdx.x;   // b*64+n
  int d = threadIdx.x;
  const float* q = xbq + (size_t)gg*512;
  xb[(size_t)gg*128 + d] = (q[d] + q[128+d] + q[256+d] + q[384+d]) * (1.0f/1023.0f);
}

// ---------------- head: pairwise distances ----------------
__global__ __launch_bounds__(64) void k_dist(const float* __restrict__ xb,
                                             float* __restrict__ out){
  int p = blockIdx.x;           // b*2016 + pair
  int b = p >= 2016 ? 1 : 0;
  int pr = p - b*2016;
  int i0 = (int)((1.0f + sqrtf(1.0f + 8.0f*(float)pr))*0.5f);
  while (i0*(i0-1)/2 > pr) i0--;
  while ((i0+1)*i0/2 <= pr) i0++;
  int i1 = pr - i0*(i0-1)/2;
  int lane = threadIdx.x;
  const float* xa = xb + ((size_t)b*64 + i0)*128;
  const float* xc = xb + ((size_t)b*64 + i1)*128;
  float d0 = xa[lane]-xc[lane], d1 = xa[lane+64]-xc[lane+64];
  float s = d0*d0 + d1*d1;
  for (int m=32;m>=1;m>>=1) s += __shfl_xor(s, m);
  if (lane == 0) out[p] = sqrtf(s + 1e-8f);
}

extern "C" void kernel_launch(void* const* d_in, const int* in_sizes, int n_in,
                              void* d_out, int out_size, void* d_ws, size_t ws_size,
                              hipStream_t stream){
  const float* x    = (const float*)d_in[0];
  const float* rq_w = (const float*)d_in[1];  const float* rq_b = (const float*)d_in[2];
  const float* rk_w = (const float*)d_in[3];  const float* rk_b = (const float*)d_in[4];
  const float* rv_w = (const float*)d_in[5];  const float* rv_b = (const float*)d_in[6];
  const float* ro_w = (const float*)d_in[7];  const float* ro_b = (const float*)d_in[8];
  const float* cq_w = (const float*)d_in[9];  const float* cq_b = (const float*)d_in[10];
  const float* ck_w = (const float*)d_in[11]; const float* ck_b = (const float*)d_in[12];
  const float* cv_w = (const float*)d_in[13]; const float* cv_b = (const float*)d_in[14];
  const float* co_w = (const float*)d_in[15]; const float* co_b = (const float*)d_in[16];
  const float* lrg  = (const float*)d_in[17]; const float* lrb  = (const float*)d_in[18];
  const float* lcg  = (const float*)d_in[19]; const float* lcb  = (const float*)d_in[20];
  const float* lfg  = (const float*)d_in[21]; const float* lfb  = (const float*)d_in[22];
  const float* f1w  = (const float*)d_in[23]; const float* f1b  = (const float*)d_in[24];
  const float* f2w  = (const float*)d_in[25]; const float* f2b  = (const float*)d_in[26];

  float* ws = (float*)d_ws;
  float*  y   = ws;                           // 16777216
  float2* st  = (float2*)(ws + 16777216);     // 262144 floats
  float*  qb_ = ws + 17039360;                // 524288
  float*  kb_ = ws + 17563648;                // 524288
  float*  Pb  = ws + 18087936;                // 1048576
  float*  hkp = ws + 19136512;                // 524288
  float*  qs  = ws + 19660800;                // 512
  float*  ks  = ws + 19661312;                // 512
  float*  xb  = ws + 19661824;                // 16384
  ushort* w1b = (ushort*)(ws + 19678208);     // 262144 ushorts
  ushort* w2b = (ushort*)(ws + 19809280);     // 262144 ushorts
  float*  xbq = ws + 19940352;                // 65536

  k_transpose<<<dim3(2048), dim3(256), 0, stream>>>(x, y);
  k_cvt<<<dim3(256), dim3(256), 0, stream>>>(f1w, w1b, 65536);
  k_cvt<<<dim3(256), dim3(256), 0, stream>>>(f2w, w2b, 65536);
  for (int l = 0; l < LCNT; l++){
    k_row<<<dim3(2048), dim3(256), 0, stream>>>(y,
        rq_w + l*512, rq_b + l*4, rk_w + l*512, rk_b + l*4,
        rv_w + (size_t)l*16384, rv_b + l*128, ro_w + (size_t)l*16384, ro_b + l*128,
        lrg + l*128, lrb + l*128,
        cq_w + l*512, cq_b + l*4, ck_w + l*512, ck_b + l*4,
        lcg + l*128, lcb + l*128,
        st, qb_, kb_);
    k_col_sum<<<dim3(512), dim3(256), 0, stream>>>(qb_, kb_, qs, ks);
    k_col_hk<<<dim3(1024), dim3(256), 0, stream>>>(y, st, kb_, ks,
        lcg + l*128, lcb + l*128, hkp);
    k_col_ktvP<<<dim3(128), dim3(256), 0, stream>>>(hkp,
        cv_w + (size_t)l*16384, cv_b + l*128, co_w + (size_t)l*16384, qs, Pb);
    k_ffn<<<dim3(2048), dim3(256), 0, stream>>>(y, qb_, Pb, co_b + l*128,
        lfg + l*128, lfb + l*128,
        w1b + (size_t)l*65536, f1b + l*512, w2b + (size_t)l*65536, f2b + l*128);
  }
  k_xbp<<<dim3(512), dim3(128), 0, stream>>>(y, xbq);
  k_xbr<<<dim3(128), dim3(128), 0, stream>>>(xbq, xb);
  k_dist<<<dim3(4032), dim3(64), 0, stream>>>(xb, (float*)d_out);
}

// Round 7
// 1296.851 us; speedup vs baseline: 3.0209x; 1.0266x over previous
//
#include <hip/hip_runtime.h>
#include <math.h>

#define LCNT 4

typedef float f32x4 __attribute__((ext_vector_type(4)));
typedef short bf16x8 __attribute__((ext_vector_type(8)));
typedef unsigned int u32;

__device__ __forceinline__ ushort bfr(float x){
  unsigned int b = __float_as_uint(x);
  return (ushort)((b + 0x7FFFu + ((b>>16)&1u)) >> 16);
}
__device__ __forceinline__ unsigned int pk2(float a, float b){
  return (unsigned int)bfr(a) | ((unsigned int)bfr(b)<<16);
}
__device__ __forceinline__ float fast_gelu(float v){
  float s = fabsf(v) * 0.70710678118f;
  float t = 1.0f/(1.0f + 0.3275911f*s);
  float p = t*(0.254829592f + t*(-0.284496736f + t*(1.421413741f +
            t*(-1.453152027f + t*1.061405429f))));
  float e = 1.0f - p*__expf(-s*s);
  e = copysignf(e, v);
  return 0.5f*v*(1.0f + e);
}
// async global->LDS, 16B per lane; LDS dest = wave-uniform base + lane*16
__device__ __forceinline__ void gl_lds16(const void* g, void* l){
  __builtin_amdgcn_global_load_lds(
      (const __attribute__((address_space(1))) u32*)g,
      (__attribute__((address_space(3))) u32*)l, 16, 0, 0);
}

// ---------------- transpose x[B,D,L,N] -> y[B,L,N,D] ----------------
__global__ __launch_bounds__(256) void k_transpose(const float* __restrict__ x,
                                                   float* __restrict__ y){
  int g = blockIdx.x;            // b*1024 + l
  int b = g >> 10, l = g & 1023;
  __shared__ float sh[128*65];
  for (int idx = threadIdx.x; idx < 128*64; idx += 256){
    int d = idx >> 6, n = idx & 63;
    sh[d*65+n] = x[(((size_t)b*128 + d)*1024 + l)*64 + n];
  }
  __syncthreads();
  for (int idx = threadIdx.x; idx < 128*64; idx += 256){
    int n = idx >> 7, d = idx & 127;
    y[((size_t)g*64 + n)*128 + d] = sh[d*65+n];
  }
}

// ---------------- fp32 -> bf16 weight conversion ----------------
__global__ __launch_bounds__(256) void k_cvt(const float* __restrict__ src,
                                             ushort* __restrict__ dst, int n4){
  int i = blockIdx.x*256 + threadIdx.x;
  if (i < n4){
    float4 v = ((const float4*)src)[i];
    ushort4 p; p.x=bfr(v.x); p.y=bfr(v.y); p.z=bfr(v.z); p.w=bfr(v.w);
    ((ushort4*)dst)[i] = p;
  }
}

// ---------------- fused per-(b,l) kernel: row LN + row attn + residual
//                  + col LN stats + col raw q,k ----------------
__global__ __launch_bounds__(256) void k_row(
    float* __restrict__ y,
    const float* __restrict__ rqw, const float* __restrict__ rqb,
    const float* __restrict__ rkw, const float* __restrict__ rkb,
    const float* __restrict__ rvw, const float* __restrict__ rvb,
    const float* __restrict__ roW, const float* __restrict__ rob,
    const float* __restrict__ lrg, const float* __restrict__ lrb,
    const float* __restrict__ cqw, const float* __restrict__ cqb,
    const float* __restrict__ ckw, const float* __restrict__ ckb,
    const float* __restrict__ lcg, const float* __restrict__ lcb,
    float2* __restrict__ stats,
    float* __restrict__ qout, float* __restrict__ kout)
{
  int g = blockIdx.x; int b = g>>10, l = g&1023;
  __shared__ float sh_h[64*129];
  __shared__ float sh_w4[2048];         // rqw|rkw|cqw|ckw (512 each)
  __shared__ float sh_q[256], sh_k[256];
  __shared__ float sh_hk[512];
  __shared__ float sh_ktv[128];
  __shared__ __align__(16) float sh_P[512];
  int tid = threadIdx.x;
  for (int i = tid; i < 512; i += 256){
    sh_w4[i] = rqw[i]; sh_w4[512+i] = rkw[i];
    sh_w4[1024+i] = cqw[i]; sh_w4[1536+i] = ckw[i];
  }
  // ---- A: load raw tile (regs) + row LN -> sh_h ----
  int ttk = tid>>2, s4 = tid&3;
  float* yr = y + ((size_t)g*64 + ttk)*128 + s4*32;
  float4 v[8];
  #pragma unroll
  for (int i=0;i<8;i++) v[i] = *(const float4*)(yr + i*4);
  float sum = 0.f;
  #pragma unroll
  for (int i=0;i<8;i++) sum += v[i].x+v[i].y+v[i].z+v[i].w;
  sum += __shfl_xor(sum,1); sum += __shfl_xor(sum,2);
  float mean = sum*(1.0f/128.0f);
  float vs = 0.f;
  #pragma unroll
  for (int i=0;i<8;i++){
    v[i].x-=mean; v[i].y-=mean; v[i].z-=mean; v[i].w-=mean;
    vs += v[i].x*v[i].x+v[i].y*v[i].y+v[i].z*v[i].z+v[i].w*v[i].w;
  }
  vs += __shfl_xor(vs,1); vs += __shfl_xor(vs,2);
  float rstd = rsqrtf(vs*(1.0f/128.0f) + 1e-5f);
  {
    const float* gp = lrg + s4*32; const float* bp = lrb + s4*32;
    float* hrow = &sh_h[ttk*129 + s4*32];
    #pragma unroll
    for (int i=0;i<8;i++){
      float4 g4 = *(const float4*)(gp+i*4);
      float4 b4 = *(const float4*)(bp+i*4);
      hrow[i*4+0]=v[i].x*rstd*g4.x+b4.x;
      hrow[i*4+1]=v[i].y*rstd*g4.y+b4.y;
      hrow[i*4+2]=v[i].z*rstd*g4.z+b4.z;
      hrow[i*4+3]=v[i].w*rstd*g4.w+b4.w;
    }
  }
  __syncthreads();
  // ---- B1: row q,k + normalize ----
  int h = tid>>6, n = tid&63;
  {
    float qr = rqb[h], kr = rkb[h];
    const float* qwp = sh_w4 + h*128;
    const float* kwp = sh_w4 + 512 + h*128;
    const float* hp  = sh_h + n*129;
    #pragma unroll 4
    for (int d=0; d<128; d++){ float hv=hp[d]; qr+=hv*qwp[d]; kr+=hv*kwp[d]; }
    qr = qr > 0.f ? qr + 1.f : __expf(qr);
    kr = kr > 0.f ? kr + 1.f : __expf(kr);
    float qs = qr; for (int m=32;m>=1;m>>=1) qs += __shfl_xor(qs, m);
    float ks = kr; for (int m=32;m>=1;m>>=1) ks += __shfl_xor(ks, m);
    sh_q[h*64+n] = qr * (64.f/qs);
    sh_k[h*64+n] = kr * (1.f/ks);
  }
  __syncthreads();
  // ---- B2: hk[h][d] ----
  #pragma unroll
  for (int r=0;r<2;r++){
    int idx = tid + r*256;
    int hh = idx>>7, d = idx&127;
    float acc = 0.f;
    #pragma unroll 4
    for (int nn=0;nn<64;nn++) acc += sh_k[hh*64+nn]*sh_h[nn*129+d];
    sh_hk[hh*128+d] = acc;
  }
  __syncthreads();
  // ---- B3: ktv[e] ----
  if (tid < 128){
    float acc = rvb[tid];
    const float* vr = rvw + (size_t)tid*128;
    const float* hp2 = sh_hk + (tid>>5)*128;
    #pragma unroll 4
    for (int d=0;d<128;d++) acc += vr[d]*hp2[d];
    sh_ktv[tid] = acc;
  }
  __syncthreads();
  // ---- B4: P[h][e] ----
  #pragma unroll
  for (int r=0;r<2;r++){
    int idx = tid + r*256;
    int hh = idx>>7, e = idx&127;
    float acc = 0.f;
    const float* orow = roW + (size_t)e*128 + hh*32;
    #pragma unroll 4
    for (int j=0;j<32;j++) acc += orow[j]*sh_ktv[hh*32+j];
    sh_P[hh*128+e] = acc;
  }
  __syncthreads();
  // ---- C: y_new = raw + ob + q.P  (write y once) ----
  {
    float q0=sh_q[ttk], q1=sh_q[64+ttk], q2=sh_q[128+ttk], q3=sh_q[192+ttk];
    const float4* P4 = (const float4*)sh_P;
    #pragma unroll
    for (int i=0;i<8;i++){
      int d4 = s4*8 + i;
      float4 p0=P4[d4], p1=P4[32+d4], p2=P4[64+d4], p3=P4[96+d4];
      float4 o4=*(const float4*)&rob[s4*32+i*4];
      v[i].x += mean + o4.x + q0*p0.x+q1*p1.x+q2*p2.x+q3*p3.x;
      v[i].y += mean + o4.y + q0*p0.y+q1*p1.y+q2*p2.y+q3*p3.y;
      v[i].z += mean + o4.z + q0*p0.z+q1*p1.z+q2*p2.z+q3*p3.z;
      v[i].w += mean + o4.w + q0*p0.w+q1*p1.w+q2*p2.w+q3*p3.w;
      *(float4*)(yr + i*4) = v[i];
    }
  }
  // ---- D0: col LN stats on y_new + hnormc -> sh_h ----
  float sum2 = 0.f;
  #pragma unroll
  for (int i=0;i<8;i++) sum2 += v[i].x+v[i].y+v[i].z+v[i].w;
  sum2 += __shfl_xor(sum2,1); sum2 += __shfl_xor(sum2,2);
  float cmean = sum2*(1.0f/128.0f);
  float cvs = 0.f;
  #pragma unroll
  for (int i=0;i<8;i++){
    v[i].x-=cmean; v[i].y-=cmean; v[i].z-=cmean; v[i].w-=cmean;
    cvs += v[i].x*v[i].x+v[i].y*v[i].y+v[i].z*v[i].z+v[i].w*v[i].w;
  }
  cvs += __shfl_xor(cvs,1); cvs += __shfl_xor(cvs,2);
  float crstd = rsqrtf(cvs*(1.0f/128.0f) + 1e-5f);
  if (s4 == 0) stats[(size_t)g*64 + ttk] = make_float2(cmean, crstd);
  {
    const float* gp = lcg + s4*32; const float* bp = lcb + s4*32;
    float* hrow = &sh_h[ttk*129 + s4*32];
    #pragma unroll
    for (int i=0;i<8;i++){
      float4 g4 = *(const float4*)(gp+i*4);
      float4 b4 = *(const float4*)(bp+i*4);
      hrow[i*4+0]=v[i].x*crstd*g4.x+b4.x;
      hrow[i*4+1]=v[i].y*crstd*g4.y+b4.y;
      hrow[i*4+2]=v[i].z*crstd*g4.z+b4.z;
      hrow[i*4+3]=v[i].w*crstd*g4.w+b4.w;
    }
  }
  __syncthreads();
  // ---- D1: col raw q,k ----
  {
    float qv = cqb[h], kv = ckb[h];
    const float* qwp = sh_w4 + 1024 + h*128;
    const float* kwp = sh_w4 + 1536 + h*128;
    const float* hp  = sh_h + n*129;
    #pragma unroll 4
    for (int d=0; d<128; d++){ float hv=hp[d]; qv+=hv*qwp[d]; kv+=hv*kwp[d]; }
    qv = qv > 0.f ? qv + 1.f : __expf(qv);
    kv = kv > 0.f ? kv + 1.f : __expf(kv);
    size_t o = (((size_t)b*64 + n)*4 + h)*1024 + l;
    qout[o] = qv; kout[o] = kv;
  }
}

// ---------------- col: q normalizer per (b,n,h) ----------------
__global__ __launch_bounds__(256) void k_col_sum(const float* __restrict__ qin,
                                                 float* __restrict__ qs){
  int gg = blockIdx.x;  // (b*64+n)*4+h
  const float* qp = qin + (size_t)gg*1024;
  float sq = 0.f;
  for (int i = threadIdx.x; i < 1024; i += 256) sq += qp[i];
  for (int m=32;m>=1;m>>=1) sq += __shfl_xor(sq, m);
  __shared__ float aq[4];
  int w = threadIdx.x >> 6;
  if ((threadIdx.x & 63) == 0) aq[w] = sq;
  __syncthreads();
  if (threadIdx.x == 0) qs[gg] = 1024.f/(aq[0]+aq[1]+aq[2]+aq[3]);
}

// ---------------- col: streaming weighted reduce S1[d]=Σ k·r·y, A=Σk, B=Σk·r·m ----
__global__ __launch_bounds__(256) void k_col_s1(
    const float* __restrict__ y, const float2* __restrict__ stats,
    const float* __restrict__ kin,
    float* __restrict__ s1p, float* __restrict__ Ab, float* __restrict__ Bb)
{
  int gg = blockIdx.x;                   // ((b*64+n)*8+s)
  int s = gg & 7, n = (gg>>3) & 63, b = gg>>9;
  int tid = threadIdx.x;
  int li = tid>>7, d = tid&127;
  const float* kp = kin + ((size_t)(b*64+n)*4)*1024;
  float a0=0.f,a1=0.f,a2=0.f,a3=0.f;
  float A0=0.f,A1=0.f,A2=0.f,A3=0.f;
  float B0=0.f,B1=0.f,B2=0.f,B3=0.f;
  for (int j=0;j<64;j++){
    int l = s*128 + 2*j + li;
    size_t t = ((size_t)(b*1024+l)*64+n);
    float2 st = stats[t];
    float w = st.y * y[t*128 + d];
    float rm = st.y*st.x;
    float k0 = kp[l], k1 = kp[1024+l], k2 = kp[2048+l], k3 = kp[3072+l];
    a0 += k0*w; a1 += k1*w; a2 += k2*w; a3 += k3*w;
    A0 += k0; A1 += k1; A2 += k2; A3 += k3;
    B0 += k0*rm; B1 += k1*rm; B2 += k2*rm; B3 += k3*rm;
  }
  __shared__ float shr[512];
  __shared__ float sAB[8];
  if (li == 1){
    shr[0*128+d]=a0; shr[1*128+d]=a1; shr[2*128+d]=a2; shr[3*128+d]=a3;
    if (d==0){ sAB[0]=A0; sAB[1]=A1; sAB[2]=A2; sAB[3]=A3;
               sAB[4]=B0; sAB[5]=B1; sAB[6]=B2; sAB[7]=B3; }
  }
  __syncthreads();
  if (li == 0){
    float* out = s1p + (size_t)gg*512;
    out[0*128+d] = a0 + shr[0*128+d];
    out[1*128+d] = a1 + shr[1*128+d];
    out[2*128+d] = a2 + shr[2*128+d];
    out[3*128+d] = a3 + shr[3*128+d];
    if (d==0){
      Ab[gg*4+0]=A0+sAB[0]; Ab[gg*4+1]=A1+sAB[1];
      Ab[gg*4+2]=A2+sAB[2]; Ab[gg*4+3]=A3+sAB[3];
      Bb[gg*4+0]=B0+sAB[4]; Bb[gg*4+1]=B1+sAB[5];
      Bb[gg*4+2]=B2+sAB[6]; Bb[gg*4+3]=B3+sAB[7];
    }
  }
}

// ---------------- col: reduce S1/A/B -> hk -> ktv -> P (qs folded) ----------------
__global__ __launch_bounds__(256) void k_col_ktvP(
    const float* __restrict__ s1p,
    const float* __restrict__ Ab, const float* __restrict__ Bb,
    const float* __restrict__ vw, const float* __restrict__ vb,
    const float* __restrict__ ow, const float* __restrict__ qsn,
    const float* __restrict__ lcg, const float* __restrict__ lcb,
    float* __restrict__ Pout)
{
  int gg = blockIdx.x;   // b*64+n
  __shared__ float sh_hk[512];
  __shared__ float sh_ktv[128];
  __shared__ float sh_A[4], sh_B[4];
  int tid = threadIdx.x;
  #pragma unroll
  for (int r = 0; r < 2; r++){
    int idx = tid + r*256;
    float acc = 0.f;
    #pragma unroll
    for (int s = 0; s < 8; s++) acc += s1p[((size_t)gg*8 + s)*512 + idx];
    sh_hk[idx] = acc;
  }
  if (tid < 4){
    float a=0.f, bb=0.f;
    #pragma unroll
    for (int s = 0; s < 8; s++){ a += Ab[(gg*8+s)*4+tid]; bb += Bb[(gg*8+s)*4+tid]; }
    sh_A[tid]=a; sh_B[tid]=bb;
  }
  __syncthreads();
  #pragma unroll
  for (int r = 0; r < 2; r++){
    int idx = tid + r*256;
    int h = idx>>7, d = idx&127;
    float Ah = sh_A[h];
    sh_hk[idx] = lcg[d]*((sh_hk[idx]-sh_B[h])/Ah) + lcb[d];
  }
  __syncthreads();
  if (tid < 128){
    float acc = vb[tid];
    const float* vr = vw + (size_t)tid*128;
    const float* hp2 = sh_hk + (tid>>5)*128;
    #pragma unroll 4
    for (int d = 0; d < 128; d++) acc += vr[d]*hp2[d];
    sh_ktv[tid] = acc;
  }
  __syncthreads();
  #pragma unroll
  for (int r = 0; r < 2; r++){
    int idx = tid + r*256;
    int hh = idx >> 7, e = idx & 127;
    float acc = 0.f;
    const float* orow = ow + (size_t)e*128 + hh*32;
    #pragma unroll 4
    for (int j = 0; j < 32; j++) acc += orow[j]*sh_ktv[hh*32+j];
    Pout[(size_t)gg*512 + hh*128 + e] = acc * qsn[gg*4 + hh];
  }
}

// ---------------- fused col-out + FFN (bf16 MFMA, pipelined gload_lds) ----------------
// 8 e-chunks of 64. Two static panels: sW1 (w1 chunk, 64x128) and sW2
// (w2 chunk, 128x64). Stages are issued right after the barrier that frees
// the panel, so they land under the following GEMM; the next __syncthreads
// drain waits only on the remainder.
__global__ __launch_bounds__(256, 2) void k_ffn(
    float* __restrict__ y,
    const float* __restrict__ qbuf, const float* __restrict__ Pb,
    const float* __restrict__ cob,
    const float* __restrict__ gam, const float* __restrict__ bet,
    const ushort* __restrict__ w1b, const float* __restrict__ b1,
    const ushort* __restrict__ w2b, const float* __restrict__ b2)
{
  __shared__ __align__(16) ushort pool[33792];  // 67584 B
  ushort* sW1 = pool;            // 8192: w1 chunk, 64 rows x 128
  ushort* sW2 = pool + 8192;     // 8192: w2 chunk, 128 rows x 64
  ushort* sH  = pool + 16384;    // 64*136
  ushort* sHf = pool + 25088;    // 64*136 (only 64 cols used)
  float*  sF  = (float*)pool;    // epilogue: 64 rows, stride 132 (33792 B)
  int tid = threadIdx.x;
  int g = blockIdx.x; int b = g>>10, l = g&1023;
  size_t tb = (size_t)g*64;

  int wid = tid>>6, ln = tid&63;
  int lr = ln&15, gq = ln>>4;
  int t0 = wid*16;

  // ---- prologue: issue w1[0] + w2[0] stages (land under LN) ----
  #pragma unroll
  for (int i = 0; i < 4; i++){
    int row = wid*16 + i*4 + (ln>>4);      // panel row 0..63
    gl_lds16(w1b + (size_t)row*128 + (((ln&15) ^ (row&7))<<3),
             &sW1[(wid*16 + i*4)*128]);
  }
  #pragma unroll
  for (int i = 0; i < 4; i++){
    int row = wid*32 + i*8 + (ln>>3);      // panel row 0..127 (= d)
    gl_lds16(w2b + (size_t)row*512 + (((ln&7) ^ (row&7))<<3),
             &sW2[(wid*32 + i*8)*64]);
  }

  // ---- LN phase + col-out, y_new kept in v[] ----
  int ttk = tid>>2, s4 = tid&3;
  float* yr = y + (tb+ttk)*128 + s4*32;
  float4 v[8];
  float fmean;
  {
    #pragma unroll
    for (int i = 0; i < 8; i++) v[i] = *(const float4*)(yr + i*4);
    const float* qp = qbuf + ((size_t)(b*64+ttk)*4)*1024 + l;
    float q0 = qp[0], q1 = qp[1024], q2 = qp[2048], q3 = qp[3072];
    const float* pr = Pb + (size_t)(b*64+ttk)*512 + s4*32;
    #pragma unroll
    for (int i = 0; i < 8; i++){
      float4 p0 = *(const float4*)(pr + i*4);
      float4 p1 = *(const float4*)(pr + 128 + i*4);
      float4 p2 = *(const float4*)(pr + 256 + i*4);
      float4 p3 = *(const float4*)(pr + 384 + i*4);
      float4 c4 = *(const float4*)&cob[s4*32 + i*4];
      v[i].x += c4.x + q0*p0.x+q1*p1.x+q2*p2.x+q3*p3.x;
      v[i].y += c4.y + q0*p0.y+q1*p1.y+q2*p2.y+q3*p3.y;
      v[i].z += c4.z + q0*p0.z+q1*p1.z+q2*p2.z+q3*p3.z;
      v[i].w += c4.w + q0*p0.w+q1*p1.w+q2*p2.w+q3*p3.w;
    }
    float sum = 0.f;
    #pragma unroll
    for (int i = 0; i < 8; i++) sum += v[i].x+v[i].y+v[i].z+v[i].w;
    sum += __shfl_xor(sum,1); sum += __shfl_xor(sum,2);
    fmean = sum*(1.0f/128.0f);
    float vs = 0.f;
    #pragma unroll
    for (int i = 0; i < 8; i++){
      v[i].x-=fmean; v[i].y-=fmean; v[i].z-=fmean; v[i].w-=fmean;
      vs += v[i].x*v[i].x+v[i].y*v[i].y+v[i].z*v[i].z+v[i].w*v[i].w;
    }
    vs += __shfl_xor(vs,1); vs += __shfl_xor(vs,2);
    float rstd = rsqrtf(vs*(1.0f/128.0f) + 1e-5f);
    const float* gp = gam + s4*32; const float* bp = bet + s4*32;
    #pragma unroll
    for (int i = 0; i < 4; i++){
      float4 ga = *(const float4*)(gp + i*8),     gb = *(const float4*)(gp + i*8 + 4);
      float4 ba = *(const float4*)(bp + i*8),     bb = *(const float4*)(bp + i*8 + 4);
      float4 va = v[i*2], vb2 = v[i*2+1];
      int4 o;
      o.x = (int)pk2(va.x*rstd*ga.x+ba.x,  va.y*rstd*ga.y+ba.y);
      o.y = (int)pk2(va.z*rstd*ga.z+ba.z,  va.w*rstd*ga.w+ba.w);
      o.z = (int)pk2(vb2.x*rstd*gb.x+bb.x, vb2.y*rstd*gb.y+bb.y);
      o.w = (int)pk2(vb2.z*rstd*gb.z+bb.z, vb2.w*rstd*gb.w+bb.w);
      *(int4*)&sH[ttk*136 + s4*32 + i*8] = o;
    }
  }
  __syncthreads();   // drains vmcnt (w1[0], w2[0] ready) + lgkm (sH ready)

  f32x4 acc2[8] = {};

  for (int c = 0; c < 8; c++){
    // ---- GEMM1: D[e-chunk][t] from sW1, sH ----
    f32x4 acc1[4] = {};
    #pragma unroll
    for (int ks = 0; ks < 4; ks++){
      bf16x8 bfv = *(const bf16x8*)&sH[(t0+lr)*136 + ks*32 + gq*8];
      #pragma unroll
      for (int i = 0; i < 4; i++){
        bf16x8 afv = *(const bf16x8*)&sW1[(i*16+lr)*128 + ((((ks<<2)|gq) ^ (lr&7))<<3)];
        acc1[i] = __builtin_amdgcn_mfma_f32_16x16x32_bf16(afv, bfv, acc1[i], 0, 0, 0);
      }
    }
    // ---- gelu -> sHf (wave-private rows, no barrier) ----
    #pragma unroll
    for (int i = 0; i < 4; i++){
      float4 bb = *(const float4*)&b1[c*64 + i*16 + gq*4];
      ushort4 pk;
      pk.x = bfr(fast_gelu(acc1[i][0] + bb.x));
      pk.y = bfr(fast_gelu(acc1[i][1] + bb.y));
      pk.z = bfr(fast_gelu(acc1[i][2] + bb.z));
      pk.w = bfr(fast_gelu(acc1[i][3] + bb.w));
      *(ushort4*)&sHf[(t0+lr)*136 + i*16 + gq*4] = pk;
    }
    __syncthreads();   // C: all waves done with sW1; w2[c] landed
    // ---- issue w1[c+1] stage (lands under GEMM2) ----
    if (c < 7){
      #pragma unroll
      for (int i = 0; i < 4; i++){
        int row = wid*16 + i*4 + (ln>>4);
        gl_lds16(w1b + (size_t)(c+1)*8192 + (size_t)row*128 + (((ln&15) ^ (row&7))<<3),
                 &sW1[(wid*16 + i*4)*128]);
      }
    }
    // ---- GEMM2: acc2[d][t] += W2chunk · Hf^T from sW2, sHf ----
    #pragma unroll
    for (int ks = 0; ks < 2; ks++){
      bf16x8 bfv = *(const bf16x8*)&sHf[(t0+lr)*136 + ks*32 + gq*8];
      #pragma unroll
      for (int j = 0; j < 8; j++){
        bf16x8 afv = *(const bf16x8*)&sW2[(j*16+lr)*64 + ((((ks<<2)|gq) ^ (lr&7))<<3)];
        acc2[j] = __builtin_amdgcn_mfma_f32_16x16x32_bf16(afv, bfv, acc2[j], 0, 0, 0);
      }
    }
    __syncthreads();   // E: drains w1[c+1]; all waves done with sW2
    // ---- issue w2[c+1] stage (lands under next GEMM1) ----
    if (c < 7){
      #pragma unroll
      for (int i = 0; i < 4; i++){
        int row = wid*32 + i*8 + (ln>>3);
        gl_lds16(w2b + (size_t)row*512 + (c+1)*64 + (((ln&7) ^ (row&7))<<3),
                 &sW2[(wid*32 + i*8)*64]);
      }
    }
  }

  // ---- epilogue: acc2 -> sF (LDS), then single y write ----
  #pragma unroll
  for (int j = 0; j < 8; j++){
    float4 fo; fo.x=acc2[j][0]; fo.y=acc2[j][1]; fo.z=acc2[j][2]; fo.w=acc2[j][3];
    *(float4*)&sF[(t0+lr)*132 + j*16 + gq*4] = fo;
  }
  __syncthreads();
  #pragma unroll
  for (int i = 0; i < 8; i++){
    float4 f = *(const float4*)&sF[ttk*132 + s4*32 + i*4];
    float4 b4 = *(const float4*)&b2[s4*32 + i*4];
    float4 o;
    o.x = v[i].x + fmean + f.x + b4.x;
    o.y = v[i].y + fmean + f.y + b4.y;
    o.z = v[i].z + fmean + f.z + b4.z;
    o.w = v[i].w + fmean + f.w + b4.w;
    *(float4*)(yr + i*4) = o;
  }
}

// ---------------- head: xb partials (4 l-slices) + reduce ----------------
__global__ __launch_bounds__(128) void k_xbp(const float* __restrict__ y,
                                             float* __restrict__ xbq){
  int gg = blockIdx.x;   // (b*64+n)*4 + s
  int s = gg & 3, n = (gg>>2) & 63, b = gg>>8;
  int d = threadIdx.x;
  float acc = 0.f;
  int l0 = s*256 + (s==0 ? 1 : 0);
  const float* p = y + (((size_t)b*1024 + l0)*64 + n)*128 + d;
  for (int l = l0; l < s*256+256; l++){ acc += *p; p += 64*128; }
  xbq[(size_t)gg*128 + d] = acc;
}
__global__ __launch_bounds__(128) void k_xbr(const float* __restrict__ xbq,
                                             float* __restrict__ xb){
  int gg = blockIdx.x;   // b*64+n
  int d = threadIdx.x;
  const float* q = xbq + (size_t)gg*512;
  xb[(size_t)gg*128 + d] = (q[d] + q[128+d] + q[256+d] + q[384+d]) * (1.0f/1023.0f);
}

// ---------------- head: pairwise distances ----------------
__global__ __launch_bounds__(64) void k_dist(const float* __restrict__ xb,
                                             float* __restrict__ out){
  int p = blockIdx.x;           // b*2016 + pair
  int b = p >= 2016 ? 1 : 0;
  int pr = p - b*2016;
  int i0 = (int)((1.0f + sqrtf(1.0f + 8.0f*(float)pr))*0.5f);
  while (i0*(i0-1)/2 > pr) i0--;
  while ((i0+1)*i0/2 <= pr) i0++;
  int i1 = pr - i0*(i0-1)/2;
  int lane = threadIdx.x;
  const float* xa = xb + ((size_t)b*64 + i0)*128;
  const float* xc = xb + ((size_t)b*64 + i1)*128;
  float d0 = xa[lane]-xc[lane], d1 = xa[lane+64]-xc[lane+64];
  float s = d0*d0 + d1*d1;
  for (int m=32;m>=1;m>>=1) s += __shfl_xor(s, m);
  if (lane == 0) out[p] = sqrtf(s + 1e-8f);
}

extern "C" void kernel_launch(void* const* d_in, const int* in_sizes, int n_in,
                              void* d_out, int out_size, void* d_ws, size_t ws_size,
                              hipStream_t stream){
  const float* x    = (const float*)d_in[0];
  const float* rq_w = (const float*)d_in[1];  const float* rq_b = (const float*)d_in[2];
  const float* rk_w = (const float*)d_in[3];  const float* rk_b = (const float*)d_in[4];
  const float* rv_w = (const float*)d_in[5];  const float* rv_b = (const float*)d_in[6];
  const float* ro_w = (const float*)d_in[7];  const float* ro_b = (const float*)d_in[8];
  const float* cq_w = (const float*)d_in[9];  const float* cq_b = (const float*)d_in[10];
  const float* ck_w = (const float*)d_in[11]; const float* ck_b = (const float*)d_in[12];
  const float* cv_w = (const float*)d_in[13]; const float* cv_b = (const float*)d_in[14];
  const float* co_w = (const float*)d_in[15]; const float* co_b = (const float*)d_in[16];
  const float* lrg  = (const float*)d_in[17]; const float* lrb  = (const float*)d_in[18];
  const float* lcg  = (const float*)d_in[19]; const float* lcb  = (const float*)d_in[20];
  const float* lfg  = (const float*)d_in[21]; const float* lfb  = (const float*)d_in[22];
  const float* f1w  = (const float*)d_in[23]; const float* f1b  = (const float*)d_in[24];
  const float* f2w  = (const float*)d_in[25]; const float* f2b  = (const float*)d_in[26];

  float* ws = (float*)d_ws;
  float*  y   = ws;                           // 16777216
  float2* st  = (float2*)(ws + 16777216);     // 262144 floats
  float*  qb_ = ws + 17039360;                // 524288
  float*  kb_ = ws + 17563648;                // 524288
  float*  Pb  = ws + 18087936;                // 1048576
  float*  s1p = ws + 19136512;                // 524288 (1024*512)
  float*  qs  = ws + 19660800;                // 512
  float*  xb  = ws + 19661824;                // 16384
  ushort* w1b = (ushort*)(ws + 19678208);     // 262144 ushorts
  ushort* w2b = (ushort*)(ws + 19809280);     // 262144 ushorts
  float*  xbq = ws + 19940352;                // 65536
  float*  Ab  = ws + 20005888;                // 4096
  float*  Bb  = ws + 20009984;                // 4096

  k_transpose<<<dim3(2048), dim3(256), 0, stream>>>(x, y);
  k_cvt<<<dim3(256), dim3(256), 0, stream>>>(f1w, w1b, 65536);
  k_cvt<<<dim3(256), dim3(256), 0, stream>>>(f2w, w2b, 65536);
  for (int l = 0; l < LCNT; l++){
    k_row<<<dim3(2048), dim3(256), 0, stream>>>(y,
        rq_w + l*512, rq_b + l*4, rk_w + l*512, rk_b + l*4,
        rv_w + (size_t)l*16384, rv_b + l*128, ro_w + (size_t)l*16384, ro_b + l*128,
        lrg + l*128, lrb + l*128,
        cq_w + l*512, cq_b + l*4, ck_w + l*512, ck_b + l*4,
        lcg + l*128, lcb + l*128,
        st, qb_, kb_);
    k_col_sum<<<dim3(512), dim3(256), 0, stream>>>(qb_, qs);
    k_col_s1<<<dim3(1024), dim3(256), 0, stream>>>(y, st, kb_, s1p, Ab, Bb);
    k_col_ktvP<<<dim3(128), dim3(256), 0, stream>>>(s1p, Ab, Bb,
        cv_w + (size_t)l*16384, cv_b + l*128, co_w + (size_t)l*16384, qs,
        lcg + l*128, lcb + l*128, Pb);
    k_ffn<<<dim3(2048), dim3(256), 0, stream>>>(y, qb_, Pb, co_b + l*128,
        lfg + l*128, lfb + l*128,
        w1b + (size_t)l*65536, f1b + l*512, w2b + (size_t)l*65536, f2b + l*128);
  }
  k_xbp<<<dim3(512), dim3(128), 0, stream>>>(y, xbq);
  k_xbr<<<dim3(128), dim3(128), 0, stream>>>(xbq, xb);
  k_dist<<<dim3(4032), dim3(64), 0, stream>>>(xb, (float*)d_out);
}

// Round 8
// 1203.526 us; speedup vs baseline: 3.2551x; 1.0775x over previous
//
#include <hip/hip_runtime.h>
#include <math.h>

#define LCNT 4

typedef float f32x4 __attribute__((ext_vector_type(4)));
typedef short bf16x8 __attribute__((ext_vector_type(8)));
typedef unsigned int u32;

__device__ __forceinline__ ushort bfr(float x){
  unsigned int b = __float_as_uint(x);
  return (ushort)((b + 0x7FFFu + ((b>>16)&1u)) >> 16);
}
__device__ __forceinline__ unsigned int pk2(float a, float b){
  return (unsigned int)bfr(a) | ((unsigned int)bfr(b)<<16);
}
__device__ __forceinline__ float fast_gelu(float v){
  float s = fabsf(v) * 0.70710678118f;
  float t = 1.0f/(1.0f + 0.3275911f*s);
  float p = t*(0.254829592f + t*(-0.284496736f + t*(1.421413741f +
            t*(-1.453152027f + t*1.061405429f))));
  float e = 1.0f - p*__expf(-s*s);
  e = copysignf(e, v);
  return 0.5f*v*(1.0f + e);
}
// async global->LDS, 16B per lane; LDS dest = wave-uniform base + lane*16
__device__ __forceinline__ void gl_lds16(const void* g, void* l){
  __builtin_amdgcn_global_load_lds(
      (const __attribute__((address_space(1))) u32*)g,
      (__attribute__((address_space(3))) u32*)l, 16, 0, 0);
}

// ---------------- transpose x[B,D,L,N] -> y[B,L,N,D] ----------------
__global__ __launch_bounds__(256) void k_transpose(const float* __restrict__ x,
                                                   float* __restrict__ y){
  int g = blockIdx.x;            // b*1024 + l
  int b = g >> 10, l = g & 1023;
  __shared__ float sh[128*65];
  for (int idx = threadIdx.x; idx < 128*64; idx += 256){
    int d = idx >> 6, n = idx & 63;
    sh[d*65+n] = x[(((size_t)b*128 + d)*1024 + l)*64 + n];
  }
  __syncthreads();
  for (int idx = threadIdx.x; idx < 128*64; idx += 256){
    int n = idx >> 7, d = idx & 127;
    y[((size_t)g*64 + n)*128 + d] = sh[d*65+n];
  }
}

// ---------------- fp32 -> bf16 weight conversion ----------------
__global__ __launch_bounds__(256) void k_cvt(const float* __restrict__ src,
                                             ushort* __restrict__ dst, int n4){
  int i = blockIdx.x*256 + threadIdx.x;
  if (i < n4){
    float4 v = ((const float4*)src)[i];
    ushort4 p; p.x=bfr(v.x); p.y=bfr(v.y); p.z=bfr(v.z); p.w=bfr(v.w);
    ((ushort4*)dst)[i] = p;
  }
}

// ---------------- fused per-(b,l) kernel: row LN + row attn + residual
//                  + col LN stats + col raw q,k ----------------
__global__ __launch_bounds__(256) void k_row(
    float* __restrict__ y,
    const float* __restrict__ rqw, const float* __restrict__ rqb,
    const float* __restrict__ rkw, const float* __restrict__ rkb,
    const float* __restrict__ rvw, const float* __restrict__ rvb,
    const float* __restrict__ roW, const float* __restrict__ rob,
    const float* __restrict__ lrg, const float* __restrict__ lrb,
    const float* __restrict__ cqw, const float* __restrict__ cqb,
    const float* __restrict__ ckw, const float* __restrict__ ckb,
    const float* __restrict__ lcg, const float* __restrict__ lcb,
    float2* __restrict__ stats,
    float* __restrict__ qout, float* __restrict__ kout)
{
  int g = blockIdx.x; int b = g>>10, l = g&1023;
  __shared__ float sh_h[64*129];
  __shared__ float sh_w4[2048];         // rqw|rkw|cqw|ckw (512 each)
  __shared__ float sh_q[256], sh_k[256];
  __shared__ float sh_hk[512];
  __shared__ float sh_ktv[128];
  __shared__ __align__(16) float sh_P[512];
  int tid = threadIdx.x;
  for (int i = tid; i < 512; i += 256){
    sh_w4[i] = rqw[i]; sh_w4[512+i] = rkw[i];
    sh_w4[1024+i] = cqw[i]; sh_w4[1536+i] = ckw[i];
  }
  // ---- A: load raw tile (regs) + row LN -> sh_h ----
  int ttk = tid>>2, s4 = tid&3;
  float* yr = y + ((size_t)g*64 + ttk)*128 + s4*32;
  float4 v[8];
  #pragma unroll
  for (int i=0;i<8;i++) v[i] = *(const float4*)(yr + i*4);
  float sum = 0.f;
  #pragma unroll
  for (int i=0;i<8;i++) sum += v[i].x+v[i].y+v[i].z+v[i].w;
  sum += __shfl_xor(sum,1); sum += __shfl_xor(sum,2);
  float mean = sum*(1.0f/128.0f);
  float vs = 0.f;
  #pragma unroll
  for (int i=0;i<8;i++){
    v[i].x-=mean; v[i].y-=mean; v[i].z-=mean; v[i].w-=mean;
    vs += v[i].x*v[i].x+v[i].y*v[i].y+v[i].z*v[i].z+v[i].w*v[i].w;
  }
  vs += __shfl_xor(vs,1); vs += __shfl_xor(vs,2);
  float rstd = rsqrtf(vs*(1.0f/128.0f) + 1e-5f);
  {
    const float* gp = lrg + s4*32; const float* bp = lrb + s4*32;
    float* hrow = &sh_h[ttk*129 + s4*32];
    #pragma unroll
    for (int i=0;i<8;i++){
      float4 g4 = *(const float4*)(gp+i*4);
      float4 b4 = *(const float4*)(bp+i*4);
      hrow[i*4+0]=v[i].x*rstd*g4.x+b4.x;
      hrow[i*4+1]=v[i].y*rstd*g4.y+b4.y;
      hrow[i*4+2]=v[i].z*rstd*g4.z+b4.z;
      hrow[i*4+3]=v[i].w*rstd*g4.w+b4.w;
    }
  }
  __syncthreads();
  // ---- B1: row q,k + normalize ----
  int h = tid>>6, n = tid&63;
  {
    float qr = rqb[h], kr = rkb[h];
    const float* qwp = sh_w4 + h*128;
    const float* kwp = sh_w4 + 512 + h*128;
    const float* hp  = sh_h + n*129;
    #pragma unroll 4
    for (int d=0; d<128; d++){ float hv=hp[d]; qr+=hv*qwp[d]; kr+=hv*kwp[d]; }
    qr = qr > 0.f ? qr + 1.f : __expf(qr);
    kr = kr > 0.f ? kr + 1.f : __expf(kr);
    float qs = qr; for (int m=32;m>=1;m>>=1) qs += __shfl_xor(qs, m);
    float ks = kr; for (int m=32;m>=1;m>>=1) ks += __shfl_xor(ks, m);
    sh_q[h*64+n] = qr * (64.f/qs);
    sh_k[h*64+n] = kr * (1.f/ks);
  }
  __syncthreads();
  // ---- B2: hk[h][d] ----
  #pragma unroll
  for (int r=0;r<2;r++){
    int idx = tid + r*256;
    int hh = idx>>7, d = idx&127;
    float acc = 0.f;
    #pragma unroll 4
    for (int nn=0;nn<64;nn++) acc += sh_k[hh*64+nn]*sh_h[nn*129+d];
    sh_hk[hh*128+d] = acc;
  }
  __syncthreads();
  // ---- B3: ktv[e] ----
  if (tid < 128){
    float acc = rvb[tid];
    const float* vr = rvw + (size_t)tid*128;
    const float* hp2 = sh_hk + (tid>>5)*128;
    #pragma unroll 4
    for (int d=0;d<128;d++) acc += vr[d]*hp2[d];
    sh_ktv[tid] = acc;
  }
  __syncthreads();
  // ---- B4: P[h][e] ----
  #pragma unroll
  for (int r=0;r<2;r++){
    int idx = tid + r*256;
    int hh = idx>>7, e = idx&127;
    float acc = 0.f;
    const float* orow = roW + (size_t)e*128 + hh*32;
    #pragma unroll 4
    for (int j=0;j<32;j++) acc += orow[j]*sh_ktv[hh*32+j];
    sh_P[hh*128+e] = acc;
  }
  __syncthreads();
  // ---- C: y_new = raw + ob + q.P  (write y once) ----
  {
    float q0=sh_q[ttk], q1=sh_q[64+ttk], q2=sh_q[128+ttk], q3=sh_q[192+ttk];
    const float4* P4 = (const float4*)sh_P;
    #pragma unroll
    for (int i=0;i<8;i++){
      int d4 = s4*8 + i;
      float4 p0=P4[d4], p1=P4[32+d4], p2=P4[64+d4], p3=P4[96+d4];
      float4 o4=*(const float4*)&rob[s4*32+i*4];
      v[i].x += mean + o4.x + q0*p0.x+q1*p1.x+q2*p2.x+q3*p3.x;
      v[i].y += mean + o4.y + q0*p0.y+q1*p1.y+q2*p2.y+q3*p3.y;
      v[i].z += mean + o4.z + q0*p0.z+q1*p1.z+q2*p2.z+q3*p3.z;
      v[i].w += mean + o4.w + q0*p0.w+q1*p1.w+q2*p2.w+q3*p3.w;
      *(float4*)(yr + i*4) = v[i];
    }
  }
  // ---- D0: col LN stats on y_new + hnormc -> sh_h ----
  float sum2 = 0.f;
  #pragma unroll
  for (int i=0;i<8;i++) sum2 += v[i].x+v[i].y+v[i].z+v[i].w;
  sum2 += __shfl_xor(sum2,1); sum2 += __shfl_xor(sum2,2);
  float cmean = sum2*(1.0f/128.0f);
  float cvs = 0.f;
  #pragma unroll
  for (int i=0;i<8;i++){
    v[i].x-=cmean; v[i].y-=cmean; v[i].z-=cmean; v[i].w-=cmean;
    cvs += v[i].x*v[i].x+v[i].y*v[i].y+v[i].z*v[i].z+v[i].w*v[i].w;
  }
  cvs += __shfl_xor(cvs,1); cvs += __shfl_xor(cvs,2);
  float crstd = rsqrtf(cvs*(1.0f/128.0f) + 1e-5f);
  if (s4 == 0) stats[(size_t)g*64 + ttk] = make_float2(cmean, crstd);
  {
    const float* gp = lcg + s4*32; const float* bp = lcb + s4*32;
    float* hrow = &sh_h[ttk*129 + s4*32];
    #pragma unroll
    for (int i=0;i<8;i++){
      float4 g4 = *(const float4*)(gp+i*4);
      float4 b4 = *(const float4*)(bp+i*4);
      hrow[i*4+0]=v[i].x*crstd*g4.x+b4.x;
      hrow[i*4+1]=v[i].y*crstd*g4.y+b4.y;
      hrow[i*4+2]=v[i].z*crstd*g4.z+b4.z;
      hrow[i*4+3]=v[i].w*crstd*g4.w+b4.w;
    }
  }
  __syncthreads();
  // ---- D1: col raw q,k ----
  {
    float qv = cqb[h], kv = ckb[h];
    const float* qwp = sh_w4 + 1024 + h*128;
    const float* kwp = sh_w4 + 1536 + h*128;
    const float* hp  = sh_h + n*129;
    #pragma unroll 4
    for (int d=0; d<128; d++){ float hv=hp[d]; qv+=hv*qwp[d]; kv+=hv*kwp[d]; }
    qv = qv > 0.f ? qv + 1.f : __expf(qv);
    kv = kv > 0.f ? kv + 1.f : __expf(kv);
    size_t o = (((size_t)b*64 + n)*4 + h)*1024 + l;
    qout[o] = qv; kout[o] = kv;
  }
}

// ---------------- col: q normalizer per (b,n,h) ----------------
__global__ __launch_bounds__(256) void k_col_sum(const float* __restrict__ qin,
                                                 float* __restrict__ qs){
  int gg = blockIdx.x;  // (b*64+n)*4+h
  const float* qp = qin + (size_t)gg*1024;
  float sq = 0.f;
  for (int i = threadIdx.x; i < 1024; i += 256) sq += qp[i];
  for (int m=32;m>=1;m>>=1) sq += __shfl_xor(sq, m);
  __shared__ float aq[4];
  int w = threadIdx.x >> 6;
  if ((threadIdx.x & 63) == 0) aq[w] = sq;
  __syncthreads();
  if (threadIdx.x == 0) qs[gg] = 1024.f/(aq[0]+aq[1]+aq[2]+aq[3]);
}

// ---------------- col: streaming weighted reduce S1[d]=Σ k·r·y, A=Σk, B=Σk·r·m ----
__global__ __launch_bounds__(256) void k_col_s1(
    const float* __restrict__ y, const float2* __restrict__ stats,
    const float* __restrict__ kin,
    float* __restrict__ s1p, float* __restrict__ Ab, float* __restrict__ Bb)
{
  int gg = blockIdx.x;                   // ((b*64+n)*8+s)
  int s = gg & 7, n = (gg>>3) & 63, b = gg>>9;
  int tid = threadIdx.x;
  int li = tid>>7, d = tid&127;
  const float* kp = kin + ((size_t)(b*64+n)*4)*1024;
  float a0=0.f,a1=0.f,a2=0.f,a3=0.f;
  float A0=0.f,A1=0.f,A2=0.f,A3=0.f;
  float B0=0.f,B1=0.f,B2=0.f,B3=0.f;
  for (int j=0;j<64;j++){
    int l = s*128 + 2*j + li;
    size_t t = ((size_t)(b*1024+l)*64+n);
    float2 st = stats[t];
    float w = st.y * y[t*128 + d];
    float rm = st.y*st.x;
    float k0 = kp[l], k1 = kp[1024+l], k2 = kp[2048+l], k3 = kp[3072+l];
    a0 += k0*w; a1 += k1*w; a2 += k2*w; a3 += k3*w;
    A0 += k0; A1 += k1; A2 += k2; A3 += k3;
    B0 += k0*rm; B1 += k1*rm; B2 += k2*rm; B3 += k3*rm;
  }
  __shared__ float shr[512];
  __shared__ float sAB[8];
  if (li == 1){
    shr[0*128+d]=a0; shr[1*128+d]=a1; shr[2*128+d]=a2; shr[3*128+d]=a3;
    if (d==0){ sAB[0]=A0; sAB[1]=A1; sAB[2]=A2; sAB[3]=A3;
               sAB[4]=B0; sAB[5]=B1; sAB[6]=B2; sAB[7]=B3; }
  }
  __syncthreads();
  if (li == 0){
    float* out = s1p + (size_t)gg*512;
    out[0*128+d] = a0 + shr[0*128+d];
    out[1*128+d] = a1 + shr[1*128+d];
    out[2*128+d] = a2 + shr[2*128+d];
    out[3*128+d] = a3 + shr[3*128+d];
    if (d==0){
      Ab[gg*4+0]=A0+sAB[0]; Ab[gg*4+1]=A1+sAB[1];
      Ab[gg*4+2]=A2+sAB[2]; Ab[gg*4+3]=A3+sAB[3];
      Bb[gg*4+0]=B0+sAB[4]; Bb[gg*4+1]=B1+sAB[5];
      Bb[gg*4+2]=B2+sAB[6]; Bb[gg*4+3]=B3+sAB[7];
    }
  }
}

// ---------------- col: reduce S1/A/B -> hk -> ktv -> P (qs folded) ----------------
__global__ __launch_bounds__(256) void k_col_ktvP(
    const float* __restrict__ s1p,
    const float* __restrict__ Ab, const float* __restrict__ Bb,
    const float* __restrict__ vw, const float* __restrict__ vb,
    const float* __restrict__ ow, const float* __restrict__ qsn,
    const float* __restrict__ lcg, const float* __restrict__ lcb,
    float* __restrict__ Pout)
{
  int gg = blockIdx.x;   // b*64+n
  __shared__ float sh_hk[512];
  __shared__ float sh_ktv[128];
  __shared__ float sh_A[4], sh_B[4];
  int tid = threadIdx.x;
  #pragma unroll
  for (int r = 0; r < 2; r++){
    int idx = tid + r*256;
    float acc = 0.f;
    #pragma unroll
    for (int s = 0; s < 8; s++) acc += s1p[((size_t)gg*8 + s)*512 + idx];
    sh_hk[idx] = acc;
  }
  if (tid < 4){
    float a=0.f, bb=0.f;
    #pragma unroll
    for (int s = 0; s < 8; s++){ a += Ab[(gg*8+s)*4+tid]; bb += Bb[(gg*8+s)*4+tid]; }
    sh_A[tid]=a; sh_B[tid]=bb;
  }
  __syncthreads();
  #pragma unroll
  for (int r = 0; r < 2; r++){
    int idx = tid + r*256;
    int h = idx>>7, d = idx&127;
    float Ah = sh_A[h];
    sh_hk[idx] = lcg[d]*((sh_hk[idx]-sh_B[h])/Ah) + lcb[d];
  }
  __syncthreads();
  if (tid < 128){
    float acc = vb[tid];
    const float* vr = vw + (size_t)tid*128;
    const float* hp2 = sh_hk + (tid>>5)*128;
    #pragma unroll 4
    for (int d = 0; d < 128; d++) acc += vr[d]*hp2[d];
    sh_ktv[tid] = acc;
  }
  __syncthreads();
  #pragma unroll
  for (int r = 0; r < 2; r++){
    int idx = tid + r*256;
    int hh = idx >> 7, e = idx & 127;
    float acc = 0.f;
    const float* orow = ow + (size_t)e*128 + hh*32;
    #pragma unroll 4
    for (int j = 0; j < 32; j++) acc += orow[j]*sh_ktv[hh*32+j];
    Pout[(size_t)gg*512 + hh*128 + e] = acc * qsn[gg*4 + hh];
  }
}

// ---------------- fused col-out + FFN (bf16 MFMA, pipelined gload_lds) ----------------
// 512 threads, 8 waves: wt=wid>>1 token group (16 tokens), we=wid&1 e/d half.
// 8 e-chunks of 64; sW1 (64x128) / sW2 (128x64) panels; stages issued after
// the barrier that frees the panel so they land under the following GEMM.
__global__ __launch_bounds__(512, 4) void k_ffn(
    float* __restrict__ y,
    const float* __restrict__ qbuf, const float* __restrict__ Pb,
    const float* __restrict__ cob,
    const float* __restrict__ gam, const float* __restrict__ bet,
    const ushort* __restrict__ w1b, const float* __restrict__ b1,
    const ushort* __restrict__ w2b, const float* __restrict__ b2)
{
  __shared__ __align__(16) ushort pool[29952];  // 59904 B
  ushort* sW1 = pool;            // 8192: w1 chunk, 64 rows x 128
  ushort* sW2 = pool + 8192;     // 8192: w2 chunk, 128 rows x 64
  ushort* sH  = pool + 16384;    // 64 x 136
  ushort* sHf = pool + 25088;    // 64 x 72 (4608)
  float*  sF  = (float*)pool;    // epilogue: 64 rows x stride 132 = 33792 B
  int tid = threadIdx.x;
  int g = blockIdx.x; int b = g>>10, l = g&1023;
  size_t tb = (size_t)g*64;

  int wid = tid>>6, ln = tid&63;
  int lr = ln&15, gq = ln>>4;
  int wt = wid>>1, we = wid&1;
  int t0 = wt*16;

  // ---- prologue: issue w1[0] + w2[0] stages (land under LN) ----
  #pragma unroll
  for (int i = 0; i < 2; i++){
    int row = wid*8 + i*4 + (ln>>4);       // 64 rows of 256B
    gl_lds16(w1b + (size_t)row*128 + (((ln&15) ^ (row&7))<<3),
             &sW1[(wid*8 + i*4)*128]);
  }
  #pragma unroll
  for (int i = 0; i < 2; i++){
    int row = wid*16 + i*8 + (ln>>3);      // 128 rows of 128B
    gl_lds16(w2b + (size_t)row*512 + (((ln&7) ^ (row&7))<<3),
             &sW2[(wid*16 + i*8)*64]);
  }

  // ---- LN phase + col-out (8 threads/token), y_new kept in v[] ----
  int ttk = tid>>3, s8 = tid&7;
  float* yr = y + (tb+ttk)*128 + s8*16;
  float4 v[4];
  float fmean;
  {
    #pragma unroll
    for (int i = 0; i < 4; i++) v[i] = *(const float4*)(yr + i*4);
    const float* qp = qbuf + ((size_t)(b*64+ttk)*4)*1024 + l;
    float q0 = qp[0], q1 = qp[1024], q2 = qp[2048], q3 = qp[3072];
    const float* pr = Pb + (size_t)(b*64+ttk)*512 + s8*16;
    #pragma unroll
    for (int i = 0; i < 4; i++){
      float4 p0 = *(const float4*)(pr + i*4);
      float4 p1 = *(const float4*)(pr + 128 + i*4);
      float4 p2 = *(const float4*)(pr + 256 + i*4);
      float4 p3 = *(const float4*)(pr + 384 + i*4);
      float4 c4 = *(const float4*)&cob[s8*16 + i*4];
      v[i].x += c4.x + q0*p0.x+q1*p1.x+q2*p2.x+q3*p3.x;
      v[i].y += c4.y + q0*p0.y+q1*p1.y+q2*p2.y+q3*p3.y;
      v[i].z += c4.z + q0*p0.z+q1*p1.z+q2*p2.z+q3*p3.z;
      v[i].w += c4.w + q0*p0.w+q1*p1.w+q2*p2.w+q3*p3.w;
    }
    float sum = 0.f;
    #pragma unroll
    for (int i = 0; i < 4; i++) sum += v[i].x+v[i].y+v[i].z+v[i].w;
    sum += __shfl_xor(sum,1); sum += __shfl_xor(sum,2); sum += __shfl_xor(sum,4);
    fmean = sum*(1.0f/128.0f);
    float vs = 0.f;
    #pragma unroll
    for (int i = 0; i < 4; i++){
      v[i].x-=fmean; v[i].y-=fmean; v[i].z-=fmean; v[i].w-=fmean;
      vs += v[i].x*v[i].x+v[i].y*v[i].y+v[i].z*v[i].z+v[i].w*v[i].w;
    }
    vs += __shfl_xor(vs,1); vs += __shfl_xor(vs,2); vs += __shfl_xor(vs,4);
    float rstd = rsqrtf(vs*(1.0f/128.0f) + 1e-5f);
    const float* gp = gam + s8*16; const float* bp = bet + s8*16;
    #pragma unroll
    for (int i = 0; i < 2; i++){
      float4 ga = *(const float4*)(gp + i*8),     gb = *(const float4*)(gp + i*8 + 4);
      float4 ba = *(const float4*)(bp + i*8),     bb = *(const float4*)(bp + i*8 + 4);
      float4 va = v[i*2], vb2 = v[i*2+1];
      int4 o;
      o.x = (int)pk2(va.x*rstd*ga.x+ba.x,  va.y*rstd*ga.y+ba.y);
      o.y = (int)pk2(va.z*rstd*ga.z+ba.z,  va.w*rstd*ga.w+ba.w);
      o.z = (int)pk2(vb2.x*rstd*gb.x+bb.x, vb2.y*rstd*gb.y+bb.y);
      o.w = (int)pk2(vb2.z*rstd*gb.z+bb.z, vb2.w*rstd*gb.w+bb.w);
      *(int4*)&sH[ttk*136 + s8*16 + i*8] = o;
    }
  }
  __syncthreads();   // drains vmcnt (w1[0], w2[0] ready) + lgkm (sH ready)

  f32x4 acc2[4] = {};

  for (int c = 0; c < 8; c++){
    // ---- GEMM1: e-tiles (we*32 + i*16) x tokens t0 ----
    f32x4 acc1[2] = {};
    #pragma unroll
    for (int ks = 0; ks < 4; ks++){
      bf16x8 bfv = *(const bf16x8*)&sH[(t0+lr)*136 + ks*32 + gq*8];
      #pragma unroll
      for (int i = 0; i < 2; i++){
        int er = we*32 + i*16 + lr;
        bf16x8 afv = *(const bf16x8*)&sW1[er*128 + ((((ks<<2)|gq) ^ (lr&7))<<3)];
        acc1[i] = __builtin_amdgcn_mfma_f32_16x16x32_bf16(afv, bfv, acc1[i], 0, 0, 0);
      }
    }
    // ---- gelu -> sHf ----
    #pragma unroll
    for (int i = 0; i < 2; i++){
      float4 bb = *(const float4*)&b1[c*64 + we*32 + i*16 + gq*4];
      ushort4 pk;
      pk.x = bfr(fast_gelu(acc1[i][0] + bb.x));
      pk.y = bfr(fast_gelu(acc1[i][1] + bb.y));
      pk.z = bfr(fast_gelu(acc1[i][2] + bb.z));
      pk.w = bfr(fast_gelu(acc1[i][3] + bb.w));
      *(ushort4*)&sHf[(t0+lr)*72 + we*32 + i*16 + gq*4] = pk;
    }
    __syncthreads();   // all waves done with sW1; sHf complete; w2[c] landed
    // ---- issue w1[c+1] stage (lands under GEMM2) ----
    if (c < 7){
      #pragma unroll
      for (int i = 0; i < 2; i++){
        int row = wid*8 + i*4 + (ln>>4);
        gl_lds16(w1b + (size_t)(c+1)*8192 + (size_t)row*128 + (((ln&15) ^ (row&7))<<3),
                 &sW1[(wid*8 + i*4)*128]);
      }
    }
    // ---- GEMM2: d-tiles (we*64 + j*16) x tokens t0 ----
    #pragma unroll
    for (int ks = 0; ks < 2; ks++){
      bf16x8 bfv = *(const bf16x8*)&sHf[(t0+lr)*72 + ks*32 + gq*8];
      #pragma unroll
      for (int j = 0; j < 4; j++){
        int dr = we*64 + j*16 + lr;
        bf16x8 afv = *(const bf16x8*)&sW2[dr*64 + ((((ks<<2)|gq) ^ (lr&7))<<3)];
        acc2[j] = __builtin_amdgcn_mfma_f32_16x16x32_bf16(afv, bfv, acc2[j], 0, 0, 0);
      }
    }
    __syncthreads();   // drains w1[c+1]; all waves done with sW2/sHf
    // ---- issue w2[c+1] stage (lands under next GEMM1) ----
    if (c < 7){
      #pragma unroll
      for (int i = 0; i < 2; i++){
        int row = wid*16 + i*8 + (ln>>3);
        gl_lds16(w2b + (size_t)row*512 + (c+1)*64 + (((ln&7) ^ (row&7))<<3),
                 &sW2[(wid*16 + i*8)*64]);
      }
    }
  }

  // ---- epilogue: acc2 -> sF (LDS), then single y write ----
  #pragma unroll
  for (int j = 0; j < 4; j++){
    float4 fo; fo.x=acc2[j][0]; fo.y=acc2[j][1]; fo.z=acc2[j][2]; fo.w=acc2[j][3];
    *(float4*)&sF[(t0+lr)*132 + we*64 + j*16 + gq*4] = fo;
  }
  __syncthreads();
  #pragma unroll
  for (int i = 0; i < 4; i++){
    float4 f = *(const float4*)&sF[ttk*132 + s8*16 + i*4];
    float4 b4 = *(const float4*)&b2[s8*16 + i*4];
    float4 o;
    o.x = v[i].x + fmean + f.x + b4.x;
    o.y = v[i].y + fmean + f.y + b4.y;
    o.z = v[i].z + fmean + f.z + b4.z;
    o.w = v[i].w + fmean + f.w + b4.w;
    *(float4*)(yr + i*4) = o;
  }
}

// ---------------- head: xb partials (4 l-slices) + reduce ----------------
__global__ __launch_bounds__(128) void k_xbp(const float* __restrict__ y,
                                             float* __restrict__ xbq){
  int gg = blockIdx.x;   // (b*64+n)*4 + s
  int s = gg & 3, n = (gg>>2) & 63, b = gg>>8;
  int d = threadIdx.x;
  float acc = 0.f;
  int l0 = s*256 + (s==0 ? 1 : 0);
  const float* p = y + (((size_t)b*1024 + l0)*64 + n)*128 + d;
  for (int l = l0; l < s*256+256; l++){ acc += *p; p += 64*128; }
  xbq[(size_t)gg*128 + d] = acc;
}
__global__ __launch_bounds__(128) void k_xbr(const float* __restrict__ xbq,
                                             float* __restrict__ xb){
  int gg = blockIdx.x;   // b*64+n
  int d = threadIdx.x;
  const float* q = xbq + (size_t)gg*512;
  xb[(size_t)gg*128 + d] = (q[d] + q[128+d] + q[256+d] + q[384+d]) * (1.0f/1023.0f);
}

// ---------------- head: pairwise distances ----------------
__global__ __launch_bounds__(64) void k_dist(const float* __restrict__ xb,
                                             float* __restrict__ out){
  int p = blockIdx.x;           // b*2016 + pair
  int b = p >= 2016 ? 1 : 0;
  int pr = p - b*2016;
  int i0 = (int)((1.0f + sqrtf(1.0f + 8.0f*(float)pr))*0.5f);
  while (i0*(i0-1)/2 > pr) i0--;
  while ((i0+1)*i0/2 <= pr) i0++;
  int i1 = pr - i0*(i0-1)/2;
  int lane = threadIdx.x;
  const float* xa = xb + ((size_t)b*64 + i0)*128;
  const float* xc = xb + ((size_t)b*64 + i1)*128;
  float d0 = xa[lane]-xc[lane], d1 = xa[lane+64]-xc[lane+64];
  float s = d0*d0 + d1*d1;
  for (int m=32;m>=1;m>>=1) s += __shfl_xor(s, m);
  if (lane == 0) out[p] = sqrtf(s + 1e-8f);
}

extern "C" void kernel_launch(void* const* d_in, const int* in_sizes, int n_in,
                              void* d_out, int out_size, void* d_ws, size_t ws_size,
                              hipStream_t stream){
  const float* x    = (const float*)d_in[0];
  const float* rq_w = (const float*)d_in[1];  const float* rq_b = (const float*)d_in[2];
  const float* rk_w = (const float*)d_in[3];  const float* rk_b = (const float*)d_in[4];
  const float* rv_w = (const float*)d_in[5];  const float* rv_b = (const float*)d_in[6];
  const float* ro_w = (const float*)d_in[7];  const float* ro_b = (const float*)d_in[8];
  const float* cq_w = (const float*)d_in[9];  const float* cq_b = (const float*)d_in[10];
  const float* ck_w = (const float*)d_in[11]; const float* ck_b = (const float*)d_in[12];
  const float* cv_w = (const float*)d_in[13]; const float* cv_b = (const float*)d_in[14];
  const float* co_w = (const float*)d_in[15]; const float* co_b = (const float*)d_in[16];
  const float* lrg  = (const float*)d_in[17]; const float* lrb  = (const float*)d_in[18];
  const float* lcg  = (const float*)d_in[19]; const float* lcb  = (const float*)d_in[20];
  const float* lfg  = (const float*)d_in[21]; const float* lfb  = (const float*)d_in[22];
  const float* f1w  = (const float*)d_in[23]; const float* f1b  = (const float*)d_in[24];
  const float* f2w  = (const float*)d_in[25]; const float* f2b  = (const float*)d_in[26];

  float* ws = (float*)d_ws;
  float*  y   = ws;                           // 16777216
  float2* st  = (float2*)(ws + 16777216);     // 262144 floats
  float*  qb_ = ws + 17039360;                // 524288
  float*  kb_ = ws + 17563648;                // 524288
  float*  Pb  = ws + 18087936;                // 1048576
  float*  s1p = ws + 19136512;                // 524288 (1024*512)
  float*  qs  = ws + 19660800;                // 512
  float*  xb  = ws + 19661824;                // 16384
  ushort* w1b = (ushort*)(ws + 19678208);     // 262144 ushorts
  ushort* w2b = (ushort*)(ws + 19809280);     // 262144 ushorts
  float*  xbq = ws + 19940352;                // 65536
  float*  Ab  = ws + 20005888;                // 4096
  float*  Bb  = ws + 20009984;                // 4096

  k_transpose<<<dim3(2048), dim3(256), 0, stream>>>(x, y);
  k_cvt<<<dim3(256), dim3(256), 0, stream>>>(f1w, w1b, 65536);
  k_cvt<<<dim3(256), dim3(256), 0, stream>>>(f2w, w2b, 65536);
  for (int l = 0; l < LCNT; l++){
    k_row<<<dim3(2048), dim3(256), 0, stream>>>(y,
        rq_w + l*512, rq_b + l*4, rk_w + l*512, rk_b + l*4,
        rv_w + (size_t)l*16384, rv_b + l*128, ro_w + (size_t)l*16384, ro_b + l*128,
        lrg + l*128, lrb + l*128,
        cq_w + l*512, cq_b + l*4, ck_w + l*512, ck_b + l*4,
        lcg + l*128, lcb + l*128,
        st, qb_, kb_);
    k_col_sum<<<dim3(512), dim3(256), 0, stream>>>(qb_, qs);
    k_col_s1<<<dim3(1024), dim3(256), 0, stream>>>(y, st, kb_, s1p, Ab, Bb);
    k_col_ktvP<<<dim3(128), dim3(256), 0, stream>>>(s1p, Ab, Bb,
        cv_w + (size_t)l*16384, cv_b + l*128, co_w + (size_t)l*16384, qs,
        lcg + l*128, lcb + l*128, Pb);
    k_ffn<<<dim3(2048), dim3(512), 0, stream>>>(y, qb_, Pb, co_b + l*128,
        lfg + l*128, lfb + l*128,
        w1b + (size_t)l*65536, f1b + l*512, w2b + (size_t)l*65536, f2b + l*128);
  }
  k_xbp<<<dim3(512), dim3(128), 0, stream>>>(y, xbq);
  k_xbr<<<dim3(128), dim3(128), 0, stream>>>(xbq, xb);
  k_dist<<<dim3(4032), dim3(64), 0, stream>>>(xb, (float*)d_out);
}

// Round 9
// 1106.700 us; speedup vs baseline: 3.5399x; 1.0875x over previous
//
#include <hip/hip_runtime.h>
#include <math.h>

#define LCNT 4

typedef float f32x4 __attribute__((ext_vector_type(4)));
typedef short bf16x8 __attribute__((ext_vector_type(8)));
typedef unsigned int u32;

__device__ __forceinline__ ushort bfr(float x){
  unsigned int b = __float_as_uint(x);
  return (ushort)((b + 0x7FFFu + ((b>>16)&1u)) >> 16);
}
__device__ __forceinline__ unsigned int pk2(float a, float b){
  return (unsigned int)bfr(a) | ((unsigned int)bfr(b)<<16);
}
// gelu, sigmoid/tanh form: v*sigmoid(2*sqrt(2/pi)*(v+0.044715 v^3)).
// |err|<2e-4 for |v|<1 (our regime); overflow-safe (exp->inf => rcp->0 => 0).
__device__ __forceinline__ float fast_gelu(float v){
  float v2 = v*v;
  float u = v*(-1.5957691f - 0.0713548162f*v2);
  float e = __expf(u);
  return v*__builtin_amdgcn_rcpf(1.f + e);
}
// async global->LDS, 16B per lane; LDS dest = wave-uniform base + lane*16
__device__ __forceinline__ void gl_lds16(const void* g, void* l){
  __builtin_amdgcn_global_load_lds(
      (const __attribute__((address_space(1))) u32*)g,
      (__attribute__((address_space(3))) u32*)l, 16, 0, 0);
}

// ---------------- transpose x[B,D,L,N] -> y[B,L,N,D] ----------------
__global__ __launch_bounds__(256) void k_transpose(const float* __restrict__ x,
                                                   float* __restrict__ y){
  int g = blockIdx.x;            // b*1024 + l
  int b = g >> 10, l = g & 1023;
  __shared__ float sh[128*65];
  for (int idx = threadIdx.x; idx < 128*64; idx += 256){
    int d = idx >> 6, n = idx & 63;
    sh[d*65+n] = x[(((size_t)b*128 + d)*1024 + l)*64 + n];
  }
  __syncthreads();
  for (int idx = threadIdx.x; idx < 128*64; idx += 256){
    int n = idx >> 7, d = idx & 127;
    y[((size_t)g*64 + n)*128 + d] = sh[d*65+n];
  }
}

// ---------------- fp32 -> bf16 weight conversion ----------------
__global__ __launch_bounds__(256) void k_cvt(const float* __restrict__ src,
                                             ushort* __restrict__ dst, int n4){
  int i = blockIdx.x*256 + threadIdx.x;
  if (i < n4){
    float4 v = ((const float4*)src)[i];
    ushort4 p; p.x=bfr(v.x); p.y=bfr(v.y); p.z=bfr(v.z); p.w=bfr(v.w);
    ((ushort4*)dst)[i] = p;
  }
}

// ---------------- fused per-(b,l): row LN + row attn + residual
//                  + col LN stats + col raw q,k ([b][l][h][n] coalesced) ----
__global__ __launch_bounds__(256) void k_row(
    float* __restrict__ y,
    const float* __restrict__ rqw, const float* __restrict__ rqb,
    const float* __restrict__ rkw, const float* __restrict__ rkb,
    const float* __restrict__ rvw, const float* __restrict__ rvb,
    const float* __restrict__ roW, const float* __restrict__ rob,
    const float* __restrict__ lrg, const float* __restrict__ lrb,
    const float* __restrict__ cqw, const float* __restrict__ cqb,
    const float* __restrict__ ckw, const float* __restrict__ ckb,
    const float* __restrict__ lcg, const float* __restrict__ lcb,
    float2* __restrict__ stats,
    float* __restrict__ qout, float* __restrict__ kout)
{
  int g = blockIdx.x;
  __shared__ float sh_h[64*129];
  __shared__ float sh_w4[2048];
  __shared__ float sh_q[256], sh_k[256];
  __shared__ float sh_hk[512];
  __shared__ float sh_ktv[128];
  __shared__ __align__(16) float sh_P[512];
  int tid = threadIdx.x;
  for (int i = tid; i < 512; i += 256){
    sh_w4[i] = rqw[i]; sh_w4[512+i] = rkw[i];
    sh_w4[1024+i] = cqw[i]; sh_w4[1536+i] = ckw[i];
  }
  int ttk = tid>>2, s4 = tid&3;
  float* yr = y + ((size_t)g*64 + ttk)*128 + s4*32;
  float4 v[8];
  #pragma unroll
  for (int i=0;i<8;i++) v[i] = *(const float4*)(yr + i*4);
  float sum = 0.f;
  #pragma unroll
  for (int i=0;i<8;i++) sum += v[i].x+v[i].y+v[i].z+v[i].w;
  sum += __shfl_xor(sum,1); sum += __shfl_xor(sum,2);
  float mean = sum*(1.0f/128.0f);
  float vs = 0.f;
  #pragma unroll
  for (int i=0;i<8;i++){
    v[i].x-=mean; v[i].y-=mean; v[i].z-=mean; v[i].w-=mean;
    vs += v[i].x*v[i].x+v[i].y*v[i].y+v[i].z*v[i].z+v[i].w*v[i].w;
  }
  vs += __shfl_xor(vs,1); vs += __shfl_xor(vs,2);
  float rstd = rsqrtf(vs*(1.0f/128.0f) + 1e-5f);
  {
    const float* gp = lrg + s4*32; const float* bp = lrb + s4*32;
    float* hrow = &sh_h[ttk*129 + s4*32];
    #pragma unroll
    for (int i=0;i<8;i++){
      float4 g4 = *(const float4*)(gp+i*4);
      float4 b4 = *(const float4*)(bp+i*4);
      hrow[i*4+0]=v[i].x*rstd*g4.x+b4.x;
      hrow[i*4+1]=v[i].y*rstd*g4.y+b4.y;
      hrow[i*4+2]=v[i].z*rstd*g4.z+b4.z;
      hrow[i*4+3]=v[i].w*rstd*g4.w+b4.w;
    }
  }
  __syncthreads();
  int h = tid>>6, n = tid&63;
  {
    float qr = rqb[h], kr = rkb[h];
    const float* qwp = sh_w4 + h*128;
    const float* kwp = sh_w4 + 512 + h*128;
    const float* hp  = sh_h + n*129;
    #pragma unroll 4
    for (int d=0; d<128; d++){ float hv=hp[d]; qr+=hv*qwp[d]; kr+=hv*kwp[d]; }
    qr = qr > 0.f ? qr + 1.f : __expf(qr);
    kr = kr > 0.f ? kr + 1.f : __expf(kr);
    float qs = qr; for (int m=32;m>=1;m>>=1) qs += __shfl_xor(qs, m);
    float ks = kr; for (int m=32;m>=1;m>>=1) ks += __shfl_xor(ks, m);
    sh_q[h*64+n] = qr * (64.f/qs);
    sh_k[h*64+n] = kr * (1.f/ks);
  }
  __syncthreads();
  #pragma unroll
  for (int r=0;r<2;r++){
    int idx = tid + r*256;
    int hh = idx>>7, d = idx&127;
    float acc = 0.f;
    #pragma unroll 4
    for (int nn=0;nn<64;nn++) acc += sh_k[hh*64+nn]*sh_h[nn*129+d];
    sh_hk[hh*128+d] = acc;
  }
  __syncthreads();
  if (tid < 128){
    float acc = rvb[tid];
    const float* vr = rvw + (size_t)tid*128;
    const float* hp2 = sh_hk + (tid>>5)*128;
    #pragma unroll 4
    for (int d=0;d<128;d++) acc += vr[d]*hp2[d];
    sh_ktv[tid] = acc;
  }
  __syncthreads();
  #pragma unroll
  for (int r=0;r<2;r++){
    int idx = tid + r*256;
    int hh = idx>>7, e = idx&127;
    float acc = 0.f;
    const float* orow = roW + (size_t)e*128 + hh*32;
    #pragma unroll 4
    for (int j=0;j<32;j++) acc += orow[j]*sh_ktv[hh*32+j];
    sh_P[hh*128+e] = acc;
  }
  __syncthreads();
  {
    float q0=sh_q[ttk], q1=sh_q[64+ttk], q2=sh_q[128+ttk], q3=sh_q[192+ttk];
    const float4* P4 = (const float4*)sh_P;
    #pragma unroll
    for (int i=0;i<8;i++){
      int d4 = s4*8 + i;
      float4 p0=P4[d4], p1=P4[32+d4], p2=P4[64+d4], p3=P4[96+d4];
      float4 o4=*(const float4*)&rob[s4*32+i*4];
      v[i].x += mean + o4.x + q0*p0.x+q1*p1.x+q2*p2.x+q3*p3.x;
      v[i].y += mean + o4.y + q0*p0.y+q1*p1.y+q2*p2.y+q3*p3.y;
      v[i].z += mean + o4.z + q0*p0.z+q1*p1.z+q2*p2.z+q3*p3.z;
      v[i].w += mean + o4.w + q0*p0.w+q1*p1.w+q2*p2.w+q3*p3.w;
      *(float4*)(yr + i*4) = v[i];
    }
  }
  float sum2 = 0.f;
  #pragma unroll
  for (int i=0;i<8;i++) sum2 += v[i].x+v[i].y+v[i].z+v[i].w;
  sum2 += __shfl_xor(sum2,1); sum2 += __shfl_xor(sum2,2);
  float cmean = sum2*(1.0f/128.0f);
  float cvs = 0.f;
  #pragma unroll
  for (int i=0;i<8;i++){
    v[i].x-=cmean; v[i].y-=cmean; v[i].z-=cmean; v[i].w-=cmean;
    cvs += v[i].x*v[i].x+v[i].y*v[i].y+v[i].z*v[i].z+v[i].w*v[i].w;
  }
  cvs += __shfl_xor(cvs,1); cvs += __shfl_xor(cvs,2);
  float crstd = rsqrtf(cvs*(1.0f/128.0f) + 1e-5f);
  if (s4 == 0) stats[(size_t)g*64 + ttk] = make_float2(cmean, crstd);
  {
    const float* gp = lcg + s4*32; const float* bp = lcb + s4*32;
    float* hrow = &sh_h[ttk*129 + s4*32];
    #pragma unroll
    for (int i=0;i<8;i++){
      float4 g4 = *(const float4*)(gp+i*4);
      float4 b4 = *(const float4*)(bp+i*4);
      hrow[i*4+0]=v[i].x*crstd*g4.x+b4.x;
      hrow[i*4+1]=v[i].y*crstd*g4.y+b4.y;
      hrow[i*4+2]=v[i].z*crstd*g4.z+b4.z;
      hrow[i*4+3]=v[i].w*crstd*g4.w+b4.w;
    }
  }
  __syncthreads();
  {
    float qv = cqb[h], kv = ckb[h];
    const float* qwp = sh_w4 + 1024 + h*128;
    const float* kwp = sh_w4 + 1536 + h*128;
    const float* hp  = sh_h + n*129;
    #pragma unroll 4
    for (int d=0; d<128; d++){ float hv=hp[d]; qv+=hv*qwp[d]; kv+=hv*kwp[d]; }
    qv = qv > 0.f ? qv + 1.f : __expf(qv);
    kv = kv > 0.f ? kv + 1.f : __expf(kv);
    size_t o = (size_t)g*256 + tid;    // [b][l][h][n] — coalesced
    qout[o] = qv; kout[o] = kv;
  }
}

// ---------------- col: q-sum partials over l chunks ----------------
__global__ __launch_bounds__(256) void k_qsum(const float* __restrict__ qin,
                                              float* __restrict__ qsp){
  int gg = blockIdx.x;  // b*8 + c
  int c = gg&7, b = gg>>3;
  int tid = threadIdx.x;
  const float* qp = qin + ((size_t)b*1024 + c*128)*256 + tid;
  float s = 0.f;
  #pragma unroll 4
  for (int j=0;j<128;j++){ s += *qp; qp += 256; }
  qsp[(size_t)gg*256 + tid] = s;       // [b][c][h*64+n]
}

// ---------------- col: streaming reduce S1[d]=Σk·r·y, A=Σk, B=Σk·r·m ----
__global__ __launch_bounds__(256) void k_col_s1(
    const float* __restrict__ y, const float2* __restrict__ stats,
    const float* __restrict__ kin,
    float* __restrict__ s1p, float* __restrict__ Ab, float* __restrict__ Bb)
{
  int gg = blockIdx.x;                   // ((b*64+n)*8+s)
  int s = gg & 7, n = (gg>>3) & 63, b = gg>>9;
  int tid = threadIdx.x;
  int li = tid>>7, d = tid&127;
  const float* kp = kin + (size_t)b*262144 + n;   // [b][l][h][n]
  float a0=0.f,a1=0.f,a2=0.f,a3=0.f;
  float A0=0.f,A1=0.f,A2=0.f,A3=0.f;
  float B0=0.f,B1=0.f,B2=0.f,B3=0.f;
  for (int j=0;j<64;j++){
    int l = s*128 + 2*j + li;
    size_t t = ((size_t)(b*1024+l)*64+n);
    float2 st = stats[t];
    float w = st.y * y[t*128 + d];
    float rm = st.y*st.x;
    const float* kl = kp + (size_t)l*256;
    float k0 = kl[0], k1 = kl[64], k2 = kl[128], k3 = kl[192];
    a0 += k0*w; a1 += k1*w; a2 += k2*w; a3 += k3*w;
    A0 += k0; A1 += k1; A2 += k2; A3 += k3;
    B0 += k0*rm; B1 += k1*rm; B2 += k2*rm; B3 += k3*rm;
  }
  __shared__ float shr[512];
  __shared__ float sAB[8];
  if (li == 1){
    shr[0*128+d]=a0; shr[1*128+d]=a1; shr[2*128+d]=a2; shr[3*128+d]=a3;
    if (d==0){ sAB[0]=A0; sAB[1]=A1; sAB[2]=A2; sAB[3]=A3;
               sAB[4]=B0; sAB[5]=B1; sAB[6]=B2; sAB[7]=B3; }
  }
  __syncthreads();
  if (li == 0){
    float* out = s1p + (size_t)gg*512;
    out[0*128+d] = a0 + shr[0*128+d];
    out[1*128+d] = a1 + shr[1*128+d];
    out[2*128+d] = a2 + shr[2*128+d];
    out[3*128+d] = a3 + shr[3*128+d];
    if (d==0){
      Ab[gg*4+0]=A0+sAB[0]; Ab[gg*4+1]=A1+sAB[1];
      Ab[gg*4+2]=A2+sAB[2]; Ab[gg*4+3]=A3+sAB[3];
      Bb[gg*4+0]=B0+sAB[4]; Bb[gg*4+1]=B1+sAB[5];
      Bb[gg*4+2]=B2+sAB[6]; Bb[gg*4+3]=B3+sAB[7];
    }
  }
}

// ---------------- col: reduce S1/A/B/qs -> hk -> ktv -> P ----------------
__global__ __launch_bounds__(256) void k_col_ktvP(
    const float* __restrict__ s1p,
    const float* __restrict__ Ab, const float* __restrict__ Bb,
    const float* __restrict__ qsp,
    const float* __restrict__ vw, const float* __restrict__ vb,
    const float* __restrict__ ow,
    const float* __restrict__ lcg, const float* __restrict__ lcb,
    float* __restrict__ Pout)
{
  int gg = blockIdx.x;   // b*64+n
  int b = gg>>6, n = gg&63;
  __shared__ float sh_hk[512];
  __shared__ float sh_ktv[128];
  __shared__ float sh_A[4], sh_B[4], sh_qs[4];
  int tid = threadIdx.x;
  #pragma unroll
  for (int r = 0; r < 2; r++){
    int idx = tid + r*256;
    float acc = 0.f;
    #pragma unroll
    for (int s = 0; s < 8; s++) acc += s1p[((size_t)gg*8 + s)*512 + idx];
    sh_hk[idx] = acc;
  }
  if (tid < 4){
    float a=0.f, bb=0.f, q=0.f;
    #pragma unroll
    for (int s = 0; s < 8; s++){ a += Ab[(gg*8+s)*4+tid]; bb += Bb[(gg*8+s)*4+tid]; }
    #pragma unroll
    for (int c = 0; c < 8; c++) q += qsp[((b*8+c)<<8) + (tid<<6) + n];
    sh_A[tid]=a; sh_B[tid]=bb; sh_qs[tid] = 1024.f/q;
  }
  __syncthreads();
  #pragma unroll
  for (int r = 0; r < 2; r++){
    int idx = tid + r*256;
    int h = idx>>7, d = idx&127;
    sh_hk[idx] = lcg[d]*((sh_hk[idx]-sh_B[h])/sh_A[h]) + lcb[d];
  }
  __syncthreads();
  if (tid < 128){
    float acc = vb[tid];
    const float* vr = vw + (size_t)tid*128;
    const float* hp2 = sh_hk + (tid>>5)*128;
    #pragma unroll 4
    for (int d = 0; d < 128; d++) acc += vr[d]*hp2[d];
    sh_ktv[tid] = acc;
  }
  __syncthreads();
  #pragma unroll
  for (int r = 0; r < 2; r++){
    int idx = tid + r*256;
    int hh = idx >> 7, e = idx & 127;
    float acc = 0.f;
    const float* orow = ow + (size_t)e*128 + hh*32;
    #pragma unroll 4
    for (int j = 0; j < 32; j++) acc += orow[j]*sh_ktv[hh*32+j];
    Pout[(size_t)gg*512 + hh*128 + e] = acc * sh_qs[hh];
  }
}

// ---------------- fused col-out + FFN (bf16 MFMA, pipelined gload_lds) ----------------
__global__ __launch_bounds__(512, 4) void k_ffn(
    float* __restrict__ y,
    const float* __restrict__ qbuf, const float* __restrict__ Pb,
    const float* __restrict__ cob,
    const float* __restrict__ gam, const float* __restrict__ bet,
    const ushort* __restrict__ w1b, const float* __restrict__ b1,
    const ushort* __restrict__ w2b, const float* __restrict__ b2)
{
  __shared__ __align__(16) ushort pool[29952];  // 59904 B
  ushort* sW1 = pool;            // w1 chunk, 64 x 128
  ushort* sW2 = pool + 8192;     // w2 chunk, 128 x 64
  ushort* sH  = pool + 16384;    // 64 x 136
  ushort* sHf = pool + 25088;    // 64 x 72
  float*  sF  = (float*)pool;    // epilogue overlay, 64 x 132
  int tid = threadIdx.x;
  int g = blockIdx.x;
  size_t tb = (size_t)g*64;

  int wid = tid>>6, ln = tid&63;
  int lr = ln&15, gq = ln>>4;
  int wt = wid>>1, we = wid&1;
  int t0 = wt*16;

  #pragma unroll
  for (int i = 0; i < 2; i++){
    int row = wid*8 + i*4 + (ln>>4);
    gl_lds16(w1b + (size_t)row*128 + (((ln&15) ^ (row&7))<<3),
             &sW1[(wid*8 + i*4)*128]);
  }
  #pragma unroll
  for (int i = 0; i < 2; i++){
    int row = wid*16 + i*8 + (ln>>3);
    gl_lds16(w2b + (size_t)row*512 + (((ln&7) ^ (row&7))<<3),
             &sW2[(wid*16 + i*8)*64]);
  }

  int ttk = tid>>3, s8 = tid&7;
  float* yr = y + (tb+ttk)*128 + s8*16;
  float4 v[4];
  float fmean;
  {
    #pragma unroll
    for (int i = 0; i < 4; i++) v[i] = *(const float4*)(yr + i*4);
    const float* qp = qbuf + (size_t)g*256 + ttk;   // [b][l][h][n]
    float q0 = qp[0], q1 = qp[64], q2 = qp[128], q3 = qp[192];
    const float* pr = Pb + ((size_t)((g>>10)*64 + ttk))*512 + s8*16;
    #pragma unroll
    for (int i = 0; i < 4; i++){
      float4 p0 = *(const float4*)(pr + i*4);
      float4 p1 = *(const float4*)(pr + 128 + i*4);
      float4 p2 = *(const float4*)(pr + 256 + i*4);
      float4 p3 = *(const float4*)(pr + 384 + i*4);
      float4 c4 = *(const float4*)&cob[s8*16 + i*4];
      v[i].x += c4.x + q0*p0.x+q1*p1.x+q2*p2.x+q3*p3.x;
      v[i].y += c4.y + q0*p0.y+q1*p1.y+q2*p2.y+q3*p3.y;
      v[i].z += c4.z + q0*p0.z+q1*p1.z+q2*p2.z+q3*p3.z;
      v[i].w += c4.w + q0*p0.w+q1*p1.w+q2*p2.w+q3*p3.w;
    }
    float sum = 0.f;
    #pragma unroll
    for (int i = 0; i < 4; i++) sum += v[i].x+v[i].y+v[i].z+v[i].w;
    sum += __shfl_xor(sum,1); sum += __shfl_xor(sum,2); sum += __shfl_xor(sum,4);
    fmean = sum*(1.0f/128.0f);
    float vs = 0.f;
    #pragma unroll
    for (int i = 0; i < 4; i++){
      v[i].x-=fmean; v[i].y-=fmean; v[i].z-=fmean; v[i].w-=fmean;
      vs += v[i].x*v[i].x+v[i].y*v[i].y+v[i].z*v[i].z+v[i].w*v[i].w;
    }
    vs += __shfl_xor(vs,1); vs += __shfl_xor(vs,2); vs += __shfl_xor(vs,4);
    float rstd = rsqrtf(vs*(1.0f/128.0f) + 1e-5f);
    const float* gp = gam + s8*16; const float* bp = bet + s8*16;
    #pragma unroll
    for (int i = 0; i < 2; i++){
      float4 ga = *(const float4*)(gp + i*8),     gb = *(const float4*)(gp + i*8 + 4);
      float4 ba = *(const float4*)(bp + i*8),     bb = *(const float4*)(bp + i*8 + 4);
      float4 va = v[i*2], vb2 = v[i*2+1];
      int4 o;
      o.x = (int)pk2(va.x*rstd*ga.x+ba.x,  va.y*rstd*ga.y+ba.y);
      o.y = (int)pk2(va.z*rstd*ga.z+ba.z,  va.w*rstd*ga.w+ba.w);
      o.z = (int)pk2(vb2.x*rstd*gb.x+bb.x, vb2.y*rstd*gb.y+bb.y);
      o.w = (int)pk2(vb2.z*rstd*gb.z+bb.z, vb2.w*rstd*gb.w+bb.w);
      *(int4*)&sH[ttk*136 + s8*16 + i*8] = o;
    }
  }
  __syncthreads();

  f32x4 acc2[4] = {};

  for (int c = 0; c < 8; c++){
    f32x4 acc1[2] = {};
    #pragma unroll
    for (int ks = 0; ks < 4; ks++){
      bf16x8 bfv = *(const bf16x8*)&sH[(t0+lr)*136 + ks*32 + gq*8];
      #pragma unroll
      for (int i = 0; i < 2; i++){
        int er = we*32 + i*16 + lr;
        bf16x8 afv = *(const bf16x8*)&sW1[er*128 + ((((ks<<2)|gq) ^ (lr&7))<<3)];
        acc1[i] = __builtin_amdgcn_mfma_f32_16x16x32_bf16(afv, bfv, acc1[i], 0, 0, 0);
      }
    }
    #pragma unroll
    for (int i = 0; i < 2; i++){
      float4 bb = *(const float4*)&b1[c*64 + we*32 + i*16 + gq*4];
      ushort4 pk;
      pk.x = bfr(fast_gelu(acc1[i][0] + bb.x));
      pk.y = bfr(fast_gelu(acc1[i][1] + bb.y));
      pk.z = bfr(fast_gelu(acc1[i][2] + bb.z));
      pk.w = bfr(fast_gelu(acc1[i][3] + bb.w));
      *(ushort4*)&sHf[(t0+lr)*72 + we*32 + i*16 + gq*4] = pk;
    }
    __syncthreads();
    if (c < 7){
      #pragma unroll
      for (int i = 0; i < 2; i++){
        int row = wid*8 + i*4 + (ln>>4);
        gl_lds16(w1b + (size_t)(c+1)*8192 + (size_t)row*128 + (((ln&15) ^ (row&7))<<3),
                 &sW1[(wid*8 + i*4)*128]);
      }
    }
    #pragma unroll
    for (int ks = 0; ks < 2; ks++){
      bf16x8 bfv = *(const bf16x8*)&sHf[(t0+lr)*72 + ks*32 + gq*8];
      #pragma unroll
      for (int j = 0; j < 4; j++){
        int dr = we*64 + j*16 + lr;
        bf16x8 afv = *(const bf16x8*)&sW2[dr*64 + ((((ks<<2)|gq) ^ (lr&7))<<3)];
        acc2[j] = __builtin_amdgcn_mfma_f32_16x16x32_bf16(afv, bfv, acc2[j], 0, 0, 0);
      }
    }
    __syncthreads();
    if (c < 7){
      #pragma unroll
      for (int i = 0; i < 2; i++){
        int row = wid*16 + i*8 + (ln>>3);
        gl_lds16(w2b + (size_t)row*512 + (c+1)*64 + (((ln&7) ^ (row&7))<<3),
                 &sW2[(wid*16 + i*8)*64]);
      }
    }
  }

  #pragma unroll
  for (int j = 0; j < 4; j++){
    float4 fo; fo.x=acc2[j][0]; fo.y=acc2[j][1]; fo.z=acc2[j][2]; fo.w=acc2[j][3];
    *(float4*)&sF[(t0+lr)*132 + we*64 + j*16 + gq*4] = fo;
  }
  __syncthreads();
  #pragma unroll
  for (int i = 0; i < 4; i++){
    float4 f = *(const float4*)&sF[ttk*132 + s8*16 + i*4];
    float4 b4 = *(const float4*)&b2[s8*16 + i*4];
    float4 o;
    o.x = v[i].x + fmean + f.x + b4.x;
    o.y = v[i].y + fmean + f.y + b4.y;
    o.z = v[i].z + fmean + f.z + b4.z;
    o.w = v[i].w + fmean + f.w + b4.w;
    *(float4*)(yr + i*4) = o;
  }
}

// ---------------- head: xb partials (4 l-slices) + reduce ----------------
__global__ __launch_bounds__(128) void k_xbp(const float* __restrict__ y,
                                             float* __restrict__ xbq){
  int gg = blockIdx.x;   // (b*64+n)*4 + s
  int s = gg & 3, n = (gg>>2) & 63, b = gg>>8;
  int d = threadIdx.x;
  float acc = 0.f;
  int l0 = s*256 + (s==0 ? 1 : 0);
  const float* p = y + (((size_t)b*1024 + l0)*64 + n)*128 + d;
  for (int l = l0; l < s*256+256; l++){ acc += *p; p += 64*128; }
  xbq[(size_t)gg*128 + d] = acc;
}
__global__ __launch_bounds__(128) void k_xbr(const float* __restrict__ xbq,
                                             float* __restrict__ xb){
  int gg = blockIdx.x;   // b*64+n
  int d = threadIdx.x;
  const float* q = xbq + (size_t)gg*512;
  xb[(size_t)gg*128 + d] = (q[d] + q[128+d] + q[256+d] + q[384+d]) * (1.0f/1023.0f);
}

// ---------------- head: pairwise distances ----------------
__global__ __launch_bounds__(64) void k_dist(const float* __restrict__ xb,
                                             float* __restrict__ out){
  int p = blockIdx.x;           // b*2016 + pair
  int b = p >= 2016 ? 1 : 0;
  int pr = p - b*2016;
  int i0 = (int)((1.0f + sqrtf(1.0f + 8.0f*(float)pr))*0.5f);
  while (i0*(i0-1)/2 > pr) i0--;
  while ((i0+1)*i0/2 <= pr) i0++;
  int i1 = pr - i0*(i0-1)/2;
  int lane = threadIdx.x;
  const float* xa = xb + ((size_t)b*64 + i0)*128;
  const float* xc = xb + ((size_t)b*64 + i1)*128;
  float d0 = xa[lane]-xc[lane], d1 = xa[lane+64]-xc[lane+64];
  float s = d0*d0 + d1*d1;
  for (int m=32;m>=1;m>>=1) s += __shfl_xor(s, m);
  if (lane == 0) out[p] = sqrtf(s + 1e-8f);
}

extern "C" void kernel_launch(void* const* d_in, const int* in_sizes, int n_in,
                              void* d_out, int out_size, void* d_ws, size_t ws_size,
                              hipStream_t stream){
  const float* x    = (const float*)d_in[0];
  const float* rq_w = (const float*)d_in[1];  const float* rq_b = (const float*)d_in[2];
  const float* rk_w = (const float*)d_in[3];  const float* rk_b = (const float*)d_in[4];
  const float* rv_w = (const float*)d_in[5];  const float* rv_b = (const float*)d_in[6];
  const float* ro_w = (const float*)d_in[7];  const float* ro_b = (const float*)d_in[8];
  const float* cq_w = (const float*)d_in[9];  const float* cq_b = (const float*)d_in[10];
  const float* ck_w = (const float*)d_in[11]; const float* ck_b = (const float*)d_in[12];
  const float* cv_w = (const float*)d_in[13]; const float* cv_b = (const float*)d_in[14];
  const float* co_w = (const float*)d_in[15]; const float* co_b = (const float*)d_in[16];
  const float* lrg  = (const float*)d_in[17]; const float* lrb  = (const float*)d_in[18];
  const float* lcg  = (const float*)d_in[19]; const float* lcb  = (const float*)d_in[20];
  const float* lfg  = (const float*)d_in[21]; const float* lfb  = (const float*)d_in[22];
  const float* f1w  = (const float*)d_in[23]; const float* f1b  = (const float*)d_in[24];
  const float* f2w  = (const float*)d_in[25]; const float* f2b  = (const float*)d_in[26];

  float* ws = (float*)d_ws;
  float*  y   = ws;                           // 16777216
  float2* st  = (float2*)(ws + 16777216);     // 262144 floats
  float*  qb_ = ws + 17039360;                // 524288
  float*  kb_ = ws + 17563648;                // 524288
  float*  Pb  = ws + 18087936;                // 1048576
  float*  s1p = ws + 19136512;                // 524288
  float*  xb  = ws + 19661824;                // 16384
  ushort* w1b = (ushort*)(ws + 19678208);     // 262144 ushorts
  ushort* w2b = (ushort*)(ws + 19809280);     // 262144 ushorts
  float*  xbq = ws + 19940352;                // 65536
  float*  Ab  = ws + 20005888;                // 4096
  float*  Bb  = ws + 20009984;                // 4096
  float*  qsp = ws + 20014080;                // 4096

  k_transpose<<<dim3(2048), dim3(256), 0, stream>>>(x, y);
  k_cvt<<<dim3(256), dim3(256), 0, stream>>>(f1w, w1b, 65536);
  k_cvt<<<dim3(256), dim3(256), 0, stream>>>(f2w, w2b, 65536);
  for (int l = 0; l < LCNT; l++){
    k_row<<<dim3(2048), dim3(256), 0, stream>>>(y,
        rq_w + l*512, rq_b + l*4, rk_w + l*512, rk_b + l*4,
        rv_w + (size_t)l*16384, rv_b + l*128, ro_w + (size_t)l*16384, ro_b + l*128,
        lrg + l*128, lrb + l*128,
        cq_w + l*512, cq_b + l*4, ck_w + l*512, ck_b + l*4,
        lcg + l*128, lcb + l*128,
        st, qb_, kb_);
    k_qsum<<<dim3(16), dim3(256), 0, stream>>>(qb_, qsp);
    k_col_s1<<<dim3(1024), dim3(256), 0, stream>>>(y, st, kb_, s1p, Ab, Bb);
    k_col_ktvP<<<dim3(128), dim3(256), 0, stream>>>(s1p, Ab, Bb, qsp,
        cv_w + (size_t)l*16384, cv_b + l*128, co_w + (size_t)l*16384,
        lcg + l*128, lcb + l*128, Pb);
    k_ffn<<<dim3(2048), dim3(512), 0, stream>>>(y, qb_, Pb, co_b + l*128,
        lfg + l*128, lfb + l*128,
        w1b + (size_t)l*65536, f1b + l*512, w2b + (size_t)l*65536, f2b + l*128);
  }
  k_xbp<<<dim3(512), dim3(128), 0, stream>>>(y, xbq);
  k_xbr<<<dim3(128), dim3(128), 0, stream>>>(xbq, xb);
  k_dist<<<dim3(4032), dim3(64), 0, stream>>>(xb, (float*)d_out);
}

// Round 10
// 1076.625 us; speedup vs baseline: 3.6388x; 1.0279x over previous
//
#include <hip/hip_runtime.h>
#include <math.h>

#define LCNT 4

typedef float f32x4 __attribute__((ext_vector_type(4)));
typedef short bf16x8 __attribute__((ext_vector_type(8)));
typedef unsigned int u32;

__device__ __forceinline__ ushort bfr(float x){
  unsigned int b = __float_as_uint(x);
  return (ushort)((b + 0x7FFFu + ((b>>16)&1u)) >> 16);
}
__device__ __forceinline__ unsigned int pk2(float a, float b){
  return (unsigned int)bfr(a) | ((unsigned int)bfr(b)<<16);
}
// gelu, sigmoid/tanh form: v*sigmoid(2*sqrt(2/pi)*(v+0.044715 v^3)).
__device__ __forceinline__ float fast_gelu(float v){
  float v2 = v*v;
  float u = v*(-1.5957691f - 0.0713548162f*v2);
  float e = __expf(u);
  return v*__builtin_amdgcn_rcpf(1.f + e);
}
// async global->LDS, 16B per lane; LDS dest = wave-uniform base + lane*16
__device__ __forceinline__ void gl_lds16(const void* g, void* l){
  __builtin_amdgcn_global_load_lds(
      (const __attribute__((address_space(1))) u32*)g,
      (__attribute__((address_space(3))) u32*)l, 16, 0, 0);
}

// ---------------- transpose x[B,D,L,N] -> y[B,L,N,D] ----------------
__global__ __launch_bounds__(256) void k_transpose(const float* __restrict__ x,
                                                   float* __restrict__ y){
  int g = blockIdx.x;            // b*1024 + l
  int b = g >> 10, l = g & 1023;
  __shared__ float sh[128*65];
  for (int idx = threadIdx.x; idx < 128*64; idx += 256){
    int d = idx >> 6, n = idx & 63;
    sh[d*65+n] = x[(((size_t)b*128 + d)*1024 + l)*64 + n];
  }
  __syncthreads();
  for (int idx = threadIdx.x; idx < 128*64; idx += 256){
    int n = idx >> 7, d = idx & 127;
    y[((size_t)g*64 + n)*128 + d] = sh[d*65+n];
  }
}

// ---------------- fp32 -> bf16 weight conversion ----------------
__global__ __launch_bounds__(256) void k_cvt(const float* __restrict__ src,
                                             ushort* __restrict__ dst, int n4){
  int i = blockIdx.x*256 + threadIdx.x;
  if (i < n4){
    float4 v = ((const float4*)src)[i];
    ushort4 p; p.x=bfr(v.x); p.y=bfr(v.y); p.z=bfr(v.z); p.w=bfr(v.w);
    ((ushort4*)dst)[i] = p;
  }
}

// ---------------- fused per-(b,l): row LN + row attn + residual
//                  + col LN stats + col raw q,k  (float4 LDS everywhere) ----
#define HSTR 132
__global__ __launch_bounds__(256) void k_row(
    float* __restrict__ y,
    const float* __restrict__ rqw, const float* __restrict__ rqb,
    const float* __restrict__ rkw, const float* __restrict__ rkb,
    const float* __restrict__ rvw, const float* __restrict__ rvb,
    const float* __restrict__ roW, const float* __restrict__ rob,
    const float* __restrict__ lrg, const float* __restrict__ lrb,
    const float* __restrict__ cqw, const float* __restrict__ cqb,
    const float* __restrict__ ckw, const float* __restrict__ ckb,
    const float* __restrict__ lcg, const float* __restrict__ lcb,
    float2* __restrict__ stats,
    float* __restrict__ qout, float* __restrict__ kout)
{
  int g = blockIdx.x;
  __shared__ __align__(16) float sh_h[64*HSTR];
  __shared__ __align__(16) float sh_w4[2048];   // rqw|rkw|cqw|ckw (512 each)
  __shared__ float sh_q[256], sh_k[256];
  __shared__ __align__(16) float sh_hk[512];
  __shared__ __align__(16) float sh_ktv[128];
  __shared__ __align__(16) float sh_P[512];
  int tid = threadIdx.x;
  for (int i = tid; i < 512; i += 256){
    sh_w4[i] = rqw[i]; sh_w4[512+i] = rkw[i];
    sh_w4[1024+i] = cqw[i]; sh_w4[1536+i] = ckw[i];
  }
  // ---- A: load raw tile (regs) + row LN -> sh_h (float4 stores) ----
  int ttk = tid>>2, s4 = tid&3;
  float* yr = y + ((size_t)g*64 + ttk)*128 + s4*32;
  float4 v[8];
  #pragma unroll
  for (int i=0;i<8;i++) v[i] = *(const float4*)(yr + i*4);
  float sum = 0.f;
  #pragma unroll
  for (int i=0;i<8;i++) sum += v[i].x+v[i].y+v[i].z+v[i].w;
  sum += __shfl_xor(sum,1); sum += __shfl_xor(sum,2);
  float mean = sum*(1.0f/128.0f);
  float vs = 0.f;
  #pragma unroll
  for (int i=0;i<8;i++){
    v[i].x-=mean; v[i].y-=mean; v[i].z-=mean; v[i].w-=mean;
    vs += v[i].x*v[i].x+v[i].y*v[i].y+v[i].z*v[i].z+v[i].w*v[i].w;
  }
  vs += __shfl_xor(vs,1); vs += __shfl_xor(vs,2);
  float rstd = rsqrtf(vs*(1.0f/128.0f) + 1e-5f);
  {
    const float* gp = lrg + s4*32; const float* bp = lrb + s4*32;
    float* hrow = &sh_h[ttk*HSTR + s4*32];
    #pragma unroll
    for (int i=0;i<8;i++){
      float4 g4 = *(const float4*)(gp+i*4);
      float4 b4 = *(const float4*)(bp+i*4);
      float4 o;
      o.x=v[i].x*rstd*g4.x+b4.x;
      o.y=v[i].y*rstd*g4.y+b4.y;
      o.z=v[i].z*rstd*g4.z+b4.z;
      o.w=v[i].w*rstd*g4.w+b4.w;
      *(float4*)(hrow + i*4) = o;
    }
  }
  __syncthreads();
  // ---- B1: row q,k + normalize (float4 reads) ----
  int h = tid>>6, n = tid&63;
  {
    float qr = rqb[h], kr = rkb[h];
    const float4* hp  = (const float4*)&sh_h[n*HSTR];
    const float4* qwp = (const float4*)&sh_w4[h*128];
    const float4* kwp = (const float4*)&sh_w4[512 + h*128];
    #pragma unroll 8
    for (int j=0;j<32;j++){
      float4 hv = hp[j], qw = qwp[j], kw = kwp[j];
      qr += hv.x*qw.x + hv.y*qw.y + hv.z*qw.z + hv.w*qw.w;
      kr += hv.x*kw.x + hv.y*kw.y + hv.z*kw.z + hv.w*kw.w;
    }
    qr = qr > 0.f ? qr + 1.f : __expf(qr);
    kr = kr > 0.f ? kr + 1.f : __expf(kr);
    float qs = qr; for (int m=32;m>=1;m>>=1) qs += __shfl_xor(qs, m);
    float ks = kr; for (int m=32;m>=1;m>>=1) ks += __shfl_xor(ks, m);
    sh_q[h*64+n] = qr * (64.f/qs);
    sh_k[h*64+n] = kr * (1.f/ks);
  }
  __syncthreads();
  // ---- B2: hk[h][d] (scalar column reads, conflict-free) ----
  #pragma unroll
  for (int r=0;r<2;r++){
    int idx = tid + r*256;
    int hh = idx>>7, d = idx&127;
    float acc = 0.f;
    #pragma unroll 4
    for (int nn=0;nn<64;nn++) acc += sh_k[hh*64+nn]*sh_h[nn*HSTR+d];
    sh_hk[hh*128+d] = acc;
  }
  __syncthreads();
  // ---- B3: ktv[e] (float4) ----
  if (tid < 128){
    float acc = rvb[tid];
    const float4* vr = (const float4*)(rvw + (size_t)tid*128);
    const float4* hp2 = (const float4*)(sh_hk + (tid>>5)*128);
    #pragma unroll 8
    for (int j=0;j<32;j++){
      float4 a = vr[j], bq = hp2[j];
      acc += a.x*bq.x + a.y*bq.y + a.z*bq.z + a.w*bq.w;
    }
    sh_ktv[tid] = acc;
  }
  __syncthreads();
  // ---- B4: P[h][e] (float4) ----
  #pragma unroll
  for (int r=0;r<2;r++){
    int idx = tid + r*256;
    int hh = idx>>7, e = idx&127;
    float acc = 0.f;
    const float4* orow = (const float4*)(roW + (size_t)e*128 + hh*32);
    const float4* kt = (const float4*)(sh_ktv + hh*32);
    #pragma unroll
    for (int j=0;j<8;j++){
      float4 a = orow[j], bq = kt[j];
      acc += a.x*bq.x + a.y*bq.y + a.z*bq.z + a.w*bq.w;
    }
    sh_P[hh*128+e] = acc;
  }
  __syncthreads();
  // ---- C: y_new = raw + ob + q.P  (write y once) ----
  {
    float q0=sh_q[ttk], q1=sh_q[64+ttk], q2=sh_q[128+ttk], q3=sh_q[192+ttk];
    const float4* P4 = (const float4*)sh_P;
    #pragma unroll
    for (int i=0;i<8;i++){
      int d4 = s4*8 + i;
      float4 p0=P4[d4], p1=P4[32+d4], p2=P4[64+d4], p3=P4[96+d4];
      float4 o4=*(const float4*)&rob[s4*32+i*4];
      v[i].x += mean + o4.x + q0*p0.x+q1*p1.x+q2*p2.x+q3*p3.x;
      v[i].y += mean + o4.y + q0*p0.y+q1*p1.y+q2*p2.y+q3*p3.y;
      v[i].z += mean + o4.z + q0*p0.z+q1*p1.z+q2*p2.z+q3*p3.z;
      v[i].w += mean + o4.w + q0*p0.w+q1*p1.w+q2*p2.w+q3*p3.w;
      *(float4*)(yr + i*4) = v[i];
    }
  }
  // ---- D0: col LN stats on y_new + hnormc -> sh_h ----
  float sum2 = 0.f;
  #pragma unroll
  for (int i=0;i<8;i++) sum2 += v[i].x+v[i].y+v[i].z+v[i].w;
  sum2 += __shfl_xor(sum2,1); sum2 += __shfl_xor(sum2,2);
  float cmean = sum2*(1.0f/128.0f);
  float cvs = 0.f;
  #pragma unroll
  for (int i=0;i<8;i++){
    v[i].x-=cmean; v[i].y-=cmean; v[i].z-=cmean; v[i].w-=cmean;
    cvs += v[i].x*v[i].x+v[i].y*v[i].y+v[i].z*v[i].z+v[i].w*v[i].w;
  }
  cvs += __shfl_xor(cvs,1); cvs += __shfl_xor(cvs,2);
  float crstd = rsqrtf(cvs*(1.0f/128.0f) + 1e-5f);
  if (s4 == 0) stats[(size_t)g*64 + ttk] = make_float2(cmean, crstd);
  {
    const float* gp = lcg + s4*32; const float* bp = lcb + s4*32;
    float* hrow = &sh_h[ttk*HSTR + s4*32];
    #pragma unroll
    for (int i=0;i<8;i++){
      float4 g4 = *(const float4*)(gp+i*4);
      float4 b4 = *(const float4*)(bp+i*4);
      float4 o;
      o.x=v[i].x*crstd*g4.x+b4.x;
      o.y=v[i].y*crstd*g4.y+b4.y;
      o.z=v[i].z*crstd*g4.z+b4.z;
      o.w=v[i].w*crstd*g4.w+b4.w;
      *(float4*)(hrow + i*4) = o;
    }
  }
  __syncthreads();
  // ---- D1: col raw q,k (float4 reads, coalesced [b][l][h][n] stores) ----
  {
    float qv = cqb[h], kv = ckb[h];
    const float4* hp  = (const float4*)&sh_h[n*HSTR];
    const float4* qwp = (const float4*)&sh_w4[1024 + h*128];
    const float4* kwp = (const float4*)&sh_w4[1536 + h*128];
    #pragma unroll 8
    for (int j=0;j<32;j++){
      float4 hv = hp[j], qw = qwp[j], kw = kwp[j];
      qv += hv.x*qw.x + hv.y*qw.y + hv.z*qw.z + hv.w*qw.w;
      kv += hv.x*kw.x + hv.y*kw.y + hv.z*kw.z + hv.w*kw.w;
    }
    qv = qv > 0.f ? qv + 1.f : __expf(qv);
    kv = kv > 0.f ? kv + 1.f : __expf(kv);
    size_t o = (size_t)g*256 + tid;    // [b][l][h][n] — coalesced
    qout[o] = qv; kout[o] = kv;
  }
}

// ---------------- col: q-sum partials over l chunks ----------------
__global__ __launch_bounds__(256) void k_qsum(const float* __restrict__ qin,
                                              float* __restrict__ qsp){
  int gg = blockIdx.x;  // b*8 + c
  int c = gg&7, b = gg>>3;
  int tid = threadIdx.x;
  const float* qp = qin + ((size_t)b*1024 + c*128)*256 + tid;
  float s = 0.f;
  #pragma unroll 4
  for (int j=0;j<128;j++){ s += *qp; qp += 256; }
  qsp[(size_t)gg*256 + tid] = s;       // [b][c][h*64+n]
}

// ---------------- col: streaming reduce S1[d]=Σk·r·y, A=Σk, B=Σk·r·m ----
__global__ __launch_bounds__(256) void k_col_s1(
    const float* __restrict__ y, const float2* __restrict__ stats,
    const float* __restrict__ kin,
    float* __restrict__ s1p, float* __restrict__ Ab, float* __restrict__ Bb)
{
  int gg = blockIdx.x;                   // ((b*64+n)*8+s)
  int s = gg & 7, n = (gg>>3) & 63, b = gg>>9;
  int tid = threadIdx.x;
  int li = tid>>7, d = tid&127;
  const float* kp = kin + (size_t)b*262144 + n;   // [b][l][h][n]
  float a0=0.f,a1=0.f,a2=0.f,a3=0.f;
  float A0=0.f,A1=0.f,A2=0.f,A3=0.f;
  float B0=0.f,B1=0.f,B2=0.f,B3=0.f;
  for (int j=0;j<64;j++){
    int l = s*128 + 2*j + li;
    size_t t = ((size_t)(b*1024+l)*64+n);
    float2 st = stats[t];
    float w = st.y * y[t*128 + d];
    float rm = st.y*st.x;
    const float* kl = kp + (size_t)l*256;
    float k0 = kl[0], k1 = kl[64], k2 = kl[128], k3 = kl[192];
    a0 += k0*w; a1 += k1*w; a2 += k2*w; a3 += k3*w;
    A0 += k0; A1 += k1; A2 += k2; A3 += k3;
    B0 += k0*rm; B1 += k1*rm; B2 += k2*rm; B3 += k3*rm;
  }
  __shared__ float shr[512];
  __shared__ float sAB[8];
  if (li == 1){
    shr[0*128+d]=a0; shr[1*128+d]=a1; shr[2*128+d]=a2; shr[3*128+d]=a3;
    if (d==0){ sAB[0]=A0; sAB[1]=A1; sAB[2]=A2; sAB[3]=A3;
               sAB[4]=B0; sAB[5]=B1; sAB[6]=B2; sAB[7]=B3; }
  }
  __syncthreads();
  if (li == 0){
    float* out = s1p + (size_t)gg*512;
    out[0*128+d] = a0 + shr[0*128+d];
    out[1*128+d] = a1 + shr[1*128+d];
    out[2*128+d] = a2 + shr[2*128+d];
    out[3*128+d] = a3 + shr[3*128+d];
    if (d==0){
      Ab[gg*4+0]=A0+sAB[0]; Ab[gg*4+1]=A1+sAB[1];
      Ab[gg*4+2]=A2+sAB[2]; Ab[gg*4+3]=A3+sAB[3];
      Bb[gg*4+0]=B0+sAB[4]; Bb[gg*4+1]=B1+sAB[5];
      Bb[gg*4+2]=B2+sAB[6]; Bb[gg*4+3]=B3+sAB[7];
    }
  }
}

// ---------------- col: reduce S1/A/B/qs -> hk -> ktv -> P ----------------
__global__ __launch_bounds__(256) void k_col_ktvP(
    const float* __restrict__ s1p,
    const float* __restrict__ Ab, const float* __restrict__ Bb,
    const float* __restrict__ qsp,
    const float* __restrict__ vw, const float* __restrict__ vb,
    const float* __restrict__ ow,
    const float* __restrict__ lcg, const float* __restrict__ lcb,
    float* __restrict__ Pout)
{
  int gg = blockIdx.x;   // b*64+n
  int b = gg>>6, n = gg&63;
  __shared__ float sh_hk[512];
  __shared__ float sh_ktv[128];
  __shared__ float sh_A[4], sh_B[4], sh_qs[4];
  int tid = threadIdx.x;
  #pragma unroll
  for (int r = 0; r < 2; r++){
    int idx = tid + r*256;
    float acc = 0.f;
    #pragma unroll
    for (int s = 0; s < 8; s++) acc += s1p[((size_t)gg*8 + s)*512 + idx];
    sh_hk[idx] = acc;
  }
  if (tid < 4){
    float a=0.f, bb=0.f, q=0.f;
    #pragma unroll
    for (int s = 0; s < 8; s++){ a += Ab[(gg*8+s)*4+tid]; bb += Bb[(gg*8+s)*4+tid]; }
    #pragma unroll
    for (int c = 0; c < 8; c++) q += qsp[((b*8+c)<<8) + (tid<<6) + n];
    sh_A[tid]=a; sh_B[tid]=bb; sh_qs[tid] = 1024.f/q;
  }
  __syncthreads();
  #pragma unroll
  for (int r = 0; r < 2; r++){
    int idx = tid + r*256;
    int h = idx>>7, d = idx&127;
    sh_hk[idx] = lcg[d]*((sh_hk[idx]-sh_B[h])/sh_A[h]) + lcb[d];
  }
  __syncthreads();
  if (tid < 128){
    float acc = vb[tid];
    const float* vr = vw + (size_t)tid*128;
    const float* hp2 = sh_hk + (tid>>5)*128;
    #pragma unroll 4
    for (int d = 0; d < 128; d++) acc += vr[d]*hp2[d];
    sh_ktv[tid] = acc;
  }
  __syncthreads();
  #pragma unroll
  for (int r = 0; r < 2; r++){
    int idx = tid + r*256;
    int hh = idx >> 7, e = idx & 127;
    float acc = 0.f;
    const float* orow = ow + (size_t)e*128 + hh*32;
    #pragma unroll 4
    for (int j = 0; j < 32; j++) acc += orow[j]*sh_ktv[hh*32+j];
    Pout[(size_t)gg*512 + hh*128 + e] = acc * sh_qs[hh];
  }
}

// ---------------- fused col-out + FFN (bf16 MFMA, pipelined gload_lds) ----------------
__global__ __launch_bounds__(512, 4) void k_ffn(
    float* __restrict__ y,
    const float* __restrict__ qbuf, const float* __restrict__ Pb,
    const float* __restrict__ cob,
    const float* __restrict__ gam, const float* __restrict__ bet,
    const ushort* __restrict__ w1b, const float* __restrict__ b1,
    const ushort* __restrict__ w2b, const float* __restrict__ b2)
{
  __shared__ __align__(16) ushort pool[29952];  // 59904 B
  ushort* sW1 = pool;            // w1 chunk, 64 x 128
  ushort* sW2 = pool + 8192;     // w2 chunk, 128 x 64
  ushort* sH  = pool + 16384;    // 64 x 136
  ushort* sHf = pool + 25088;    // 64 x 72
  float*  sF  = (float*)pool;    // epilogue overlay, 64 x 132
  int tid = threadIdx.x;
  int g = blockIdx.x;
  size_t tb = (size_t)g*64;

  int wid = tid>>6, ln = tid&63;
  int lr = ln&15, gq = ln>>4;
  int wt = wid>>1, we = wid&1;
  int t0 = wt*16;

  #pragma unroll
  for (int i = 0; i < 2; i++){
    int row = wid*8 + i*4 + (ln>>4);
    gl_lds16(w1b + (size_t)row*128 + (((ln&15) ^ (row&7))<<3),
             &sW1[(wid*8 + i*4)*128]);
  }
  #pragma unroll
  for (int i = 0; i < 2; i++){
    int row = wid*16 + i*8 + (ln>>3);
    gl_lds16(w2b + (size_t)row*512 + (((ln&7) ^ (row&7))<<3),
             &sW2[(wid*16 + i*8)*64]);
  }

  int ttk = tid>>3, s8 = tid&7;
  float* yr = y + (tb+ttk)*128 + s8*16;
  float4 v[4];
  float fmean;
  {
    #pragma unroll
    for (int i = 0; i < 4; i++) v[i] = *(const float4*)(yr + i*4);
    const float* qp = qbuf + (size_t)g*256 + ttk;   // [b][l][h][n]
    float q0 = qp[0], q1 = qp[64], q2 = qp[128], q3 = qp[192];
    const float* pr = Pb + ((size_t)((g>>10)*64 + ttk))*512 + s8*16;
    #pragma unroll
    for (int i = 0; i < 4; i++){
      float4 p0 = *(const float4*)(pr + i*4);
      float4 p1 = *(const float4*)(pr + 128 + i*4);
      float4 p2 = *(const float4*)(pr + 256 + i*4);
      float4 p3 = *(const float4*)(pr + 384 + i*4);
      float4 c4 = *(const float4*)&cob[s8*16 + i*4];
      v[i].x += c4.x + q0*p0.x+q1*p1.x+q2*p2.x+q3*p3.x;
      v[i].y += c4.y + q0*p0.y+q1*p1.y+q2*p2.y+q3*p3.y;
      v[i].z += c4.z + q0*p0.z+q1*p1.z+q2*p2.z+q3*p3.z;
      v[i].w += c4.w + q0*p0.w+q1*p1.w+q2*p2.w+q3*p3.w;
    }
    float sum = 0.f;
    #pragma unroll
    for (int i = 0; i < 4; i++) sum += v[i].x+v[i].y+v[i].z+v[i].w;
    sum += __shfl_xor(sum,1); sum += __shfl_xor(sum,2); sum += __shfl_xor(sum,4);
    fmean = sum*(1.0f/128.0f);
    float vs = 0.f;
    #pragma unroll
    for (int i = 0; i < 4; i++){
      v[i].x-=fmean; v[i].y-=fmean; v[i].z-=fmean; v[i].w-=fmean;
      vs += v[i].x*v[i].x+v[i].y*v[i].y+v[i].z*v[i].z+v[i].w*v[i].w;
    }
    vs += __shfl_xor(vs,1); vs += __shfl_xor(vs,2); vs += __shfl_xor(vs,4);
    float rstd = rsqrtf(vs*(1.0f/128.0f) + 1e-5f);
    const float* gp = gam + s8*16; const float* bp = bet + s8*16;
    #pragma unroll
    for (int i = 0; i < 2; i++){
      float4 ga = *(const float4*)(gp + i*8),     gb = *(const float4*)(gp + i*8 + 4);
      float4 ba = *(const float4*)(bp + i*8),     bb = *(const float4*)(bp + i*8 + 4);
      float4 va = v[i*2], vb2 = v[i*2+1];
      int4 o;
      o.x = (int)pk2(va.x*rstd*ga.x+ba.x,  va.y*rstd*ga.y+ba.y);
      o.y = (int)pk2(va.z*rstd*ga.z+ba.z,  va.w*rstd*ga.w+ba.w);
      o.z = (int)pk2(vb2.x*rstd*gb.x+bb.x, vb2.y*rstd*gb.y+bb.y);
      o.w = (int)pk2(vb2.z*rstd*gb.z+bb.z, vb2.w*rstd*gb.w+bb.w);
      *(int4*)&sH[ttk*136 + s8*16 + i*8] = o;
    }
  }
  __syncthreads();

  f32x4 acc2[4] = {};

  for (int c = 0; c < 8; c++){
    f32x4 acc1[2] = {};
    #pragma unroll
    for (int ks = 0; ks < 4; ks++){
      bf16x8 bfv = *(const bf16x8*)&sH[(t0+lr)*136 + ks*32 + gq*8];
      #pragma unroll
      for (int i = 0; i < 2; i++){
        int er = we*32 + i*16 + lr;
        bf16x8 afv = *(const bf16x8*)&sW1[er*128 + ((((ks<<2)|gq) ^ (lr&7))<<3)];
        acc1[i] = __builtin_amdgcn_mfma_f32_16x16x32_bf16(afv, bfv, acc1[i], 0, 0, 0);
      }
    }
    #pragma unroll
    for (int i = 0; i < 2; i++){
      float4 bb = *(const float4*)&b1[c*64 + we*32 + i*16 + gq*4];
      ushort4 pk;
      pk.x = bfr(fast_gelu(acc1[i][0] + bb.x));
      pk.y = bfr(fast_gelu(acc1[i][1] + bb.y));
      pk.z = bfr(fast_gelu(acc1[i][2] + bb.z));
      pk.w = bfr(fast_gelu(acc1[i][3] + bb.w));
      *(ushort4*)&sHf[(t0+lr)*72 + we*32 + i*16 + gq*4] = pk;
    }
    __syncthreads();
    if (c < 7){
      #pragma unroll
      for (int i = 0; i < 2; i++){
        int row = wid*8 + i*4 + (ln>>4);
        gl_lds16(w1b + (size_t)(c+1)*8192 + (size_t)row*128 + (((ln&15) ^ (row&7))<<3),
                 &sW1[(wid*8 + i*4)*128]);
      }
    }
    #pragma unroll
    for (int ks = 0; ks < 2; ks++){
      bf16x8 bfv = *(const bf16x8*)&sHf[(t0+lr)*72 + ks*32 + gq*8];
      #pragma unroll
      for (int j = 0; j < 4; j++){
        int dr = we*64 + j*16 + lr;
        bf16x8 afv = *(const bf16x8*)&sW2[dr*64 + ((((ks<<2)|gq) ^ (lr&7))<<3)];
        acc2[j] = __builtin_amdgcn_mfma_f32_16x16x32_bf16(afv, bfv, acc2[j], 0, 0, 0);
      }
    }
    __syncthreads();
    if (c < 7){
      #pragma unroll
      for (int i = 0; i < 2; i++){
        int row = wid*16 + i*8 + (ln>>3);
        gl_lds16(w2b + (size_t)row*512 + (c+1)*64 + (((ln&7) ^ (row&7))<<3),
                 &sW2[(wid*16 + i*8)*64]);
      }
    }
  }

  #pragma unroll
  for (int j = 0; j < 4; j++){
    float4 fo; fo.x=acc2[j][0]; fo.y=acc2[j][1]; fo.z=acc2[j][2]; fo.w=acc2[j][3];
    *(float4*)&sF[(t0+lr)*132 + we*64 + j*16 + gq*4] = fo;
  }
  __syncthreads();
  #pragma unroll
  for (int i = 0; i < 4; i++){
    float4 f = *(const float4*)&sF[ttk*132 + s8*16 + i*4];
    float4 b4 = *(const float4*)&b2[s8*16 + i*4];
    float4 o;
    o.x = v[i].x + fmean + f.x + b4.x;
    o.y = v[i].y + fmean + f.y + b4.y;
    o.z = v[i].z + fmean + f.z + b4.z;
    o.w = v[i].w + fmean + f.w + b4.w;
    *(float4*)(yr + i*4) = o;
  }
}

// ---------------- head: xb partials (4 l-slices) + reduce ----------------
__global__ __launch_bounds__(128) void k_xbp(const float* __restrict__ y,
                                             float* __restrict__ xbq){
  int gg = blockIdx.x;   // (b*64+n)*4 + s
  int s = gg & 3, n = (gg>>2) & 63, b = gg>>8;
  int d = threadIdx.x;
  float acc = 0.f;
  int l0 = s*256 + (s==0 ? 1 : 0);
  const float* p = y + (((size_t)b*1024 + l0)*64 + n)*128 + d;
  for (int l = l0; l < s*256+256; l++){ acc += *p; p += 64*128; }
  xbq[(size_t)gg*128 + d] = acc;
}
__global__ __launch_bounds__(128) void k_xbr(const float* __restrict__ xbq,
                                             float* __restrict__ xb){
  int gg = blockIdx.x;   // b*64+n
  int d = threadIdx.x;
  const float* q = xbq + (size_t)gg*512;
  xb[(size_t)gg*128 + d] = (q[d] + q[128+d] + q[256+d] + q[384+d]) * (1.0f/1023.0f);
}

// ---------------- head: pairwise distances ----------------
__global__ __launch_bounds__(64) void k_dist(const float* __restrict__ xb,
                                             float* __restrict__ out){
  int p = blockIdx.x;           // b*2016 + pair
  int b = p >= 2016 ? 1 : 0;
  int pr = p - b*2016;
  int i0 = (int)((1.0f + sqrtf(1.0f + 8.0f*(float)pr))*0.5f);
  while (i0*(i0-1)/2 > pr) i0--;
  while ((i0+1)*i0/2 <= pr) i0++;
  int i1 = pr - i0*(i0-1)/2;
  int lane = threadIdx.x;
  const float* xa = xb + ((size_t)b*64 + i0)*128;
  const float* xc = xb + ((size_t)b*64 + i1)*128;
  float d0 = xa[lane]-xc[lane], d1 = xa[lane+64]-xc[lane+64];
  float s = d0*d0 + d1*d1;
  for (int m=32;m>=1;m>>=1) s += __shfl_xor(s, m);
  if (lane == 0) out[p] = sqrtf(s + 1e-8f);
}

extern "C" void kernel_launch(void* const* d_in, const int* in_sizes, int n_in,
                              void* d_out, int out_size, void* d_ws, size_t ws_size,
                              hipStream_t stream){
  const float* x    = (const float*)d_in[0];
  const float* rq_w = (const float*)d_in[1];  const float* rq_b = (const float*)d_in[2];
  const float* rk_w = (const float*)d_in[3];  const float* rk_b = (const float*)d_in[4];
  const float* rv_w = (const float*)d_in[5];  const float* rv_b = (const float*)d_in[6];
  const float* ro_w = (const float*)d_in[7];  const float* ro_b = (const float*)d_in[8];
  const float* cq_w = (const float*)d_in[9];  const float* cq_b = (const float*)d_in[10];
  const float* ck_w = (const float*)d_in[11]; const float* ck_b = (const float*)d_in[12];
  const float* cv_w = (const float*)d_in[13]; const float* cv_b = (const float*)d_in[14];
  const float* co_w = (const float*)d_in[15]; const float* co_b = (const float*)d_in[16];
  const float* lrg  = (const float*)d_in[17]; const float* lrb  = (const float*)d_in[18];
  const float* lcg  = (const float*)d_in[19]; const float* lcb  = (const float*)d_in[20];
  const float* lfg  = (const float*)d_in[21]; const float* lfb  = (const float*)d_in[22];
  const float* f1w  = (const float*)d_in[23]; const float* f1b  = (const float*)d_in[24];
  const float* f2w  = (const float*)d_in[25]; const float* f2b  = (const float*)d_in[26];

  float* ws = (float*)d_ws;
  float*  y   = ws;                           // 16777216
  float2* st  = (float2*)(ws + 16777216);     // 262144 floats
  float*  qb_ = ws + 17039360;                // 524288
  float*  kb_ = ws + 17563648;                // 524288
  float*  Pb  = ws + 18087936;                // 1048576
  float*  s1p = ws + 19136512;                // 524288
  float*  xb  = ws + 19661824;                // 16384
  ushort* w1b = (ushort*)(ws + 19678208);     // 262144 ushorts
  ushort* w2b = (ushort*)(ws + 19809280);     // 262144 ushorts
  float*  xbq = ws + 19940352;                // 65536
  float*  Ab  = ws + 20005888;                // 4096
  float*  Bb  = ws + 20009984;                // 4096
  float*  qsp = ws + 20014080;                // 4096

  k_transpose<<<dim3(2048), dim3(256), 0, stream>>>(x, y);
  k_cvt<<<dim3(256), dim3(256), 0, stream>>>(f1w, w1b, 65536);
  k_cvt<<<dim3(256), dim3(256), 0, stream>>>(f2w, w2b, 65536);
  for (int l = 0; l < LCNT; l++){
    k_row<<<dim3(2048), dim3(256), 0, stream>>>(y,
        rq_w + l*512, rq_b + l*4, rk_w + l*512, rk_b + l*4,
        rv_w + (size_t)l*16384, rv_b + l*128, ro_w + (size_t)l*16384, ro_b + l*128,
        lrg + l*128, lrb + l*128,
        cq_w + l*512, cq_b + l*4, ck_w + l*512, ck_b + l*4,
        lcg + l*128, lcb + l*128,
        st, qb_, kb_);
    k_qsum<<<dim3(16), dim3(256), 0, stream>>>(qb_, qsp);
    k_col_s1<<<dim3(1024), dim3(256), 0, stream>>>(y, st, kb_, s1p, Ab, Bb);
    k_col_ktvP<<<dim3(128), dim3(256), 0, stream>>>(s1p, Ab, Bb, qsp,
        cv_w + (size_t)l*16384, cv_b + l*128, co_w + (size_t)l*16384,
        lcg + l*128, lcb + l*128, Pb);
    k_ffn<<<dim3(2048), dim3(512), 0, stream>>>(y, qb_, Pb, co_b + l*128,
        lfg + l*128, lfb + l*128,
        w1b + (size_t)l*65536, f1b + l*512, w2b + (size_t)l*65536, f2b + l*128);
  }
  k_xbp<<<dim3(512), dim3(128), 0, stream>>>(y, xbq);
  k_xbr<<<dim3(128), dim3(128), 0, stream>>>(xbq, xb);
  k_dist<<<dim3(4032), dim3(64), 0, stream>>>(xb, (float*)d_out);
}